// Round 5
// baseline (2009.351 us; speedup 1.0000x reference)
//
#include <hip/hip_runtime.h>
#include <math.h>

#define Bq 4
#define Sq 4096
#define Dq 1024
#define Hq 128
#define Mq 256
#define Rq 64
#define Cq 64
#define NCHUNK 64
#define BSq (Bq*Sq)

typedef __attribute__((ext_vector_type(8))) short short8;
typedef __attribute__((ext_vector_type(4))) float f32x4;
typedef __attribute__((ext_vector_type(2))) unsigned int uintx2;

// ---- packed-weight arena layout (elements of unsigned short) ----
#define U_WKVTH  ((size_t)0)
#define U_WKVTL  (U_WKVTH + (size_t)2*Hq*Dq)
#define U_WEDATH (U_WKVTL + (size_t)2*Hq*Dq)
#define U_WEDATL (U_WEDATH + (size_t)3*Rq*Dq)
#define U_WGTH   (U_WEDATL + (size_t)3*Rq*Dq)
#define U_WGTL   (U_WGTH + (size_t)Dq*Dq)
#define U_WE2TH  (U_WGTL + (size_t)Dq*Dq)
#define U_WE2TL  (U_WE2TH + (size_t)Hq*Rq)
#define U_WD2TH  (U_WE2TL + (size_t)Hq*Rq)
#define U_WD2TL  (U_WD2TH + (size_t)Hq*Rq)
#define U_WA2TH  (U_WD2TL + (size_t)Hq*Rq)
#define U_WA2TL  (U_WA2TH + (size_t)Hq*Rq)
#define U_WOTH   (U_WA2TL + (size_t)Hq*Rq)
#define U_WOTL   (U_WOTH + (size_t)Dq*Hq)
#define U_END    (U_WOTL + (size_t)Dq*Hq)

__device__ __forceinline__ float softplusf_(float x){
  return fmaxf(x,0.f) + log1pf(expf(-fabsf(x)));
}
__device__ __forceinline__ float sigmoidf_(float x){
  return 1.f/(1.f+__expf(-x));
}
__device__ __forceinline__ unsigned short bf16rn(float x){
  unsigned u = __float_as_uint(x);
  u += 0x7fffu + ((u>>16)&1u);
  return (unsigned short)(u>>16);
}
__device__ __forceinline__ float bf16tof(unsigned short s){
  return __uint_as_float(((unsigned)s)<<16);
}
// packed 2xf32 -> 2xbf16 in one instruction (RNE, matches bf16rn).
__device__ __forceinline__ unsigned cvt_pk_bf16(float a, float b){
  unsigned r;
  asm("v_cvt_pk_bf16_f32 %0, %1, %2" : "=v"(r) : "v"(a), "v"(b));
  return r;
}
__device__ __forceinline__ float lo16f(unsigned p){ return __uint_as_float(p<<16); }
__device__ __forceinline__ float hi16f(unsigned p){ return __uint_as_float(p & 0xffff0000u); }
union pk8 { unsigned u[4]; short8 s; };

// branchless erf-gelu (A&S 7.1.26, |err|<=1.5e-7)
__device__ __forceinline__ float gelu_fast(float x){
  float z  = x*0.70710678118f;
  float az = fabsf(z);
  float t  = __builtin_amdgcn_rcpf(fmaf(0.3275911f, az, 1.f));
  float p  = fmaf(t, 1.061405429f, -1.453152027f);
  p = fmaf(t, p, 1.421413741f);
  p = fmaf(t, p, -0.284496736f);
  p = fmaf(t, p, 0.254829592f);
  p = p*t;
  float e  = __expf(-az*az);
  float er = copysignf(1.f - p*e, z);
  return 0.5f*x*(1.f + er);
}

// ---------------- bf16x3 MFMA GEMM, f32 A (cvt_pk staging) ----------------
template<int BN, int ACT>
__global__ __launch_bounds__(256) void gemm_bf3(
    const float* __restrict__ Af,
    const unsigned short* __restrict__ BhT, const unsigned short* __restrict__ BlT,
    float* __restrict__ C, const float* __restrict__ gate, int N, int K)
{
  constexpr int BM = 128;
  constexpr int PK = 40;
  constexpr int TN = BN/32;
  __shared__ __align__(16) unsigned short As[2][BM*PK];
  __shared__ __align__(16) unsigned short Bs[2][BN*PK];
  const int tid = threadIdx.x;
  const int bm = blockIdx.y*BM, bn = blockIdx.x*BN;
  const int wv = tid>>6, lane = tid&63;
  const int n16 = lane&15, q = lane>>4;
  const int wm = wv>>1, wn = wv&1;

  f32x4 acc[4][TN];
  #pragma unroll
  for (int i=0;i<4;i++){
    #pragma unroll
    for (int j=0;j<TN;j++){ f32x4 z={0.f,0.f,0.f,0.f}; acc[i][j]=z; }
  }
  for (int k0=0;k0<K;k0+=32){
    #pragma unroll
    for (int c0=0;c0<BM*8;c0+=256){
      int c = c0 + tid;
      int row = c>>3, kg = (c&7)*4;
      float4 v = *(const float4*)&Af[(size_t)(bm+row)*K + k0+kg];
      unsigned hp0 = cvt_pk_bf16(v.x, v.y), hp1 = cvt_pk_bf16(v.z, v.w);
      unsigned lp0 = cvt_pk_bf16(v.x-lo16f(hp0), v.y-hi16f(hp0));
      unsigned lp1 = cvt_pk_bf16(v.z-lo16f(hp1), v.w-hi16f(hp1));
      int off = row*PK+kg;
      uintx2 th = {hp0, hp1}, tl = {lp0, lp1};
      *(uintx2*)&As[0][off] = th;
      *(uintx2*)&As[1][off] = tl;
    }
    #pragma unroll
    for (int c0=0;c0<BN*4;c0+=256){
      int c = c0 + tid;
      int row = c>>2, kg = (c&3)*8;
      *(short8*)&Bs[0][row*PK+kg] = *(const short8*)&BhT[(size_t)(bn+row)*K + k0+kg];
      *(short8*)&Bs[1][row*PK+kg] = *(const short8*)&BlT[(size_t)(bn+row)*K + k0+kg];
    }
    __syncthreads();
    short8 a_h[4], a_l[4], b_h[TN], b_l[TN];
    #pragma unroll
    for (int i=0;i<4;i++){
      int r = wm*64 + i*16 + n16;
      a_h[i] = *(const short8*)&As[0][r*PK + q*8];
      a_l[i] = *(const short8*)&As[1][r*PK + q*8];
    }
    #pragma unroll
    for (int j=0;j<TN;j++){
      int r = wn*(BN/2) + j*16 + n16;
      b_h[j] = *(const short8*)&Bs[0][r*PK + q*8];
      b_l[j] = *(const short8*)&Bs[1][r*PK + q*8];
    }
    #pragma unroll
    for (int i=0;i<4;i++){
      #pragma unroll
      for (int j=0;j<TN;j++){
        acc[i][j] = __builtin_amdgcn_mfma_f32_16x16x32_bf16(a_h[i], b_h[j], acc[i][j], 0,0,0);
        acc[i][j] = __builtin_amdgcn_mfma_f32_16x16x32_bf16(a_l[i], b_h[j], acc[i][j], 0,0,0);
        acc[i][j] = __builtin_amdgcn_mfma_f32_16x16x32_bf16(a_h[i], b_l[j], acc[i][j], 0,0,0);
      }
    }
    __syncthreads();
  }
  #pragma unroll
  for (int i=0;i<4;i++){
    #pragma unroll
    for (int j=0;j<TN;j++){
      #pragma unroll
      for (int r=0;r<4;r++){
        int row = bm + wm*64 + i*16 + q*4 + r;
        int col = bn + wn*(BN/2) + j*16 + n16;
        float v = acc[i][j][r];
        if (ACT==1) v = softplusf_(v);
        else if (ACT==2) v = sigmoidf_(v);
        else if (ACT==3) v *= sigmoidf_(gate[(size_t)row*N+col]);
        C[(size_t)row*N+col] = v;
      }
    }
  }
}

// ---------------- bf16x3 MFMA GEMM, pre-split bf16 A (copy staging) --------
template<int BN>
__global__ __launch_bounds__(256) void gemm_bb(
    const unsigned short* __restrict__ Ah, const unsigned short* __restrict__ Al,
    const unsigned short* __restrict__ BhT, const unsigned short* __restrict__ BlT,
    float* __restrict__ C0, float* __restrict__ C1, float* __restrict__ C2, int K)
{
  constexpr int BM = 128;
  constexpr int PK = 40;
  constexpr int TN = BN/32;
  __shared__ __align__(16) unsigned short As[2][BM*PK];
  __shared__ __align__(16) unsigned short Bs[2][BN*PK];
  const int tid = threadIdx.x;
  const int bx = blockIdx.x;
  const int bm = blockIdx.y*BM;
  const int bnB = bx*BN;                   // row offset into packed B
  float* __restrict__ C = (bx==0) ? C0 : ((bx==1) ? C1 : C2);
  const int wv = tid>>6, lane = tid&63;
  const int n16 = lane&15, q = lane>>4;
  const int wm = wv>>1, wn = wv&1;

  f32x4 acc[4][TN];
  #pragma unroll
  for (int i=0;i<4;i++){
    #pragma unroll
    for (int j=0;j<TN;j++){ f32x4 z={0.f,0.f,0.f,0.f}; acc[i][j]=z; }
  }
  for (int k0=0;k0<K;k0+=32){
    #pragma unroll
    for (int c0=0;c0<BM*4;c0+=256){
      int c = c0 + tid;
      int row = c>>2, kg = (c&3)*8;
      *(short8*)&As[0][row*PK+kg] = *(const short8*)&Ah[(size_t)(bm+row)*K + k0+kg];
      *(short8*)&As[1][row*PK+kg] = *(const short8*)&Al[(size_t)(bm+row)*K + k0+kg];
    }
    #pragma unroll
    for (int c0=0;c0<BN*4;c0+=256){
      int c = c0 + tid;
      int row = c>>2, kg = (c&3)*8;
      *(short8*)&Bs[0][row*PK+kg] = *(const short8*)&BhT[(size_t)(bnB+row)*K + k0+kg];
      *(short8*)&Bs[1][row*PK+kg] = *(const short8*)&BlT[(size_t)(bnB+row)*K + k0+kg];
    }
    __syncthreads();
    short8 a_h[4], a_l[4], b_h[TN], b_l[TN];
    #pragma unroll
    for (int i=0;i<4;i++){
      int r = wm*64 + i*16 + n16;
      a_h[i] = *(const short8*)&As[0][r*PK + q*8];
      a_l[i] = *(const short8*)&As[1][r*PK + q*8];
    }
    #pragma unroll
    for (int j=0;j<TN;j++){
      int r = wn*(BN/2) + j*16 + n16;
      b_h[j] = *(const short8*)&Bs[0][r*PK + q*8];
      b_l[j] = *(const short8*)&Bs[1][r*PK + q*8];
    }
    #pragma unroll
    for (int i=0;i<4;i++){
      #pragma unroll
      for (int j=0;j<TN;j++){
        acc[i][j] = __builtin_amdgcn_mfma_f32_16x16x32_bf16(a_h[i], b_h[j], acc[i][j], 0,0,0);
        acc[i][j] = __builtin_amdgcn_mfma_f32_16x16x32_bf16(a_l[i], b_h[j], acc[i][j], 0,0,0);
        acc[i][j] = __builtin_amdgcn_mfma_f32_16x16x32_bf16(a_h[i], b_l[j], acc[i][j], 0,0,0);
      }
    }
    __syncthreads();
  }
  #pragma unroll
  for (int i=0;i<4;i++){
    #pragma unroll
    for (int j=0;j<TN;j++){
      #pragma unroll
      for (int r=0;r<4;r++){
        int row = bm + wm*64 + i*16 + q*4 + r;
        int col = wn*(BN/2) + j*16 + n16;
        C[(size_t)row*BN+col] = acc[i][j][r];
      }
    }
  }
}

// ---------------- merged second-stage R=64 GEMMs (eta/delta/alpha) --------
__global__ __launch_bounds__(256) void gemm_eda2(
    const float* __restrict__ te, const float* __restrict__ td, const float* __restrict__ ta,
    const unsigned short* __restrict__ usb,
    float* __restrict__ etab, float* __restrict__ deltab, float* __restrict__ alphab)
{
  constexpr int BM = 128, PK = 40, BN = 128, TN = 4, K = Rq, N = Hq;
  __shared__ __align__(16) unsigned short As[2][BM*PK];
  __shared__ __align__(16) unsigned short Bs[2][BN*PK];
  const int tid = threadIdx.x;
  const int bx = blockIdx.x;
  const int bm = blockIdx.y*BM;
  const float* __restrict__ Af = (bx==0) ? te : (bx==1) ? td : ta;
  const unsigned short* __restrict__ BhT = usb + ((bx==0) ? U_WE2TH : (bx==1) ? U_WD2TH : U_WA2TH);
  const unsigned short* __restrict__ BlT = usb + ((bx==0) ? U_WE2TL : (bx==1) ? U_WD2TL : U_WA2TL);
  float* __restrict__ C = (bx==0) ? etab : (bx==1) ? deltab : alphab;
  const int wv = tid>>6, lane = tid&63;
  const int n16 = lane&15, q = lane>>4;
  const int wm = wv>>1, wn = wv&1;

  f32x4 acc[4][TN];
  #pragma unroll
  for (int i=0;i<4;i++){
    #pragma unroll
    for (int j=0;j<TN;j++){ f32x4 z={0.f,0.f,0.f,0.f}; acc[i][j]=z; }
  }
  for (int k0=0;k0<K;k0+=32){
    #pragma unroll
    for (int c0=0;c0<BM*8;c0+=256){
      int c = c0 + tid;
      int row = c>>3, kg = (c&7)*4;
      float4 v = *(const float4*)&Af[(size_t)(bm+row)*K + k0+kg];
      unsigned hp0 = cvt_pk_bf16(v.x, v.y), hp1 = cvt_pk_bf16(v.z, v.w);
      unsigned lp0 = cvt_pk_bf16(v.x-lo16f(hp0), v.y-hi16f(hp0));
      unsigned lp1 = cvt_pk_bf16(v.z-lo16f(hp1), v.w-hi16f(hp1));
      int off = row*PK+kg;
      uintx2 th = {hp0, hp1}, tl = {lp0, lp1};
      *(uintx2*)&As[0][off] = th;
      *(uintx2*)&As[1][off] = tl;
    }
    #pragma unroll
    for (int c0=0;c0<BN*4;c0+=256){
      int c = c0 + tid;
      int row = c>>2, kg = (c&3)*8;
      *(short8*)&Bs[0][row*PK+kg] = *(const short8*)&BhT[(size_t)row*K + k0+kg];
      *(short8*)&Bs[1][row*PK+kg] = *(const short8*)&BlT[(size_t)row*K + k0+kg];
    }
    __syncthreads();
    short8 a_h[4], a_l[4], b_h[TN], b_l[TN];
    #pragma unroll
    for (int i=0;i<4;i++){
      int r = wm*64 + i*16 + n16;
      a_h[i] = *(const short8*)&As[0][r*PK + q*8];
      a_l[i] = *(const short8*)&As[1][r*PK + q*8];
    }
    #pragma unroll
    for (int j=0;j<TN;j++){
      int r = wn*(BN/2) + j*16 + n16;
      b_h[j] = *(const short8*)&Bs[0][r*PK + q*8];
      b_l[j] = *(const short8*)&Bs[1][r*PK + q*8];
    }
    #pragma unroll
    for (int i=0;i<4;i++){
      #pragma unroll
      for (int j=0;j<TN;j++){
        acc[i][j] = __builtin_amdgcn_mfma_f32_16x16x32_bf16(a_h[i], b_h[j], acc[i][j], 0,0,0);
        acc[i][j] = __builtin_amdgcn_mfma_f32_16x16x32_bf16(a_l[i], b_h[j], acc[i][j], 0,0,0);
        acc[i][j] = __builtin_amdgcn_mfma_f32_16x16x32_bf16(a_h[i], b_l[j], acc[i][j], 0,0,0);
      }
    }
    __syncthreads();
  }
  #pragma unroll
  for (int i=0;i<4;i++){
    #pragma unroll
    for (int j=0;j<TN;j++){
      #pragma unroll
      for (int r=0;r<4;r++){
        int row = bm + wm*64 + i*16 + q*4 + r;
        int col = wn*(BN/2) + j*16 + n16;
        float v = acc[i][j][r];
        v = (bx==2) ? sigmoidf_(v) : softplusf_(v);
        C[(size_t)row*N+col] = v;
      }
    }
  }
}

// ---------------- one-shot weight transpose+split (10 segments) ------------
__global__ __launch_bounds__(256) void splitT_all(
    const float* __restrict__ Wk,  const float* __restrict__ Wv,
    const float* __restrict__ We1, const float* __restrict__ Wd1,
    const float* __restrict__ Wa1, const float* __restrict__ Wg,
    const float* __restrict__ We2, const float* __restrict__ Wd2,
    const float* __restrict__ Wa2, const float* __restrict__ Wo,
    unsigned short* __restrict__ usb)
{
  size_t idx = (size_t)blockIdx.x*256 + threadIdx.x;
#define SEG(SRC, DH, DL, K_, N_) \
  { size_t sz = (size_t)(K_)*(N_); \
    if (idx < sz){ \
      int nn = (int)(idx/(K_)); int k = (int)(idx - (size_t)nn*(K_)); \
      float v = (SRC)[(size_t)k*(N_) + nn]; \
      unsigned short hh = bf16rn(v); \
      (DH)[idx] = hh; (DL)[idx] = bf16rn(v - bf16tof(hh)); \
      return; } \
    idx -= sz; }
  SEG(Wk,  usb+U_WKVTH,                    usb+U_WKVTL,                    Dq, Hq)
  SEG(Wv,  usb+U_WKVTH+(size_t)Hq*Dq,      usb+U_WKVTL+(size_t)Hq*Dq,      Dq, Hq)
  SEG(We1, usb+U_WEDATH,                   usb+U_WEDATL,                   Dq, Rq)
  SEG(Wd1, usb+U_WEDATH+(size_t)Rq*Dq,     usb+U_WEDATL+(size_t)Rq*Dq,     Dq, Rq)
  SEG(Wa1, usb+U_WEDATH+(size_t)2*Rq*Dq,   usb+U_WEDATL+(size_t)2*Rq*Dq,   Dq, Rq)
  SEG(Wg,  usb+U_WGTH,                     usb+U_WGTL,                     Dq, Dq)
  SEG(We2, usb+U_WE2TH,                    usb+U_WE2TL,                    Rq, Hq)
  SEG(Wd2, usb+U_WD2TH,                    usb+U_WD2TL,                    Rq, Hq)
  SEG(Wa2, usb+U_WA2TH,                    usb+U_WA2TL,                    Rq, Hq)
  SEG(Wo,  usb+U_WOTH,                     usb+U_WOTL,                     Hq, Dq)
#undef SEG
}

// row-major f32 [M][K] -> bf16 hi/lo planes (no transpose). 1 float4/thread.
__global__ __launch_bounds__(256) void splitX(const float* __restrict__ A,
    unsigned short* __restrict__ h, unsigned short* __restrict__ l)
{
  size_t idx = ((size_t)blockIdx.x*256 + threadIdx.x)*4;
  float4 v = *(const float4*)&A[idx];
  unsigned hp0 = cvt_pk_bf16(v.x, v.y), hp1 = cvt_pk_bf16(v.z, v.w);
  unsigned lp0 = cvt_pk_bf16(v.x-lo16f(hp0), v.y-hi16f(hp0));
  unsigned lp1 = cvt_pk_bf16(v.z-lo16f(hp1), v.w-hi16f(hp1));
  uintx2 th = {hp0, hp1}, tl = {lp0, lp1};
  *(uintx2*)&h[idx] = th;
  *(uintx2*)&l[idx] = tl;
}

// conv+LN for k: emits pre-split bf16 hi/lo planes (the scan's GEMM1 reads
// A-fragments straight from these; kc LDS staging eliminated). v: f32.
__global__ __launch_bounds__(128) void conv_ln_kernel(
  const float* __restrict__ k_raw, const float* __restrict__ v_raw,
  const float* __restrict__ conv_w, const float* __restrict__ conv_b,
  const float* __restrict__ kn_g, const float* __restrict__ kn_b,
  unsigned short* __restrict__ khi, unsigned short* __restrict__ klo,
  float* __restrict__ v_out)
{
  int s = blockIdx.x, b = blockIdx.y, which = blockIdx.z;
  int h = threadIdx.x;
  const float* src = (which==0) ? k_raw : v_raw;
  float acc = conv_b[h];
  #pragma unroll
  for (int j=0;j<4;j++){
    int ss = s-3+j;
    if (ss>=0) acc += conv_w[h*4+j]*src[((size_t)b*Sq+ss)*Hq + h];
  }
  if (which==0){
    __shared__ float red[4];
    float sv = acc, s2 = acc*acc;
    #pragma unroll
    for (int off=32; off>0; off>>=1){
      sv += __shfl_down(sv, off, 64);
      s2 += __shfl_down(s2, off, 64);
    }
    if ((h&63)==0){ red[(h>>6)*2]=sv; red[(h>>6)*2+1]=s2; }
    __syncthreads();
    float mean = (red[0]+red[2])*(1.f/128.f);
    float var  = (red[1]+red[3])*(1.f/128.f) - mean*mean;
    float y = (acc-mean)*rsqrtf(var+1e-5f)*kn_g[h]+kn_b[h];
    unsigned short hh = bf16rn(y);
    size_t idx = ((size_t)b*Sq+s)*Hq + h;
    khi[idx] = hh;
    klo[idx] = bf16rn(y - bf16tof(hh));
  } else {
    v_out[((size_t)b*Sq+s)*Hq + h] = acc;
  }
}

// ---- LDS overlay offsets (bytes) for the fused kernel's scan branch ----
// kc staging removed (GEMM1 reads global khi/klo directly); Dred/Suu removed
// (b1u via register w2t). Scan total 38,416 B; Wg branch needs 40,960.
#define OFF_ACTH  0            // 64*256*2 = 32768
#define OFF_SAM   32768        // 1024
#define OFF_SUS   33792        // 512
#define OFF_PEN   34304        // 64*12*4 = 3072
#define OFF_SAB   37376        // 512
#define OFF_SEB   37888        // 512
#define OFF_SABP  38400        // 8
#define OFF_SEBP  38408        // 8
#define LDS_TOTAL 40960

// Fused kernel: blocks 0..3 = sequential scan (1 per batch);
// blocks 4.. = Wg GEMM tiles. launch_bounds (512,1): VGPR cap 256 (8-wave
// block still forces 2 waves/SIMD; w2t state needs the headroom).
// Scan schedule (3 barriers/chunk):
//   BS -> [ab/eb issue] -> W1+w2t+b1 update(t-1) -> GEMM1(global kc frags)
//      -> gelu/act/am -> publish -> BA -> [vv/dd + touch issue] -> GEMM2
//      -> epi/pen -> BP -> en/grad/us -> Sus -> b2 -> ush -> W2 update -> BS
__global__ __launch_bounds__(512, 1) void fused_scan_wg(
  const unsigned short* __restrict__ khi, const unsigned short* __restrict__ klo,
  const float* __restrict__ v_c,
  const float* __restrict__ eta, const float* __restrict__ delta,
  const float* __restrict__ alpha,
  const float* __restrict__ mW1, const float* __restrict__ mb1,
  const float* __restrict__ mW2, const float* __restrict__ mb2,
  float* __restrict__ combined,
  const float* __restrict__ x,
  const unsigned short* __restrict__ WgTh, const unsigned short* __restrict__ WgTl,
  float* __restrict__ glog)
{
  __shared__ __align__(16) char smem[LDS_TOTAL];
  const int blk = blockIdx.x;
  const int tid = threadIdx.x;
  const int wv = tid >> 6;
  const int lane = tid & 63;
  const int n = lane & 15;
  const int q = lane >> 4;

  if (blk >= 4){
    // ================= Wg GEMM branch (512 thr, 128x128 tile) =================
    unsigned short* As_h = (unsigned short*)smem;          // 128*40
    unsigned short* As_l = As_h + 128*40;
    unsigned short* Bs_h = As_l + 128*40;
    unsigned short* Bs_l = Bs_h + 128*40;
    const int g = blk - 4;
    const int bm = (g>>3)*128, bn = (g&7)*128;
    const int wm = wv&3, wn = wv>>2;
    f32x4 acc[2][4];
    #pragma unroll
    for (int i=0;i<2;i++){
      #pragma unroll
      for (int j=0;j<4;j++){ f32x4 z={0.f,0.f,0.f,0.f}; acc[i][j]=z; }
    }
    for (int k0=0;k0<Dq;k0+=32){
      #pragma unroll
      for (int r=0;r<2;r++){
        int idx = tid + 512*r;
        int row = idx>>3, kg = (idx&7)*4;
        float4 v = *(const float4*)&x[(size_t)(bm+row)*Dq + k0+kg];
        unsigned hp0 = cvt_pk_bf16(v.x, v.y), hp1 = cvt_pk_bf16(v.z, v.w);
        unsigned lp0 = cvt_pk_bf16(v.x-lo16f(hp0), v.y-hi16f(hp0));
        unsigned lp1 = cvt_pk_bf16(v.z-lo16f(hp1), v.w-hi16f(hp1));
        int off = row*40+kg;
        uintx2 th = {hp0, hp1}, tl = {lp0, lp1};
        *(uintx2*)&As_h[off] = th;
        *(uintx2*)&As_l[off] = tl;
      }
      {
        int row = tid>>2, kg = (tid&3)*8;
        *(short8*)&Bs_h[row*40+kg] = *(const short8*)&WgTh[(size_t)(bn+row)*Dq + k0+kg];
        *(short8*)&Bs_l[row*40+kg] = *(const short8*)&WgTl[(size_t)(bn+row)*Dq + k0+kg];
      }
      __syncthreads();
      short8 a_h[2], a_l[2], b_h[4], b_l[4];
      #pragma unroll
      for (int i=0;i<2;i++){
        int r = wm*32 + i*16 + n;
        a_h[i] = *(const short8*)&As_h[r*40 + q*8];
        a_l[i] = *(const short8*)&As_l[r*40 + q*8];
      }
      #pragma unroll
      for (int j=0;j<4;j++){
        int r = wn*64 + j*16 + n;
        b_h[j] = *(const short8*)&Bs_h[r*40 + q*8];
        b_l[j] = *(const short8*)&Bs_l[r*40 + q*8];
      }
      #pragma unroll
      for (int i=0;i<2;i++){
        #pragma unroll
        for (int j=0;j<4;j++){
          acc[i][j] = __builtin_amdgcn_mfma_f32_16x16x32_bf16(a_h[i], b_h[j], acc[i][j], 0,0,0);
          acc[i][j] = __builtin_amdgcn_mfma_f32_16x16x32_bf16(a_l[i], b_h[j], acc[i][j], 0,0,0);
          acc[i][j] = __builtin_amdgcn_mfma_f32_16x16x32_bf16(a_h[i], b_l[j], acc[i][j], 0,0,0);
        }
      }
      __syncthreads();
    }
    #pragma unroll
    for (int i=0;i<2;i++){
      #pragma unroll
      for (int j=0;j<4;j++){
        #pragma unroll
        for (int r=0;r<4;r++){
          int row = bm + wm*32 + i*16 + q*4 + r;
          int col = bn + wn*64 + j*16 + n;
          glog[(size_t)row*Dq+col] = acc[i][j][r];
        }
      }
    }
    return;
  }

  // ================= scan branch =================
  unsigned short* act_hi = (unsigned short*)(smem + OFF_ACTH);
  float* Sam = (float*)(smem + OFF_SAM);
  float* Sus = (float*)(smem + OFF_SUS);
  float* pen = (float*)(smem + OFF_PEN);   // [c][12] (8 wave partials)
  float* Sab = (float*)(smem + OFF_SAB);
  float* Seb = (float*)(smem + OFF_SEB);
  float* Sabp = (float*)(smem + OFF_SABP);
  float* Sebp = (float*)(smem + OFF_SEBP);

  const int b = blk;
  const int h = wv*16 + n;          // W2 row ownership (A-frag of swapped GEMM2)
  // register state: W1 (GEMM1-B layout), W2 (GEMM2-A layout), W2^T copy
  // (h-major per-m, for the all-VALU b1u = us.nW2 path — replaces the
  // shuffle butterfly + Dred/Suu LDS traffic).
  float w1m[2][4][8];   // W1[m=(2wv+tt)*16+n][h=ks*32+q*8+j]
  float w2m[8][8];      // W2[h=wv*16+n][m=ks2*32+q*8+j]
  float w2t[2][4][8];   // W2[h=ks*32+q*8+j][m=(2wv+tt)*16+n]
  float b1reg[2];       // b1[m=(2wv+tt)*16+n]
  float b2n[4];         // b2[h2=wv*16+q*4+r]
  #pragma unroll
  for (int tt=0;tt<2;tt++){
    int m = (2*wv+tt)*16 + n;
    #pragma unroll
    for (int ks=0;ks<4;ks++){
      const float* p = mW1 + (size_t)m*Hq + ks*32 + q*8;
      #pragma unroll
      for (int j=0;j<8;j++) w1m[tt][ks][j] = p[j];
      #pragma unroll
      for (int j=0;j<8;j++) w2t[tt][ks][j] = mW2[(size_t)(ks*32+q*8+j)*Mq + m];
    }
    b1reg[tt] = mb1[m];
  }
  {
    #pragma unroll
    for (int ks2=0;ks2<8;ks2++){
      const float* p = mW2 + (size_t)h*Mq + ks2*32 + q*8;
      #pragma unroll
      for (int j=0;j<8;j++) w2m[ks2][j] = p[j];
    }
    #pragma unroll
    for (int r=0;r<4;r++) b2n[r] = mb2[wv*16 + q*4 + r];
  }
  // cross-chunk carried scalars (chunk t-1 values, consumed at t's top)
  float aw = 0.f, ew = 0.f;
  float am_own[2] = {0.f, 0.f};

  const unsigned short* khb = khi + (size_t)b*Sq*Hq;
  const unsigned short* klb = klo + (size_t)b*Sq*Hq;

  for (int t=0; t<NCHUNK; ++t){
    const size_t base = ((size_t)b*Sq + (size_t)t*Cq)*Hq;
    const size_t kcb  = (size_t)t*Cq*Hq;     // chunk offset inside khb/klb
    __syncthreads();   // BS: Sus(t-1) ready (and chunk handoff)

    // ---- issue alpha/eta row-63 loads (drain at BA, covered by GEMM1) ----
    float ab_=0.f, eb_=0.f;
    if (tid < 128){
      ab_ = alpha[base + 63*Hq + tid];
      eb_ = eta[base + 63*Hq + tid];
    }

    // ---- W1 + w2t + b1 update from chunk t-1 (reads Sus; all-VALU) ----
    if (t > 0){
      float4 s0[4], s1[4];
      #pragma unroll
      for (int ks=0;ks<4;ks++){
        s0[ks] = *(const float4*)&Sus[ks*32 + q*8];
        s1[ks] = *(const float4*)&Sus[ks*32 + q*8 + 4];
      }
      #pragma unroll
      for (int tt=0;tt<2;tt++){
        float amm = am_own[tt];
        float eam = ew*amm;
        float part = 0.f;
        #pragma unroll
        for (int ks=0;ks<4;ks++){
          #pragma unroll
          for (int j=0;j<4;j++){
            float su0 = s0[ks][j], su1 = s1[ks][j];
            w1m[tt][ks][j]   = aw*w1m[tt][ks][j]   - eam*su0;
            w1m[tt][ks][j+4] = aw*w1m[tt][ks][j+4] - eam*su1;
            float nw0 = aw*w2t[tt][ks][j]   - ew*su0*amm;
            float nw1 = aw*w2t[tt][ks][j+4] - ew*su1*amm;
            w2t[tt][ks][j] = nw0;  w2t[tt][ks][j+4] = nw1;
            part += su0*nw0 + su1*nw1;
          }
        }
        part += __shfl_xor(part, 16, 64);
        part += __shfl_xor(part, 32, 64);
        b1reg[tt] = aw*b1reg[tt] - ew*part;   // b1u = us . nW2[:,m]
      }
    }

    // ---- GEMM1: inter = kc @ W1^T; A-frags read DIRECTLY from global ----
    f32x4 acc1[2][4];
    #pragma unroll
    for (int tt=0;tt<2;tt++){
      #pragma unroll
      for (int ct=0;ct<4;ct++){ f32x4 z={0.f,0.f,0.f,0.f}; acc1[tt][ct]=z; }
    }
    __builtin_amdgcn_s_setprio(1);
    #pragma unroll
    for (int ks=0;ks<4;ks++){
      pk8 BH[2], BL[2];
      #pragma unroll
      for (int tt=0;tt<2;tt++){
        #pragma unroll
        for (int jp=0;jp<4;jp++){
          float a0 = w1m[tt][ks][2*jp], a1 = w1m[tt][ks][2*jp+1];
          unsigned hp = cvt_pk_bf16(a0, a1);
          BH[tt].u[jp] = hp;
          BL[tt].u[jp] = cvt_pk_bf16(a0 - lo16f(hp), a1 - hi16f(hp));
        }
      }
      #pragma unroll
      for (int ct=0;ct<4;ct++){
        size_t off = kcb + (size_t)(ct*16+n)*Hq + (ks*4+q)*8;
        short8 ah = *(const short8*)&khb[off];
        short8 al = *(const short8*)&klb[off];
        #pragma unroll
        for (int tt=0;tt<2;tt++){
          acc1[tt][ct] = __builtin_amdgcn_mfma_f32_16x16x32_bf16(ah, BH[tt].s, acc1[tt][ct], 0,0,0);
          acc1[tt][ct] = __builtin_amdgcn_mfma_f32_16x16x32_bf16(al, BH[tt].s, acc1[tt][ct], 0,0,0);
          acc1[tt][ct] = __builtin_amdgcn_mfma_f32_16x16x32_bf16(ah, BL[tt].s, acc1[tt][ct], 0,0,0);
        }
      }
    }
    __builtin_amdgcn_s_setprio(0);
    // gelu -> act_hi + am
    #pragma unroll
    for (int tt=0;tt<2;tt++){
      int m = (2*wv+tt)*16 + n;
      float b1v = b1reg[tt];
      float amsum = 0.f;
      #pragma unroll
      for (int ct=0;ct<4;ct++){
        #pragma unroll
        for (int r=0;r<4;r++){
          float g = gelu_fast(acc1[tt][ct][r] + b1v);
          amsum += g;
          int c = ct*16 + q*4 + r;
          int pg = (m>>3) ^ (c & 15);
          act_hi[c*Mq + (pg<<3) + (m&7)] = bf16rn(g);
        }
      }
      amsum += __shfl_xor(amsum, 16, 64);
      amsum += __shfl_xor(amsum, 32, 64);
      am_own[tt] = amsum*(1.f/64.f);
      if (q==0) Sam[m] = am_own[tt];
    }
    // publish alpha/eta
    if (tid < 128){ Sab[tid] = ab_; Seb[tid] = eb_; }
    if (wv < 2){
      float a2 = ab_, e2 = eb_;
      #pragma unroll
      for (int mk=1;mk<64;mk<<=1){ a2 += __shfl_xor(a2,mk,64); e2 += __shfl_xor(e2,mk,64); }
      if (lane==0){ Sabp[wv] = a2; Sebp[wv] = e2; }
    }
    __syncthreads();   // BA: act/Sam/Sab/Sabp ready

    // ---- issue v_c/delta float4 loads (drain at BP, covered by GEMM2) ----
    f32x4 vvv[4], ddd[4];
    #pragma unroll
    for (int ct=0;ct<4;ct++){
      size_t off = base + (size_t)(ct*16+n)*Hq + wv*16 + q*4;
      vvv[ct] = *(const f32x4*)&v_c[off];
      ddd[ct] = *(const f32x4*)&delta[off];
    }
    // ---- touch next chunk's khi/klo (L1/L2 warm; keepalive vs DCE) ----
    {
      size_t nb = (size_t)((t+1<NCHUNK)?(t+1):t)*Cq*Hq;
      short8 t0 = *(const short8*)&khb[nb + tid*8];
      short8 t1 = *(const short8*)&khb[nb + 4096 + tid*8];
      short8 t2 = *(const short8*)&klb[nb + tid*8];
      short8 t3 = *(const short8*)&klb[nb + 4096 + tid*8];
      asm volatile("" :: "v"((int)t0[0]), "v"((int)t1[0]), "v"((int)t2[0]), "v"((int)t3[0]));
    }

    // ---- GEMM2 (operand-swapped): out^T = W2 @ act^T -> out[h2][c] ----
    f32x4 acc2[4];
    #pragma unroll
    for (int ct=0;ct<4;ct++){ f32x4 z={0.f,0.f,0.f,0.f}; acc2[ct]=z; }
    __builtin_amdgcn_s_setprio(1);
    #pragma unroll
    for (int ks2=0;ks2<8;ks2++){
      pk8 BH, BL;
      #pragma unroll
      for (int jp=0;jp<4;jp++){
        float a0 = w2m[ks2][2*jp], a1 = w2m[ks2][2*jp+1];
        unsigned hp = cvt_pk_bf16(a0, a1);
        BH.u[jp] = hp;
        BL.u[jp] = cvt_pk_bf16(a0 - lo16f(hp), a1 - hi16f(hp));
      }
      #pragma unroll
      for (int ct=0;ct<4;ct++){
        int c = ct*16 + n;
        int off = c*Mq + ((((ks2*4+q)^n))<<3);
        short8 ah = *(const short8*)&act_hi[off];
        acc2[ct] = __builtin_amdgcn_mfma_f32_16x16x32_bf16(BH.s, ah, acc2[ct], 0,0,0);
        acc2[ct] = __builtin_amdgcn_mfma_f32_16x16x32_bf16(BL.s, ah, acc2[ct], 0,0,0);
      }
    }
    __builtin_amdgcn_s_setprio(0);

    // ---- epilogue: float4 out store, err, pen partials (2 shfl) ----
    float err[4][4];
    {
      float* cb = combined + base;
      #pragma unroll
      for (int ct=0;ct<4;ct++){
        int c = ct*16 + n;
        f32x4 ov;
        #pragma unroll
        for (int r=0;r<4;r++){
          float o = acc2[ct][r] + b2n[r];
          ov[r] = o;
          err[ct][r] = o - vvv[ct][r];
        }
        *(f32x4*)&cb[(size_t)c*Hq + wv*16 + q*4] = ov;
      }
      #pragma unroll
      for (int ct=0;ct<4;ct++){
        float s = err[ct][0]*err[ct][0] + err[ct][1]*err[ct][1]
                + err[ct][2]*err[ct][2] + err[ct][3]*err[ct][3];
        s += __shfl_xor(s, 16, 64);
        s += __shfl_xor(s, 32, 64);
        if (q==0) pen[(ct*16+n)*12 + wv] = s;
      }
    }
    __syncthreads();   // BP: pen ready

    aw = (Sabp[0]+Sabp[1])*(1.f/128.f);
    ew = (Sebp[0]+Sebp[1])*(1.f/128.f);

    // ---- en (direct pen reads) -> grad -> us (n-butterfly) ----
    float en_c[4];
    #pragma unroll
    for (int ct=0;ct<4;ct++){
      int c = ct*16 + n;
      float4 e0 = *(const float4*)&pen[c*12];
      float4 e1 = *(const float4*)&pen[c*12+4];
      en_c[ct] = sqrtf(e0.x+e0.y+e0.z+e0.w+e1.x+e1.y+e1.z+e1.w);
    }
    float us_r[4];
    #pragma unroll
    for (int r=0;r<4;r++){
      float s = 0.f;
      #pragma unroll
      for (int ct=0;ct<4;ct++){
        float e = err[ct][r];
        float dvv = ddd[ct][r];
        float en = en_c[ct];
        float g = (en > dvv) ? dvv*e*__builtin_amdgcn_rcpf(en+1e-9f) : e;
        s += g;
      }
      s += __shfl_xor(s,1,64); s += __shfl_xor(s,2,64);
      s += __shfl_xor(s,4,64); s += __shfl_xor(s,8,64);
      us_r[r] = s*(1.f/64.f);     // us[h2 = wv*16+q*4+r], replicated over n
    }
    if (n==0){
      #pragma unroll
      for (int r=0;r<4;r++) Sus[wv*16 + q*4 + r] = us_r[r];
    }
    // ---- b2 update (in-register, float4 Sab/Seb reads) ----
    {
      f32x4 sab = *(const f32x4*)&Sab[wv*16 + q*4];
      f32x4 seb = *(const f32x4*)&Seb[wv*16 + q*4];
      #pragma unroll
      for (int r=0;r<4;r++) b2n[r] = sab[r]*b2n[r] - seb[r]*us_r[r];
    }
    // ---- ush at W2-ownership lane (h = wv*16+n) via shfl pulls ----
    float ush;
    {
      int src = (n>>2)<<4;     // any lane in q-group n>>2 (us_r replicated over n)
      float p0 = __shfl(us_r[0], src, 64);
      float p1 = __shfl(us_r[1], src, 64);
      float p2 = __shfl(us_r[2], src, 64);
      float p3 = __shfl(us_r[3], src, 64);
      int rr = n&3;
      ush = (rr==0) ? p0 : (rr==1) ? p1 : (rr==2) ? p2 : p3;
    }
    // ---- W2m update (uses ush, Sam reads; consumed post-BA(t+1)) ----
    {
      float eus = ew*ush;
      #pragma unroll
      for (int ks2=0;ks2<8;ks2++){
        float4 a0 = *(const float4*)&Sam[ks2*32 + q*8];
        float4 a1 = *(const float4*)&Sam[ks2*32 + q*8 + 4];
        #pragma unroll
        for (int j=0;j<4;j++){
          w2m[ks2][j]   = aw*w2m[ks2][j]   - eus*a0[j];
          w2m[ks2][j+4] = aw*w2m[ks2][j+4] - eus*a1[j];
        }
      }
    }
    // W1 + w2t + b1 update deferred to top of chunk t+1 (after BS).
  }
}

extern "C" void kernel_launch(void* const* d_in, const int* in_sizes, int n_in,
                              void* d_out, int out_size, void* d_ws, size_t ws_size,
                              hipStream_t stream)
{
  const float* x    = (const float*)d_in[0];
  // d_in[1]=Wq, d_in[14],[15]=qn_g/qn_b: dead (q path unused by output).
  const float* Wk   = (const float*)d_in[2];
  const float* Wv   = (const float*)d_in[3];
  const float* Wo   = (const float*)d_in[4];
  const float* Wg   = (const float*)d_in[5];
  const float* We1  = (const float*)d_in[6];
  const float* We2  = (const float*)d_in[7];
  const float* Wd1  = (const float*)d_in[8];
  const float* Wd2  = (const float*)d_in[9];
  const float* Wa1  = (const float*)d_in[10];
  const float* Wa2  = (const float*)d_in[11];
  const float* conv_w = (const float*)d_in[12];
  const float* conv_b = (const float*)d_in[13];
  const float* kn_g = (const float*)d_in[16];
  const float* kn_b = (const float*)d_in[17];
  const float* mW1  = (const float*)d_in[18];
  const float* mb1  = (const float*)d_in[19];
  const float* mW2  = (const float*)d_in[20];
  const float* mb2  = (const float*)d_in[21];
  float* out = (float*)d_out;

  float* ws = (float*)d_ws;
  size_t o = 0;
  float* k_raw = ws + o; o += (size_t)BSq*Hq;
  float* v_raw = ws + o; o += (size_t)BSq*Hq;
  float* te    = ws + o; o += (size_t)BSq*Rq;
  float* td    = ws + o; o += (size_t)BSq*Rq;
  float* ta    = ws + o; o += (size_t)BSq*Rq;
  float* glog  = ws + o; o += (size_t)BSq*Dq;
  float* etab  = ws + o; o += (size_t)BSq*Hq;
  float* deltab= ws + o; o += (size_t)BSq*Hq;
  float* alphab= ws + o; o += (size_t)BSq*Hq;
  float* kslot = ws + o; o += (size_t)BSq*Hq;   // khi/klo bf16 planes (8MB slot)
  float* v_c   = ws + o; o += (size_t)BSq*Hq;
  float* comb  = ws + o; o += (size_t)BSq*Hq;
  unsigned short* usb = (unsigned short*)(ws + o);

  unsigned short* khi = (unsigned short*)kslot;
  unsigned short* klo = khi + (size_t)BSq*Hq;

  // xh/xl (bf16 planes of x, 32MB each) overlay glog (64MB): dead once the
  // projections complete; glog written later by the fused kernel.
  unsigned short* xh = (unsigned short*)glog;
  unsigned short* xl = xh + (size_t)BSq*Dq;

  // one-shot weight transpose+split (all 10 weights, 1 launch)
  {
    size_t total = 2*(size_t)Hq*Dq + 3*(size_t)Rq*Dq + (size_t)Dq*Dq
                 + 3*(size_t)Hq*Rq + (size_t)Dq*Hq;
    splitT_all<<<(unsigned)(total/256), 256, 0, stream>>>(
        Wk, Wv, We1, Wd1, Wa1, Wg, We2, Wd2, Wa2, Wo, usb);
  }
  splitX<<<(size_t)BSq*Dq/4/256, 256, 0, stream>>>(x, xh, xl);

  dim3 blk(256);
  // merged x-projections: [Wk|Wv] -> k_raw/v_raw ; [We1|Wd1|Wa1] -> te/td/ta
  gemm_bb<128><<<dim3(2, BSq/128), blk, 0, stream>>>(xh, xl, usb+U_WKVTH, usb+U_WKVTL, k_raw, v_raw, nullptr, Dq);
  gemm_bb<64> <<<dim3(3, BSq/128), blk, 0, stream>>>(xh, xl, usb+U_WEDATH, usb+U_WEDATL, te, td, ta, Dq);
  // merged second-stage R=64 GEMMs (eta/delta/alpha) -> 1 dispatch
  gemm_eda2<<<dim3(3, BSq/128), blk, 0, stream>>>(te, td, ta, usb, etab, deltab, alphab);
  conv_ln_kernel<<<dim3(Sq, Bq, 2), dim3(128), 0, stream>>>(
      k_raw, v_raw, conv_w, conv_b, kn_g, kn_b, khi, klo, v_c);
  // fused: scan (blocks 0..3) + Wg GEMM (blocks 4..1027) co-scheduled
  fused_scan_wg<<<dim3(4 + (BSq/128)*(Dq/128)), dim3(512), 0, stream>>>(
      khi, klo, v_c, etab, deltab, alphab, mW1, mb1, mW2, mb2, comb,
      x, usb+U_WGTH, usb+U_WGTL, glog);
  gemm_bf3<128,3><<<dim3(Dq/128, BSq/128), blk, 0, stream>>>(comb, usb+U_WOTH, usb+U_WOTL, out, glog, Dq, Hq);
}

// Round 6
// 1371.361 us; speedup vs baseline: 1.4652x; 1.4652x over previous
//
#include <hip/hip_runtime.h>
#include <math.h>

#define Bq 4
#define Sq 4096
#define Dq 1024
#define Hq 128
#define Mq 256
#define Rq 64
#define Cq 64
#define NCHUNK 64
#define BSq (Bq*Sq)

typedef __attribute__((ext_vector_type(8))) short short8;
typedef __attribute__((ext_vector_type(4))) float f32x4;
typedef __attribute__((ext_vector_type(2))) unsigned int uintx2;

// ---- packed-weight arena layout (elements of unsigned short) ----
#define U_WKVTH  ((size_t)0)
#define U_WKVTL  (U_WKVTH + (size_t)2*Hq*Dq)
#define U_WEDATH (U_WKVTL + (size_t)2*Hq*Dq)
#define U_WEDATL (U_WEDATH + (size_t)3*Rq*Dq)
#define U_WGTH   (U_WEDATL + (size_t)3*Rq*Dq)
#define U_WGTL   (U_WGTH + (size_t)Dq*Dq)
#define U_WE2TH  (U_WGTL + (size_t)Dq*Dq)
#define U_WE2TL  (U_WE2TH + (size_t)Hq*Rq)
#define U_WD2TH  (U_WE2TL + (size_t)Hq*Rq)
#define U_WD2TL  (U_WD2TH + (size_t)Hq*Rq)
#define U_WA2TH  (U_WD2TL + (size_t)Hq*Rq)
#define U_WA2TL  (U_WA2TH + (size_t)Hq*Rq)
#define U_WOTH   (U_WA2TL + (size_t)Hq*Rq)
#define U_WOTL   (U_WOTH + (size_t)Dq*Hq)
#define U_END    (U_WOTL + (size_t)Dq*Hq)

__device__ __forceinline__ float softplusf_(float x){
  return fmaxf(x,0.f) + log1pf(expf(-fabsf(x)));
}
__device__ __forceinline__ float sigmoidf_(float x){
  return 1.f/(1.f+__expf(-x));
}
__device__ __forceinline__ unsigned short bf16rn(float x){
  unsigned u = __float_as_uint(x);
  u += 0x7fffu + ((u>>16)&1u);
  return (unsigned short)(u>>16);
}
__device__ __forceinline__ float bf16tof(unsigned short s){
  return __uint_as_float(((unsigned)s)<<16);
}
// packed 2xf32 -> 2xbf16 in one instruction (RNE, matches bf16rn).
__device__ __forceinline__ unsigned cvt_pk_bf16(float a, float b){
  unsigned r;
  asm("v_cvt_pk_bf16_f32 %0, %1, %2" : "=v"(r) : "v"(a), "v"(b));
  return r;
}
__device__ __forceinline__ float lo16f(unsigned p){ return __uint_as_float(p<<16); }
__device__ __forceinline__ float hi16f(unsigned p){ return __uint_as_float(p & 0xffff0000u); }
union pk8 { unsigned u[4]; short8 s; };

// async global->LDS 16B copy: per-lane global src, wave-uniform LDS base
// (HW adds lane*16 to the LDS dest). C-style addrspace casts (CK pattern).
__device__ __forceinline__ void g2lds16(const unsigned short* g, void* lds){
  __builtin_amdgcn_global_load_lds(
      (const __attribute__((address_space(1))) unsigned int*)(const void*)g,
      (__attribute__((address_space(3))) unsigned int*)lds,
      16, 0, 0);
}

// branchless erf-gelu (A&S 7.1.26, |err|<=1.5e-7)
__device__ __forceinline__ float gelu_fast(float x){
  float z  = x*0.70710678118f;
  float az = fabsf(z);
  float t  = __builtin_amdgcn_rcpf(fmaf(0.3275911f, az, 1.f));
  float p  = fmaf(t, 1.061405429f, -1.453152027f);
  p = fmaf(t, p, 1.421413741f);
  p = fmaf(t, p, -0.284496736f);
  p = fmaf(t, p, 0.254829592f);
  p = p*t;
  float e  = __expf(-az*az);
  float er = copysignf(1.f - p*e, z);
  return 0.5f*x*(1.f + er);
}

// ---------------- bf16x3 MFMA GEMM, f32 A (cvt_pk staging) ----------------
template<int BN, int ACT>
__global__ __launch_bounds__(256) void gemm_bf3(
    const float* __restrict__ Af,
    const unsigned short* __restrict__ BhT, const unsigned short* __restrict__ BlT,
    float* __restrict__ C, const float* __restrict__ gate, int N, int K)
{
  constexpr int BM = 128;
  constexpr int PK = 40;
  constexpr int TN = BN/32;
  __shared__ __align__(16) unsigned short As[2][BM*PK];
  __shared__ __align__(16) unsigned short Bs[2][BN*PK];
  const int tid = threadIdx.x;
  const int bm = blockIdx.y*BM, bn = blockIdx.x*BN;
  const int wv = tid>>6, lane = tid&63;
  const int n16 = lane&15, q = lane>>4;
  const int wm = wv>>1, wn = wv&1;

  f32x4 acc[4][TN];
  #pragma unroll
  for (int i=0;i<4;i++){
    #pragma unroll
    for (int j=0;j<TN;j++){ f32x4 z={0.f,0.f,0.f,0.f}; acc[i][j]=z; }
  }
  for (int k0=0;k0<K;k0+=32){
    #pragma unroll
    for (int c0=0;c0<BM*8;c0+=256){
      int c = c0 + tid;
      int row = c>>3, kg = (c&7)*4;
      float4 v = *(const float4*)&Af[(size_t)(bm+row)*K + k0+kg];
      unsigned hp0 = cvt_pk_bf16(v.x, v.y), hp1 = cvt_pk_bf16(v.z, v.w);
      unsigned lp0 = cvt_pk_bf16(v.x-lo16f(hp0), v.y-hi16f(hp0));
      unsigned lp1 = cvt_pk_bf16(v.z-lo16f(hp1), v.w-hi16f(hp1));
      int off = row*PK+kg;
      uintx2 th = {hp0, hp1}, tl = {lp0, lp1};
      *(uintx2*)&As[0][off] = th;
      *(uintx2*)&As[1][off] = tl;
    }
    #pragma unroll
    for (int c0=0;c0<BN*4;c0+=256){
      int c = c0 + tid;
      int row = c>>2, kg = (c&3)*8;
      *(short8*)&Bs[0][row*PK+kg] = *(const short8*)&BhT[(size_t)(bn+row)*K + k0+kg];
      *(short8*)&Bs[1][row*PK+kg] = *(const short8*)&BlT[(size_t)(bn+row)*K + k0+kg];
    }
    __syncthreads();
    short8 a_h[4], a_l[4], b_h[TN], b_l[TN];
    #pragma unroll
    for (int i=0;i<4;i++){
      int r = wm*64 + i*16 + n16;
      a_h[i] = *(const short8*)&As[0][r*PK + q*8];
      a_l[i] = *(const short8*)&As[1][r*PK + q*8];
    }
    #pragma unroll
    for (int j=0;j<TN;j++){
      int r = wn*(BN/2) + j*16 + n16;
      b_h[j] = *(const short8*)&Bs[0][r*PK + q*8];
      b_l[j] = *(const short8*)&Bs[1][r*PK + q*8];
    }
    #pragma unroll
    for (int i=0;i<4;i++){
      #pragma unroll
      for (int j=0;j<TN;j++){
        acc[i][j] = __builtin_amdgcn_mfma_f32_16x16x32_bf16(a_h[i], b_h[j], acc[i][j], 0,0,0);
        acc[i][j] = __builtin_amdgcn_mfma_f32_16x16x32_bf16(a_l[i], b_h[j], acc[i][j], 0,0,0);
        acc[i][j] = __builtin_amdgcn_mfma_f32_16x16x32_bf16(a_h[i], b_l[j], acc[i][j], 0,0,0);
      }
    }
    __syncthreads();
  }
  #pragma unroll
  for (int i=0;i<4;i++){
    #pragma unroll
    for (int j=0;j<TN;j++){
      #pragma unroll
      for (int r=0;r<4;r++){
        int row = bm + wm*64 + i*16 + q*4 + r;
        int col = bn + wn*(BN/2) + j*16 + n16;
        float v = acc[i][j][r];
        if (ACT==1) v = softplusf_(v);
        else if (ACT==2) v = sigmoidf_(v);
        else if (ACT==3) v *= sigmoidf_(gate[(size_t)row*N+col]);
        C[(size_t)row*N+col] = v;
      }
    }
  }
}

// ---------------- bf16x3 MFMA GEMM, pre-split bf16 A (copy staging) --------
template<int BN>
__global__ __launch_bounds__(256) void gemm_bb(
    const unsigned short* __restrict__ Ah, const unsigned short* __restrict__ Al,
    const unsigned short* __restrict__ BhT, const unsigned short* __restrict__ BlT,
    float* __restrict__ C0, float* __restrict__ C1, float* __restrict__ C2, int K)
{
  constexpr int BM = 128;
  constexpr int PK = 40;
  constexpr int TN = BN/32;
  __shared__ __align__(16) unsigned short As[2][BM*PK];
  __shared__ __align__(16) unsigned short Bs[2][BN*PK];
  const int tid = threadIdx.x;
  const int bx = blockIdx.x;
  const int bm = blockIdx.y*BM;
  const int bnB = bx*BN;                   // row offset into packed B
  float* __restrict__ C = (bx==0) ? C0 : ((bx==1) ? C1 : C2);
  const int wv = tid>>6, lane = tid&63;
  const int n16 = lane&15, q = lane>>4;
  const int wm = wv>>1, wn = wv&1;

  f32x4 acc[4][TN];
  #pragma unroll
  for (int i=0;i<4;i++){
    #pragma unroll
    for (int j=0;j<TN;j++){ f32x4 z={0.f,0.f,0.f,0.f}; acc[i][j]=z; }
  }
  for (int k0=0;k0<K;k0+=32){
    #pragma unroll
    for (int c0=0;c0<BM*4;c0+=256){
      int c = c0 + tid;
      int row = c>>2, kg = (c&3)*8;
      *(short8*)&As[0][row*PK+kg] = *(const short8*)&Ah[(size_t)(bm+row)*K + k0+kg];
      *(short8*)&As[1][row*PK+kg] = *(const short8*)&Al[(size_t)(bm+row)*K + k0+kg];
    }
    #pragma unroll
    for (int c0=0;c0<BN*4;c0+=256){
      int c = c0 + tid;
      int row = c>>2, kg = (c&3)*8;
      *(short8*)&Bs[0][row*PK+kg] = *(const short8*)&BhT[(size_t)(bnB+row)*K + k0+kg];
      *(short8*)&Bs[1][row*PK+kg] = *(const short8*)&BlT[(size_t)(bnB+row)*K + k0+kg];
    }
    __syncthreads();
    short8 a_h[4], a_l[4], b_h[TN], b_l[TN];
    #pragma unroll
    for (int i=0;i<4;i++){
      int r = wm*64 + i*16 + n16;
      a_h[i] = *(const short8*)&As[0][r*PK + q*8];
      a_l[i] = *(const short8*)&As[1][r*PK + q*8];
    }
    #pragma unroll
    for (int j=0;j<TN;j++){
      int r = wn*(BN/2) + j*16 + n16;
      b_h[j] = *(const short8*)&Bs[0][r*PK + q*8];
      b_l[j] = *(const short8*)&Bs[1][r*PK + q*8];
    }
    #pragma unroll
    for (int i=0;i<4;i++){
      #pragma unroll
      for (int j=0;j<TN;j++){
        acc[i][j] = __builtin_amdgcn_mfma_f32_16x16x32_bf16(a_h[i], b_h[j], acc[i][j], 0,0,0);
        acc[i][j] = __builtin_amdgcn_mfma_f32_16x16x32_bf16(a_l[i], b_h[j], acc[i][j], 0,0,0);
        acc[i][j] = __builtin_amdgcn_mfma_f32_16x16x32_bf16(a_h[i], b_l[j], acc[i][j], 0,0,0);
      }
    }
    __syncthreads();
  }
  #pragma unroll
  for (int i=0;i<4;i++){
    #pragma unroll
    for (int j=0;j<TN;j++){
      #pragma unroll
      for (int r=0;r<4;r++){
        int row = bm + wm*64 + i*16 + q*4 + r;
        int col = wn*(BN/2) + j*16 + n16;
        C[(size_t)row*BN+col] = acc[i][j][r];
      }
    }
  }
}

// ---------------- merged second-stage R=64 GEMMs (eta/delta/alpha) --------
__global__ __launch_bounds__(256) void gemm_eda2(
    const float* __restrict__ te, const float* __restrict__ td, const float* __restrict__ ta,
    const unsigned short* __restrict__ usb,
    float* __restrict__ etab, float* __restrict__ deltab, float* __restrict__ alphab)
{
  constexpr int BM = 128, PK = 40, BN = 128, TN = 4, K = Rq, N = Hq;
  __shared__ __align__(16) unsigned short As[2][BM*PK];
  __shared__ __align__(16) unsigned short Bs[2][BN*PK];
  const int tid = threadIdx.x;
  const int bx = blockIdx.x;
  const int bm = blockIdx.y*BM;
  const float* __restrict__ Af = (bx==0) ? te : (bx==1) ? td : ta;
  const unsigned short* __restrict__ BhT = usb + ((bx==0) ? U_WE2TH : (bx==1) ? U_WD2TH : U_WA2TH);
  const unsigned short* __restrict__ BlT = usb + ((bx==0) ? U_WE2TL : (bx==1) ? U_WD2TL : U_WA2TL);
  float* __restrict__ C = (bx==0) ? etab : (bx==1) ? deltab : alphab;
  const int wv = tid>>6, lane = tid&63;
  const int n16 = lane&15, q = lane>>4;
  const int wm = wv>>1, wn = wv&1;

  f32x4 acc[4][TN];
  #pragma unroll
  for (int i=0;i<4;i++){
    #pragma unroll
    for (int j=0;j<TN;j++){ f32x4 z={0.f,0.f,0.f,0.f}; acc[i][j]=z; }
  }
  for (int k0=0;k0<K;k0+=32){
    #pragma unroll
    for (int c0=0;c0<BM*8;c0+=256){
      int c = c0 + tid;
      int row = c>>3, kg = (c&7)*4;
      float4 v = *(const float4*)&Af[(size_t)(bm+row)*K + k0+kg];
      unsigned hp0 = cvt_pk_bf16(v.x, v.y), hp1 = cvt_pk_bf16(v.z, v.w);
      unsigned lp0 = cvt_pk_bf16(v.x-lo16f(hp0), v.y-hi16f(hp0));
      unsigned lp1 = cvt_pk_bf16(v.z-lo16f(hp1), v.w-hi16f(hp1));
      int off = row*PK+kg;
      uintx2 th = {hp0, hp1}, tl = {lp0, lp1};
      *(uintx2*)&As[0][off] = th;
      *(uintx2*)&As[1][off] = tl;
    }
    #pragma unroll
    for (int c0=0;c0<BN*4;c0+=256){
      int c = c0 + tid;
      int row = c>>2, kg = (c&3)*8;
      *(short8*)&Bs[0][row*PK+kg] = *(const short8*)&BhT[(size_t)row*K + k0+kg];
      *(short8*)&Bs[1][row*PK+kg] = *(const short8*)&BlT[(size_t)row*K + k0+kg];
    }
    __syncthreads();
    short8 a_h[4], a_l[4], b_h[TN], b_l[TN];
    #pragma unroll
    for (int i=0;i<4;i++){
      int r = wm*64 + i*16 + n16;
      a_h[i] = *(const short8*)&As[0][r*PK + q*8];
      a_l[i] = *(const short8*)&As[1][r*PK + q*8];
    }
    #pragma unroll
    for (int j=0;j<TN;j++){
      int r = wn*(BN/2) + j*16 + n16;
      b_h[j] = *(const short8*)&Bs[0][r*PK + q*8];
      b_l[j] = *(const short8*)&Bs[1][r*PK + q*8];
    }
    #pragma unroll
    for (int i=0;i<4;i++){
      #pragma unroll
      for (int j=0;j<TN;j++){
        acc[i][j] = __builtin_amdgcn_mfma_f32_16x16x32_bf16(a_h[i], b_h[j], acc[i][j], 0,0,0);
        acc[i][j] = __builtin_amdgcn_mfma_f32_16x16x32_bf16(a_l[i], b_h[j], acc[i][j], 0,0,0);
        acc[i][j] = __builtin_amdgcn_mfma_f32_16x16x32_bf16(a_h[i], b_l[j], acc[i][j], 0,0,0);
      }
    }
    __syncthreads();
  }
  #pragma unroll
  for (int i=0;i<4;i++){
    #pragma unroll
    for (int j=0;j<TN;j++){
      #pragma unroll
      for (int r=0;r<4;r++){
        int row = bm + wm*64 + i*16 + q*4 + r;
        int col = wn*(BN/2) + j*16 + n16;
        float v = acc[i][j][r];
        v = (bx==2) ? sigmoidf_(v) : softplusf_(v);
        C[(size_t)row*N+col] = v;
      }
    }
  }
}

// ---------------- one-shot weight transpose+split (10 segments) ------------
__global__ __launch_bounds__(256) void splitT_all(
    const float* __restrict__ Wk,  const float* __restrict__ Wv,
    const float* __restrict__ We1, const float* __restrict__ Wd1,
    const float* __restrict__ Wa1, const float* __restrict__ Wg,
    const float* __restrict__ We2, const float* __restrict__ Wd2,
    const float* __restrict__ Wa2, const float* __restrict__ Wo,
    unsigned short* __restrict__ usb)
{
  size_t idx = (size_t)blockIdx.x*256 + threadIdx.x;
#define SEG(SRC, DH, DL, K_, N_) \
  { size_t sz = (size_t)(K_)*(N_); \
    if (idx < sz){ \
      int nn = (int)(idx/(K_)); int k = (int)(idx - (size_t)nn*(K_)); \
      float v = (SRC)[(size_t)k*(N_) + nn]; \
      unsigned short hh = bf16rn(v); \
      (DH)[idx] = hh; (DL)[idx] = bf16rn(v - bf16tof(hh)); \
      return; } \
    idx -= sz; }
  SEG(Wk,  usb+U_WKVTH,                    usb+U_WKVTL,                    Dq, Hq)
  SEG(Wv,  usb+U_WKVTH+(size_t)Hq*Dq,      usb+U_WKVTL+(size_t)Hq*Dq,      Dq, Hq)
  SEG(We1, usb+U_WEDATH,                   usb+U_WEDATL,                   Dq, Rq)
  SEG(Wd1, usb+U_WEDATH+(size_t)Rq*Dq,     usb+U_WEDATL+(size_t)Rq*Dq,     Dq, Rq)
  SEG(Wa1, usb+U_WEDATH+(size_t)2*Rq*Dq,   usb+U_WEDATL+(size_t)2*Rq*Dq,   Dq, Rq)
  SEG(Wg,  usb+U_WGTH,                     usb+U_WGTL,                     Dq, Dq)
  SEG(We2, usb+U_WE2TH,                    usb+U_WE2TL,                    Rq, Hq)
  SEG(Wd2, usb+U_WD2TH,                    usb+U_WD2TL,                    Rq, Hq)
  SEG(Wa2, usb+U_WA2TH,                    usb+U_WA2TL,                    Rq, Hq)
  SEG(Wo,  usb+U_WOTH,                     usb+U_WOTL,                     Hq, Dq)
#undef SEG
}

// row-major f32 [M][K] -> bf16 hi/lo planes (no transpose). 1 float4/thread.
__global__ __launch_bounds__(256) void splitX(const float* __restrict__ A,
    unsigned short* __restrict__ h, unsigned short* __restrict__ l)
{
  size_t idx = ((size_t)blockIdx.x*256 + threadIdx.x)*4;
  float4 v = *(const float4*)&A[idx];
  unsigned hp0 = cvt_pk_bf16(v.x, v.y), hp1 = cvt_pk_bf16(v.z, v.w);
  unsigned lp0 = cvt_pk_bf16(v.x-lo16f(hp0), v.y-hi16f(hp0));
  unsigned lp1 = cvt_pk_bf16(v.z-lo16f(hp1), v.w-hi16f(hp1));
  uintx2 th = {hp0, hp1}, tl = {lp0, lp1};
  *(uintx2*)&h[idx] = th;
  *(uintx2*)&l[idx] = tl;
}

// conv+LN for k: emits pre-split bf16 hi/lo planes (same split of the same
// f32 value -> GEMM1 inputs bit-identical to the old in-kernel split). v: f32.
__global__ __launch_bounds__(128) void conv_ln_kernel(
  const float* __restrict__ k_raw, const float* __restrict__ v_raw,
  const float* __restrict__ conv_w, const float* __restrict__ conv_b,
  const float* __restrict__ kn_g, const float* __restrict__ kn_b,
  unsigned short* __restrict__ khi, unsigned short* __restrict__ klo,
  float* __restrict__ v_out)
{
  int s = blockIdx.x, b = blockIdx.y, which = blockIdx.z;
  int h = threadIdx.x;
  const float* src = (which==0) ? k_raw : v_raw;
  float acc = conv_b[h];
  #pragma unroll
  for (int j=0;j<4;j++){
    int ss = s-3+j;
    if (ss>=0) acc += conv_w[h*4+j]*src[((size_t)b*Sq+ss)*Hq + h];
  }
  if (which==0){
    __shared__ float red[4];
    float sv = acc, s2 = acc*acc;
    #pragma unroll
    for (int off=32; off>0; off>>=1){
      sv += __shfl_down(sv, off, 64);
      s2 += __shfl_down(s2, off, 64);
    }
    if ((h&63)==0){ red[(h>>6)*2]=sv; red[(h>>6)*2+1]=s2; }
    __syncthreads();
    float mean = (red[0]+red[2])*(1.f/128.f);
    float var  = (red[1]+red[3])*(1.f/128.f) - mean*mean;
    float y = (acc-mean)*rsqrtf(var+1e-5f)*kn_g[h]+kn_b[h];
    unsigned short hh = bf16rn(y);
    size_t idx = ((size_t)b*Sq+s)*Hq + h;
    khi[idx] = hh;
    klo[idx] = bf16rn(y - bf16tof(hh));
  } else {
    v_out[((size_t)b*Sq+s)*Hq + h] = acc;
  }
}

// ---- LDS overlay offsets (bytes) for the fused kernel's scan branch ----
// (identical to round-4 layout; kc buffers now filled by global_load_lds)
#define OFF_KCH   0            // 64*128*2   = 16384
#define OFF_KCL   16384        // 16384
#define OFF_ACTH  32768        // 64*256*2   = 32768
#define OFF_SAM   65536        // 1024
#define OFF_SUS   66560        // 512
#define OFF_PEN   67072        // 64*12*4 = 3072
#define OFF_DRED  70144        // 8*256*4 = 8192
#define OFF_SUU   78336        // 32
#define OFF_SAB   78368        // 512
#define OFF_SEB   78880        // 512
#define OFF_SABP  79392        // 8
#define OFF_SEBP  79400        // 8
#define LDS_TOTAL 79408

// Fused kernel: blocks 0..3 = sequential scan (1 per batch);
// blocks 4.. = Wg GEMM tiles, co-scheduled on idle CUs.
// Scan schedule (3 barriers/chunk; __syncthreads drains vmcnt -> staging
// issued post-B2 lands by B3, consumed by GEMM1 of the NEXT chunk):
//   [vv/dd + ab/eb issue] -> B1 -> W1+b1 upd(t-1) -> GEMM1(kc LDS) -> gelu
//   -> publish -> B2 -> stage kc(t+1) via global_load_lds -> GEMM2
//   -> epilogue/pen -> B3 -> en/grad/us -> b2 -> butterfly d[m] -> W2 upd
__global__ __launch_bounds__(512, 2) void fused_scan_wg(
  const unsigned short* __restrict__ khi, const unsigned short* __restrict__ klo,
  const float* __restrict__ v_c,
  const float* __restrict__ eta, const float* __restrict__ delta,
  const float* __restrict__ alpha,
  const float* __restrict__ mW1, const float* __restrict__ mb1,
  const float* __restrict__ mW2, const float* __restrict__ mb2,
  float* __restrict__ combined,
  const float* __restrict__ x,
  const unsigned short* __restrict__ WgTh, const unsigned short* __restrict__ WgTl,
  float* __restrict__ glog)
{
  __shared__ __align__(16) char smem[LDS_TOTAL];
  const int blk = blockIdx.x;
  const int tid = threadIdx.x;
  const int wv = tid >> 6;
  const int lane = tid & 63;
  const int n = lane & 15;
  const int q = lane >> 4;

  if (blk >= 4){
    // ================= Wg GEMM branch (512 thr, 128x128 tile) =================
    unsigned short* As_h = (unsigned short*)smem;          // 128*40
    unsigned short* As_l = As_h + 128*40;
    unsigned short* Bs_h = As_l + 128*40;
    unsigned short* Bs_l = Bs_h + 128*40;
    const int g = blk - 4;
    const int bm = (g>>3)*128, bn = (g&7)*128;
    const int wm = wv&3, wn = wv>>2;
    f32x4 acc[2][4];
    #pragma unroll
    for (int i=0;i<2;i++){
      #pragma unroll
      for (int j=0;j<4;j++){ f32x4 z={0.f,0.f,0.f,0.f}; acc[i][j]=z; }
    }
    for (int k0=0;k0<Dq;k0+=32){
      #pragma unroll
      for (int r=0;r<2;r++){
        int idx = tid + 512*r;
        int row = idx>>3, kg = (idx&7)*4;
        float4 v = *(const float4*)&x[(size_t)(bm+row)*Dq + k0+kg];
        unsigned hp0 = cvt_pk_bf16(v.x, v.y), hp1 = cvt_pk_bf16(v.z, v.w);
        unsigned lp0 = cvt_pk_bf16(v.x-lo16f(hp0), v.y-hi16f(hp0));
        unsigned lp1 = cvt_pk_bf16(v.z-lo16f(hp1), v.w-hi16f(hp1));
        int off = row*40+kg;
        uintx2 th = {hp0, hp1}, tl = {lp0, lp1};
        *(uintx2*)&As_h[off] = th;
        *(uintx2*)&As_l[off] = tl;
      }
      {
        int row = tid>>2, kg = (tid&3)*8;
        *(short8*)&Bs_h[row*40+kg] = *(const short8*)&WgTh[(size_t)(bn+row)*Dq + k0+kg];
        *(short8*)&Bs_l[row*40+kg] = *(const short8*)&WgTl[(size_t)(bn+row)*Dq + k0+kg];
      }
      __syncthreads();
      short8 a_h[2], a_l[2], b_h[4], b_l[4];
      #pragma unroll
      for (int i=0;i<2;i++){
        int r = wm*32 + i*16 + n;
        a_h[i] = *(const short8*)&As_h[r*40 + q*8];
        a_l[i] = *(const short8*)&As_l[r*40 + q*8];
      }
      #pragma unroll
      for (int j=0;j<4;j++){
        int r = wn*64 + j*16 + n;
        b_h[j] = *(const short8*)&Bs_h[r*40 + q*8];
        b_l[j] = *(const short8*)&Bs_l[r*40 + q*8];
      }
      #pragma unroll
      for (int i=0;i<2;i++){
        #pragma unroll
        for (int j=0;j<4;j++){
          acc[i][j] = __builtin_amdgcn_mfma_f32_16x16x32_bf16(a_h[i], b_h[j], acc[i][j], 0,0,0);
          acc[i][j] = __builtin_amdgcn_mfma_f32_16x16x32_bf16(a_l[i], b_h[j], acc[i][j], 0,0,0);
          acc[i][j] = __builtin_amdgcn_mfma_f32_16x16x32_bf16(a_h[i], b_l[j], acc[i][j], 0,0,0);
        }
      }
      __syncthreads();
    }
    #pragma unroll
    for (int i=0;i<2;i++){
      #pragma unroll
      for (int j=0;j<4;j++){
        #pragma unroll
        for (int r=0;r<4;r++){
          int row = bm + wm*32 + i*16 + q*4 + r;
          int col = bn + wn*64 + j*16 + n;
          glog[(size_t)row*Dq+col] = acc[i][j][r];
        }
      }
    }
    return;
  }

  // ================= scan branch =================
  unsigned short* kc_hi  = (unsigned short*)(smem + OFF_KCH);
  unsigned short* kc_lo  = (unsigned short*)(smem + OFF_KCL);
  unsigned short* act_hi = (unsigned short*)(smem + OFF_ACTH);
  float* Sam = (float*)(smem + OFF_SAM);
  float* Sus = (float*)(smem + OFF_SUS);
  float* pen = (float*)(smem + OFF_PEN);   // [c][12] (8 wave partials)
  float* Dred= (float*)(smem + OFF_DRED);  // [wv][256] per-wave d = us.W2old partials
  float* Suu = (float*)(smem + OFF_SUU);   // [8]  per-wave us.us partials
  float* Sab = (float*)(smem + OFF_SAB);
  float* Seb = (float*)(smem + OFF_SEB);
  float* Sabp = (float*)(smem + OFF_SABP);
  float* Sebp = (float*)(smem + OFF_SEBP);

  const int b = blk;
  const int h = wv*16 + n;          // W2 row ownership (A-frag of swapped GEMM2)
  float w1m[2][4][8];   // W1[m=(2wv+tt)*16+n][h=ks*32+q*8+j]
  float w2m[8][8];      // W2[h=wv*16+n][m=ks2*32+q*8+j]
  float b1reg[2];       // b1[m=(2wv+tt)*16+n]
  float b2n[4];         // b2[h2=wv*16+q*4+r]  (swapped-GEMM2 output rows)
  #pragma unroll
  for (int tt=0;tt<2;tt++){
    int m = (2*wv+tt)*16 + n;
    #pragma unroll
    for (int ks=0;ks<4;ks++){
      const float* p = mW1 + (size_t)m*Hq + ks*32 + q*8;
      #pragma unroll
      for (int j=0;j<8;j++) w1m[tt][ks][j] = p[j];
    }
    b1reg[tt] = mb1[m];
  }
  {
    #pragma unroll
    for (int ks2=0;ks2<8;ks2++){
      const float* p = mW2 + (size_t)h*Mq + ks2*32 + q*8;
      #pragma unroll
      for (int j=0;j<8;j++) w2m[ks2][j] = p[j];
    }
    #pragma unroll
    for (int r=0;r<4;r++) b2n[r] = mb2[wv*16 + q*4 + r];
  }
  // cross-chunk carried scalars (chunk t-1 values, consumed at t's top)
  float aw = 0.f, ew = 0.f;
  float am_own[2] = {0.f, 0.f};

  const unsigned short* khb = khi + (size_t)b*Sq*Hq;
  const unsigned short* klb = klo + (size_t)b*Sq*Hq;

  // ---- async kc staging setup: pre-swizzled per-lane global offsets so the
  // linear global_load_lds write (base + lane*16) produces the swizzled LDS
  // image LDS[c*128 + pg*8 + e] = k[c][((pg^(c&15))<<3)+e].
  // Wave wv stages rows c in [wv*8, wv*8+8); issue i covers c-quad i.
  const int c0s = (wv*2+0)*4 + (lane>>4);
  const int c1s = (wv*2+1)*4 + (lane>>4);
  const int soff0 = c0s*Hq + ((((lane&15)^(c0s&15)))<<3);
  const int soff1 = c1s*Hq + ((((lane&15)^(c1s&15)))<<3);
  char* d_kh0 = smem + OFF_KCH + (wv*2+0)*1024;
  char* d_kh1 = smem + OFF_KCH + (wv*2+1)*1024;
  char* d_kl0 = smem + OFF_KCL + (wv*2+0)*1024;
  char* d_kl1 = smem + OFF_KCL + (wv*2+1)*1024;
  // prologue: stage chunk 0 (drains at B1 of t=0 via __syncthreads vmcnt(0))
  g2lds16(khb + soff0, d_kh0);
  g2lds16(khb + soff1, d_kh1);
  g2lds16(klb + soff0, d_kl0);
  g2lds16(klb + soff1, d_kl1);

  for (int t=0; t<NCHUNK; ++t){
    const size_t base = ((size_t)b*Sq + (size_t)t*Cq)*Hq;
    // ---- issue this chunk's v_c/delta float4 loads (consumed in epilogue) ----
    f32x4 vvv[4], ddd[4];
    #pragma unroll
    for (int ct=0;ct<4;ct++){
      size_t off = base + (size_t)(ct*16+n)*Hq + wv*16 + q*4;
      vvv[ct] = *(const f32x4*)&v_c[off];
      ddd[ct] = *(const f32x4*)&delta[off];
    }
    float ab_=0.f, eb_=0.f;
    if (tid < 128){
      ab_ = alpha[base + 63*Hq + tid];
      eb_ = eta[base + 63*Hq + tid];
    }
    __syncthreads();   // B1: kc(t) staged; orders prev-chunk Sus/Dred/Suu

    // ---- W1 + b1 update from chunk t-1 (reads Sus/Dred/Suu) ----
    if (t > 0){
      float4 s0[4], s1[4];
      #pragma unroll
      for (int ks=0;ks<4;ks++){
        s0[ks] = *(const float4*)&Sus[ks*32 + q*8];
        s1[ks] = *(const float4*)&Sus[ks*32 + q*8 + 4];
      }
      float4 u0 = *(const float4*)&Suu[0];
      float4 u1 = *(const float4*)&Suu[4];
      float uu = u0.x+u0.y+u0.z+u0.w+u1.x+u1.y+u1.z+u1.w;
      #pragma unroll
      for (int tt=0;tt<2;tt++){
        int m = (2*wv+tt)*16 + n;
        float amm = am_own[tt];
        float eam = ew*amm;
        #pragma unroll
        for (int ks=0;ks<4;ks++){
          #pragma unroll
          for (int j=0;j<4;j++){
            w1m[tt][ks][j]   = aw*w1m[tt][ks][j]   - eam*s0[ks][j];
            w1m[tt][ks][j+4] = aw*w1m[tt][ks][j+4] - eam*s1[ks][j];
          }
        }
        float dsum = 0.f;
        #pragma unroll
        for (int w8=0;w8<8;w8++) dsum += Dred[w8*256 + m];
        // b1u = us.nW2[:,m] = aw*dsum - ew*uu*am[m]
        b1reg[tt] = aw*b1reg[tt] - ew*(aw*dsum - ew*uu*amm);
      }
    }

    // ---- GEMM1: inter = kc @ W1^T (kc hi/lo from LDS, W1 hi/lo: 3-MFMA) ----
    f32x4 acc1[2][4];
    #pragma unroll
    for (int tt=0;tt<2;tt++){
      #pragma unroll
      for (int ct=0;ct<4;ct++){ f32x4 z={0.f,0.f,0.f,0.f}; acc1[tt][ct]=z; }
    }
    __builtin_amdgcn_s_setprio(1);
    #pragma unroll
    for (int ks=0;ks<4;ks++){
      pk8 BH[2], BL[2];
      #pragma unroll
      for (int tt=0;tt<2;tt++){
        #pragma unroll
        for (int jp=0;jp<4;jp++){
          float a0 = w1m[tt][ks][2*jp], a1 = w1m[tt][ks][2*jp+1];
          unsigned hp = cvt_pk_bf16(a0, a1);
          BH[tt].u[jp] = hp;
          BL[tt].u[jp] = cvt_pk_bf16(a0 - lo16f(hp), a1 - hi16f(hp));
        }
      }
      #pragma unroll
      for (int ct=0;ct<4;ct++){
        int c = ct*16 + n;
        int off = c*Hq + ((((ks*4+q)^n))<<3);
        short8 ah = *(const short8*)&kc_hi[off];
        short8 al = *(const short8*)&kc_lo[off];
        #pragma unroll
        for (int tt=0;tt<2;tt++){
          acc1[tt][ct] = __builtin_amdgcn_mfma_f32_16x16x32_bf16(ah, BH[tt].s, acc1[tt][ct], 0,0,0);
          acc1[tt][ct] = __builtin_amdgcn_mfma_f32_16x16x32_bf16(al, BH[tt].s, acc1[tt][ct], 0,0,0);
          acc1[tt][ct] = __builtin_amdgcn_mfma_f32_16x16x32_bf16(ah, BL[tt].s, acc1[tt][ct], 0,0,0);
        }
      }
    }
    __builtin_amdgcn_s_setprio(0);
    // gelu -> act_hi + am
    #pragma unroll
    for (int tt=0;tt<2;tt++){
      int m = (2*wv+tt)*16 + n;
      float b1v = b1reg[tt];
      float amsum = 0.f;
      #pragma unroll
      for (int ct=0;ct<4;ct++){
        #pragma unroll
        for (int r=0;r<4;r++){
          float g = gelu_fast(acc1[tt][ct][r] + b1v);
          amsum += g;
          int c = ct*16 + q*4 + r;
          int pg = (m>>3) ^ (c & 15);
          act_hi[c*Mq + (pg<<3) + (m&7)] = bf16rn(g);
        }
      }
      amsum += __shfl_xor(amsum, 16, 64);
      amsum += __shfl_xor(amsum, 32, 64);
      am_own[tt] = amsum*(1.f/64.f);
      if (q==0) Sam[m] = am_own[tt];
    }
    // publish alpha/eta
    if (tid < 128){ Sab[tid] = ab_; Seb[tid] = eb_; }
    if (wv < 2){
      float a2 = ab_, e2 = eb_;
      #pragma unroll
      for (int mk=1;mk<64;mk<<=1){ a2 += __shfl_xor(a2,mk,64); e2 += __shfl_xor(e2,mk,64); }
      if (lane==0){ Sabp[wv] = a2; Sebp[wv] = e2; }
    }
    __syncthreads();   // B2: act/Sam/Sab/Sabp ready; all GEMM1 kc reads done

    // ---- stage kc(t+1) into LDS (async; drains at B3 under GEMM2 cover) ----
    {
      const size_t nb = (size_t)((t+1<NCHUNK)?(t+1):t)*Cq*Hq;
      g2lds16(khb + nb + soff0, d_kh0);
      g2lds16(khb + nb + soff1, d_kh1);
      g2lds16(klb + nb + soff0, d_kl0);
      g2lds16(klb + nb + soff1, d_kl1);
    }

    // ---- GEMM2 (operand-swapped): out^T = W2 @ act^T -> out[h2][c] ----
    f32x4 acc2[4];
    #pragma unroll
    for (int ct=0;ct<4;ct++){ f32x4 z={0.f,0.f,0.f,0.f}; acc2[ct]=z; }
    __builtin_amdgcn_s_setprio(1);
    #pragma unroll
    for (int ks2=0;ks2<8;ks2++){
      pk8 BH, BL;
      #pragma unroll
      for (int jp=0;jp<4;jp++){
        float a0 = w2m[ks2][2*jp], a1 = w2m[ks2][2*jp+1];
        unsigned hp = cvt_pk_bf16(a0, a1);
        BH.u[jp] = hp;
        BL.u[jp] = cvt_pk_bf16(a0 - lo16f(hp), a1 - hi16f(hp));
      }
      #pragma unroll
      for (int ct=0;ct<4;ct++){
        int c = ct*16 + n;
        int off = c*Mq + ((((ks2*4+q)^n))<<3);
        short8 ah = *(const short8*)&act_hi[off];
        acc2[ct] = __builtin_amdgcn_mfma_f32_16x16x32_bf16(BH.s, ah, acc2[ct], 0,0,0);
        acc2[ct] = __builtin_amdgcn_mfma_f32_16x16x32_bf16(BL.s, ah, acc2[ct], 0,0,0);
      }
    }
    __builtin_amdgcn_s_setprio(0);

    // ---- epilogue: float4 out store, err, pen partials (2 shfl) ----
    float err[4][4];
    {
      float* cb = combined + base;
      #pragma unroll
      for (int ct=0;ct<4;ct++){
        int c = ct*16 + n;
        f32x4 ov;
        #pragma unroll
        for (int r=0;r<4;r++){
          float o = acc2[ct][r] + b2n[r];
          ov[r] = o;
          err[ct][r] = o - vvv[ct][r];
        }
        *(f32x4*)&cb[(size_t)c*Hq + wv*16 + q*4] = ov;
      }
      #pragma unroll
      for (int ct=0;ct<4;ct++){
        float s = err[ct][0]*err[ct][0] + err[ct][1]*err[ct][1]
                + err[ct][2]*err[ct][2] + err[ct][3]*err[ct][3];
        s += __shfl_xor(s, 16, 64);
        s += __shfl_xor(s, 32, 64);
        if (q==0) pen[(ct*16+n)*12 + wv] = s;
      }
    }
    __syncthreads();   // B3: pen ready; kc(t+1) staging drained (vmcnt(0))

    aw = (Sabp[0]+Sabp[1])*(1.f/128.f);
    ew = (Sebp[0]+Sebp[1])*(1.f/128.f);

    // ---- en (direct pen reads) -> grad -> us (n-butterfly) ----
    float en_c[4];
    #pragma unroll
    for (int ct=0;ct<4;ct++){
      int c = ct*16 + n;
      float4 e0 = *(const float4*)&pen[c*12];
      float4 e1 = *(const float4*)&pen[c*12+4];
      en_c[ct] = sqrtf(e0.x+e0.y+e0.z+e0.w+e1.x+e1.y+e1.z+e1.w);
    }
    float us_r[4];
    #pragma unroll
    for (int r=0;r<4;r++){
      float s = 0.f;
      #pragma unroll
      for (int ct=0;ct<4;ct++){
        float e = err[ct][r];
        float dvv = ddd[ct][r];
        float en = en_c[ct];
        float g = (en > dvv) ? dvv*e*__builtin_amdgcn_rcpf(en+1e-9f) : e;
        s += g;
      }
      s += __shfl_xor(s,1,64); s += __shfl_xor(s,2,64);
      s += __shfl_xor(s,4,64); s += __shfl_xor(s,8,64);
      us_r[r] = s*(1.f/64.f);     // us[h2 = wv*16+q*4+r], replicated over n
    }
    if (n==0){
      #pragma unroll
      for (int r=0;r<4;r++) Sus[wv*16 + q*4 + r] = us_r[r];
    }
    // uu partial over this wave's 16 h (sum over r in-thread, then over q)
    {
      float uun = us_r[0]*us_r[0] + us_r[1]*us_r[1]
                + us_r[2]*us_r[2] + us_r[3]*us_r[3];
      uun += __shfl_xor(uun, 16, 64);
      uun += __shfl_xor(uun, 32, 64);
      if (lane==0) Suu[wv] = uun;
    }
    // ---- b2 update (in-register, float4 Sab/Seb reads) ----
    {
      f32x4 sab = *(const f32x4*)&Sab[wv*16 + q*4];
      f32x4 seb = *(const f32x4*)&Seb[wv*16 + q*4];
      #pragma unroll
      for (int r=0;r<4;r++) b2n[r] = sab[r]*b2n[r] - seb[r]*us_r[r];
    }
    // ---- ush at W2-ownership lane (h = wv*16+n) via shfl pulls ----
    float ush;
    {
      int src = (n>>2)<<4;     // any lane in q-group n>>2 (us_r replicated over n)
      float p0 = __shfl(us_r[0], src, 64);
      float p1 = __shfl(us_r[1], src, 64);
      float p2 = __shfl(us_r[2], src, 64);
      float p3 = __shfl(us_r[3], src, 64);
      int rr = n&3;
      ush = (rr==0) ? p0 : (rr==1) ? p1 : (rr==2) ? p2 : p3;
    }

    // ---- d[m] = us . W2_old[:,m]: reduce-scatter butterfly over n ----
    {
      const bool bb0 = (n&1);
      float p1[8][4];
      #pragma unroll
      for (int k2=0;k2<8;k2++){
        #pragma unroll
        for (int l=0;l<4;l++){
          float mine = ush * (bb0 ? w2m[k2][l+4] : w2m[k2][l]);
          float oth  = ush * (bb0 ? w2m[k2][l]   : w2m[k2][l+4]);
          p1[k2][l] = mine + __shfl_xor(oth, 1, 64);
        }
      }
      const bool bb1 = (n>>1)&1;
      float p2[4][4];
      #pragma unroll
      for (int k2=0;k2<4;k2++){
        #pragma unroll
        for (int l=0;l<4;l++){
          float mine = bb1 ? p1[2*k2+1][l] : p1[2*k2][l];
          float oth  = bb1 ? p1[2*k2][l]   : p1[2*k2+1][l];
          p2[k2][l] = mine + __shfl_xor(oth, 2, 64);
        }
      }
      const bool bb2 = (n>>2)&1;
      float p3[2][4];
      #pragma unroll
      for (int k2=0;k2<2;k2++){
        #pragma unroll
        for (int l=0;l<4;l++){
          float mine = bb2 ? p2[2*k2+1][l] : p2[2*k2][l];
          float oth  = bb2 ? p2[2*k2][l]   : p2[2*k2+1][l];
          p3[k2][l] = mine + __shfl_xor(oth, 4, 64);
        }
      }
      const bool bb3 = (n>>3)&1;
      float4 p4;
      {
        float m0 = bb3 ? p3[1][0] : p3[0][0];
        float o0 = bb3 ? p3[0][0] : p3[1][0];
        p4.x = m0 + __shfl_xor(o0, 8, 64);
        float m1 = bb3 ? p3[1][1] : p3[0][1];
        float o1 = bb3 ? p3[0][1] : p3[1][1];
        p4.y = m1 + __shfl_xor(o1, 8, 64);
        float m2 = bb3 ? p3[1][2] : p3[0][2];
        float o2 = bb3 ? p3[0][2] : p3[1][2];
        p4.z = m2 + __shfl_xor(o2, 8, 64);
        float m3 = bb3 ? p3[1][3] : p3[0][3];
        float o3 = bb3 ? p3[0][3] : p3[1][3];
        p4.w = m3 + __shfl_xor(o3, 8, 64);
      }
      // lane owns 4 consecutive m: (n>>1)*32 + q*8 + (n&1)*4 + [0..3]
      int base_m = (n>>1)*32 + q*8 + (n&1)*4;
      *(float4*)&Dred[wv*256 + base_m] = p4;
    }

    // ---- W2 update (uses ush at h=wv*16+n, Sam reads; consumed by
    //      GEMM2(t+1) which is past B2(t+1) -> no extra barrier) ----
    {
      float eus = ew*ush;
      #pragma unroll
      for (int ks2=0;ks2<8;ks2++){
        float4 a0 = *(const float4*)&Sam[ks2*32 + q*8];
        float4 a1 = *(const float4*)&Sam[ks2*32 + q*8 + 4];
        #pragma unroll
        for (int j=0;j<4;j++){
          w2m[ks2][j]   = aw*w2m[ks2][j]   - eus*a0[j];
          w2m[ks2][j+4] = aw*w2m[ks2][j+4] - eus*a1[j];
        }
      }
    }
    // W1 + b1 update deferred to top of chunk t+1 (after B1).
  }
}

extern "C" void kernel_launch(void* const* d_in, const int* in_sizes, int n_in,
                              void* d_out, int out_size, void* d_ws, size_t ws_size,
                              hipStream_t stream)
{
  const float* x    = (const float*)d_in[0];
  // d_in[1]=Wq, d_in[14],[15]=qn_g/qn_b: dead (q path unused by output).
  const float* Wk   = (const float*)d_in[2];
  const float* Wv   = (const float*)d_in[3];
  const float* Wo   = (const float*)d_in[4];
  const float* Wg   = (const float*)d_in[5];
  const float* We1  = (const float*)d_in[6];
  const float* We2  = (const float*)d_in[7];
  const float* Wd1  = (const float*)d_in[8];
  const float* Wd2  = (const float*)d_in[9];
  const float* Wa1  = (const float*)d_in[10];
  const float* Wa2  = (const float*)d_in[11];
  const float* conv_w = (const float*)d_in[12];
  const float* conv_b = (const float*)d_in[13];
  const float* kn_g = (const float*)d_in[16];
  const float* kn_b = (const float*)d_in[17];
  const float* mW1  = (const float*)d_in[18];
  const float* mb1  = (const float*)d_in[19];
  const float* mW2  = (const float*)d_in[20];
  const float* mb2  = (const float*)d_in[21];
  float* out = (float*)d_out;

  float* ws = (float*)d_ws;
  size_t o = 0;
  float* k_raw = ws + o; o += (size_t)BSq*Hq;
  float* v_raw = ws + o; o += (size_t)BSq*Hq;
  float* te    = ws + o; o += (size_t)BSq*Rq;
  float* td    = ws + o; o += (size_t)BSq*Rq;
  float* ta    = ws + o; o += (size_t)BSq*Rq;
  float* glog  = ws + o; o += (size_t)BSq*Dq;
  float* etab  = ws + o; o += (size_t)BSq*Hq;
  float* deltab= ws + o; o += (size_t)BSq*Hq;
  float* alphab= ws + o; o += (size_t)BSq*Hq;
  float* kslot = ws + o; o += (size_t)BSq*Hq;   // khi/klo bf16 planes (8MB slot)
  float* v_c   = ws + o; o += (size_t)BSq*Hq;
  float* comb  = ws + o; o += (size_t)BSq*Hq;
  unsigned short* usb = (unsigned short*)(ws + o);

  unsigned short* khi = (unsigned short*)kslot;
  unsigned short* klo = khi + (size_t)BSq*Hq;

  // xh/xl (bf16 planes of x, 32MB each) overlay glog (64MB): dead once the
  // projections complete; glog written later by the fused kernel.
  unsigned short* xh = (unsigned short*)glog;
  unsigned short* xl = xh + (size_t)BSq*Dq;

  // one-shot weight transpose+split (all 10 weights, 1 launch)
  {
    size_t total = 2*(size_t)Hq*Dq + 3*(size_t)Rq*Dq + (size_t)Dq*Dq
                 + 3*(size_t)Hq*Rq + (size_t)Dq*Hq;
    splitT_all<<<(unsigned)(total/256), 256, 0, stream>>>(
        Wk, Wv, We1, Wd1, Wa1, Wg, We2, Wd2, Wa2, Wo, usb);
  }
  splitX<<<(size_t)BSq*Dq/4/256, 256, 0, stream>>>(x, xh, xl);

  dim3 blk(256);
  // merged x-projections: [Wk|Wv] -> k_raw/v_raw ; [We1|Wd1|Wa1] -> te/td/ta
  gemm_bb<128><<<dim3(2, BSq/128), blk, 0, stream>>>(xh, xl, usb+U_WKVTH, usb+U_WKVTL, k_raw, v_raw, nullptr, Dq);
  gemm_bb<64> <<<dim3(3, BSq/128), blk, 0, stream>>>(xh, xl, usb+U_WEDATH, usb+U_WEDATL, te, td, ta, Dq);
  // merged second-stage R=64 GEMMs (eta/delta/alpha) -> 1 dispatch
  gemm_eda2<<<dim3(3, BSq/128), blk, 0, stream>>>(te, td, ta, usb, etab, deltab, alphab);
  conv_ln_kernel<<<dim3(Sq, Bq, 2), dim3(128), 0, stream>>>(
      k_raw, v_raw, conv_w, conv_b, kn_g, kn_b, khi, klo, v_c);
  // fused: scan (blocks 0..3) + Wg GEMM (blocks 4..1027) co-scheduled
  fused_scan_wg<<<dim3(4 + (BSq/128)*(Dq/128)), dim3(512), 0, stream>>>(
      khi, klo, v_c, etab, deltab, alphab, mW1, mb1, mW2, mb2, comb,
      x, usb+U_WGTH, usb+U_WGTL, glog);
  gemm_bf3<128,3><<<dim3(Dq/128, BSq/128), blk, 0, stream>>>(comb, usb+U_WOTH, usb+U_WOTL, out, glog, Dq, Hq);
}

// Round 7
// 1215.513 us; speedup vs baseline: 1.6531x; 1.1282x over previous
//
#include <hip/hip_runtime.h>
#include <math.h>

#define Bq 4
#define Sq 4096
#define Dq 1024
#define Hq 128
#define Mq 256
#define Rq 64
#define Cq 64
#define NCHUNK 64
#define BSq (Bq*Sq)

typedef __attribute__((ext_vector_type(8))) short short8;
typedef __attribute__((ext_vector_type(4))) float f32x4;
typedef __attribute__((ext_vector_type(2))) unsigned int uintx2;

// ---- packed-weight arena layout (elements of unsigned short) ----
#define U_WKVTH  ((size_t)0)
#define U_WKVTL  (U_WKVTH + (size_t)2*Hq*Dq)
#define U_WEDATH (U_WKVTL + (size_t)2*Hq*Dq)
#define U_WEDATL (U_WEDATH + (size_t)3*Rq*Dq)
#define U_WGTH   (U_WEDATL + (size_t)3*Rq*Dq)
#define U_WGTL   (U_WGTH + (size_t)Dq*Dq)
#define U_WE2TH  (U_WGTL + (size_t)Dq*Dq)
#define U_WE2TL  (U_WE2TH + (size_t)Hq*Rq)
#define U_WD2TH  (U_WE2TL + (size_t)Hq*Rq)
#define U_WD2TL  (U_WD2TH + (size_t)Hq*Rq)
#define U_WA2TH  (U_WD2TL + (size_t)Hq*Rq)
#define U_WA2TL  (U_WA2TH + (size_t)Hq*Rq)
#define U_WOTH   (U_WA2TL + (size_t)Hq*Rq)
#define U_WOTL   (U_WOTH + (size_t)Dq*Hq)
#define U_END    (U_WOTL + (size_t)Dq*Hq)

__device__ __forceinline__ float softplusf_(float x){
  return fmaxf(x,0.f) + log1pf(expf(-fabsf(x)));
}
__device__ __forceinline__ float sigmoidf_(float x){
  return 1.f/(1.f+__expf(-x));
}
__device__ __forceinline__ unsigned short bf16rn(float x){
  unsigned u = __float_as_uint(x);
  u += 0x7fffu + ((u>>16)&1u);
  return (unsigned short)(u>>16);
}
__device__ __forceinline__ float bf16tof(unsigned short s){
  return __uint_as_float(((unsigned)s)<<16);
}
// packed 2xf32 -> 2xbf16 in one instruction (RNE, matches bf16rn).
__device__ __forceinline__ unsigned cvt_pk_bf16(float a, float b){
  unsigned r;
  asm("v_cvt_pk_bf16_f32 %0, %1, %2" : "=v"(r) : "v"(a), "v"(b));
  return r;
}
__device__ __forceinline__ float lo16f(unsigned p){ return __uint_as_float(p<<16); }
__device__ __forceinline__ float hi16f(unsigned p){ return __uint_as_float(p & 0xffff0000u); }
union pk8 { unsigned u[4]; short8 s; };

// async global->LDS 16B copy: per-lane global src, wave-uniform LDS base
// (HW adds lane*16 to the LDS dest). C-style addrspace casts (CK pattern).
__device__ __forceinline__ void g2lds16(const unsigned short* g, void* lds){
  __builtin_amdgcn_global_load_lds(
      (const __attribute__((address_space(1))) unsigned int*)(const void*)g,
      (__attribute__((address_space(3))) unsigned int*)lds,
      16, 0, 0);
}

// branchless erf-gelu (A&S 7.1.26, |err|<=1.5e-7)
__device__ __forceinline__ float gelu_fast(float x){
  float z  = x*0.70710678118f;
  float az = fabsf(z);
  float t  = __builtin_amdgcn_rcpf(fmaf(0.3275911f, az, 1.f));
  float p  = fmaf(t, 1.061405429f, -1.453152027f);
  p = fmaf(t, p, 1.421413741f);
  p = fmaf(t, p, -0.284496736f);
  p = fmaf(t, p, 0.254829592f);
  p = p*t;
  float e  = __expf(-az*az);
  float er = copysignf(1.f - p*e, z);
  return 0.5f*x*(1.f + er);
}

// ---------------- bf16x3 MFMA GEMM, f32 A (cvt_pk staging) ----------------
template<int BN, int ACT>
__global__ __launch_bounds__(256) void gemm_bf3(
    const float* __restrict__ Af,
    const unsigned short* __restrict__ BhT, const unsigned short* __restrict__ BlT,
    float* __restrict__ C, const float* __restrict__ gate, int N, int K)
{
  constexpr int BM = 128;
  constexpr int PK = 40;
  constexpr int TN = BN/32;
  __shared__ __align__(16) unsigned short As[2][BM*PK];
  __shared__ __align__(16) unsigned short Bs[2][BN*PK];
  const int tid = threadIdx.x;
  const int bm = blockIdx.y*BM, bn = blockIdx.x*BN;
  const int wv = tid>>6, lane = tid&63;
  const int n16 = lane&15, q = lane>>4;
  const int wm = wv>>1, wn = wv&1;

  f32x4 acc[4][TN];
  #pragma unroll
  for (int i=0;i<4;i++){
    #pragma unroll
    for (int j=0;j<TN;j++){ f32x4 z={0.f,0.f,0.f,0.f}; acc[i][j]=z; }
  }
  for (int k0=0;k0<K;k0+=32){
    #pragma unroll
    for (int c0=0;c0<BM*8;c0+=256){
      int c = c0 + tid;
      int row = c>>3, kg = (c&7)*4;
      float4 v = *(const float4*)&Af[(size_t)(bm+row)*K + k0+kg];
      unsigned hp0 = cvt_pk_bf16(v.x, v.y), hp1 = cvt_pk_bf16(v.z, v.w);
      unsigned lp0 = cvt_pk_bf16(v.x-lo16f(hp0), v.y-hi16f(hp0));
      unsigned lp1 = cvt_pk_bf16(v.z-lo16f(hp1), v.w-hi16f(hp1));
      int off = row*PK+kg;
      uintx2 th = {hp0, hp1}, tl = {lp0, lp1};
      *(uintx2*)&As[0][off] = th;
      *(uintx2*)&As[1][off] = tl;
    }
    #pragma unroll
    for (int c0=0;c0<BN*4;c0+=256){
      int c = c0 + tid;
      int row = c>>2, kg = (c&3)*8;
      *(short8*)&Bs[0][row*PK+kg] = *(const short8*)&BhT[(size_t)(bn+row)*K + k0+kg];
      *(short8*)&Bs[1][row*PK+kg] = *(const short8*)&BlT[(size_t)(bn+row)*K + k0+kg];
    }
    __syncthreads();
    short8 a_h[4], a_l[4], b_h[TN], b_l[TN];
    #pragma unroll
    for (int i=0;i<4;i++){
      int r = wm*64 + i*16 + n16;
      a_h[i] = *(const short8*)&As[0][r*PK + q*8];
      a_l[i] = *(const short8*)&As[1][r*PK + q*8];
    }
    #pragma unroll
    for (int j=0;j<TN;j++){
      int r = wn*(BN/2) + j*16 + n16;
      b_h[j] = *(const short8*)&Bs[0][r*PK + q*8];
      b_l[j] = *(const short8*)&Bs[1][r*PK + q*8];
    }
    #pragma unroll
    for (int i=0;i<4;i++){
      #pragma unroll
      for (int j=0;j<TN;j++){
        acc[i][j] = __builtin_amdgcn_mfma_f32_16x16x32_bf16(a_h[i], b_h[j], acc[i][j], 0,0,0);
        acc[i][j] = __builtin_amdgcn_mfma_f32_16x16x32_bf16(a_l[i], b_h[j], acc[i][j], 0,0,0);
        acc[i][j] = __builtin_amdgcn_mfma_f32_16x16x32_bf16(a_h[i], b_l[j], acc[i][j], 0,0,0);
      }
    }
    __syncthreads();
  }
  #pragma unroll
  for (int i=0;i<4;i++){
    #pragma unroll
    for (int j=0;j<TN;j++){
      #pragma unroll
      for (int r=0;r<4;r++){
        int row = bm + wm*64 + i*16 + q*4 + r;
        int col = bn + wn*(BN/2) + j*16 + n16;
        float v = acc[i][j][r];
        if (ACT==1) v = softplusf_(v);
        else if (ACT==2) v = sigmoidf_(v);
        else if (ACT==3) v *= sigmoidf_(gate[(size_t)row*N+col]);
        C[(size_t)row*N+col] = v;
      }
    }
  }
}

// ---------------- bf16x3 MFMA GEMM, pre-split bf16 A, BM=64 tiles ---------
// BM=64 doubles the block count vs the old BM=128 (2+ blocks/CU -> 2+
// waves/SIMD latency hiding; these kernels were at exactly 1 wave/SIMD).
template<int BN>
__global__ __launch_bounds__(256) void gemm_bb(
    const unsigned short* __restrict__ Ah, const unsigned short* __restrict__ Al,
    const unsigned short* __restrict__ BhT, const unsigned short* __restrict__ BlT,
    float* __restrict__ C0, float* __restrict__ C1, float* __restrict__ C2, int K)
{
  constexpr int BM = 64;
  constexpr int PK = 40;
  constexpr int TN = BN/32;
  __shared__ __align__(16) unsigned short As[2][BM*PK];
  __shared__ __align__(16) unsigned short Bs[2][BN*PK];
  const int tid = threadIdx.x;
  const int bx = blockIdx.x;
  const int bm = blockIdx.y*BM;
  const int bnB = bx*BN;                   // row offset into packed B
  float* __restrict__ C = (bx==0) ? C0 : ((bx==1) ? C1 : C2);
  const int wv = tid>>6, lane = tid&63;
  const int n16 = lane&15, q = lane>>4;
  const int wm = wv>>1, wn = wv&1;

  f32x4 acc[2][TN];
  #pragma unroll
  for (int i=0;i<2;i++){
    #pragma unroll
    for (int j=0;j<TN;j++){ f32x4 z={0.f,0.f,0.f,0.f}; acc[i][j]=z; }
  }
  for (int k0=0;k0<K;k0+=32){
    {
      int row = tid>>2, kg = (tid&3)*8;
      *(short8*)&As[0][row*PK+kg] = *(const short8*)&Ah[(size_t)(bm+row)*K + k0+kg];
      *(short8*)&As[1][row*PK+kg] = *(const short8*)&Al[(size_t)(bm+row)*K + k0+kg];
    }
    #pragma unroll
    for (int c0=0;c0<BN*4;c0+=256){
      int c = c0 + tid;
      int row = c>>2, kg = (c&3)*8;
      *(short8*)&Bs[0][row*PK+kg] = *(const short8*)&BhT[(size_t)(bnB+row)*K + k0+kg];
      *(short8*)&Bs[1][row*PK+kg] = *(const short8*)&BlT[(size_t)(bnB+row)*K + k0+kg];
    }
    __syncthreads();
    short8 a_h[2], a_l[2], b_h[TN], b_l[TN];
    #pragma unroll
    for (int i=0;i<2;i++){
      int r = wm*32 + i*16 + n16;
      a_h[i] = *(const short8*)&As[0][r*PK + q*8];
      a_l[i] = *(const short8*)&As[1][r*PK + q*8];
    }
    #pragma unroll
    for (int j=0;j<TN;j++){
      int r = wn*(BN/2) + j*16 + n16;
      b_h[j] = *(const short8*)&Bs[0][r*PK + q*8];
      b_l[j] = *(const short8*)&Bs[1][r*PK + q*8];
    }
    #pragma unroll
    for (int i=0;i<2;i++){
      #pragma unroll
      for (int j=0;j<TN;j++){
        acc[i][j] = __builtin_amdgcn_mfma_f32_16x16x32_bf16(a_h[i], b_h[j], acc[i][j], 0,0,0);
        acc[i][j] = __builtin_amdgcn_mfma_f32_16x16x32_bf16(a_l[i], b_h[j], acc[i][j], 0,0,0);
        acc[i][j] = __builtin_amdgcn_mfma_f32_16x16x32_bf16(a_h[i], b_l[j], acc[i][j], 0,0,0);
      }
    }
    __syncthreads();
  }
  #pragma unroll
  for (int i=0;i<2;i++){
    #pragma unroll
    for (int j=0;j<TN;j++){
      #pragma unroll
      for (int r=0;r<4;r++){
        int row = bm + wm*32 + i*16 + q*4 + r;
        int col = wn*(BN/2) + j*16 + n16;
        C[(size_t)row*BN+col] = acc[i][j][r];
      }
    }
  }
}

// ---------------- merged second-stage R=64 GEMMs, BM=64 tiles -------------
__global__ __launch_bounds__(256) void gemm_eda2(
    const float* __restrict__ te, const float* __restrict__ td, const float* __restrict__ ta,
    const unsigned short* __restrict__ usb,
    float* __restrict__ etab, float* __restrict__ deltab, float* __restrict__ alphab)
{
  constexpr int BM = 64, PK = 40, BN = 128, TN = 4, K = Rq, N = Hq;
  __shared__ __align__(16) unsigned short As[2][BM*PK];
  __shared__ __align__(16) unsigned short Bs[2][BN*PK];
  const int tid = threadIdx.x;
  const int bx = blockIdx.x;
  const int bm = blockIdx.y*BM;
  const float* __restrict__ Af = (bx==0) ? te : (bx==1) ? td : ta;
  const unsigned short* __restrict__ BhT = usb + ((bx==0) ? U_WE2TH : (bx==1) ? U_WD2TH : U_WA2TH);
  const unsigned short* __restrict__ BlT = usb + ((bx==0) ? U_WE2TL : (bx==1) ? U_WD2TL : U_WA2TL);
  float* __restrict__ C = (bx==0) ? etab : (bx==1) ? deltab : alphab;
  const int wv = tid>>6, lane = tid&63;
  const int n16 = lane&15, q = lane>>4;
  const int wm = wv>>1, wn = wv&1;

  f32x4 acc[2][TN];
  #pragma unroll
  for (int i=0;i<2;i++){
    #pragma unroll
    for (int j=0;j<TN;j++){ f32x4 z={0.f,0.f,0.f,0.f}; acc[i][j]=z; }
  }
  for (int k0=0;k0<K;k0+=32){
    #pragma unroll
    for (int c0=0;c0<BM*8;c0+=256){
      int c = c0 + tid;
      int row = c>>3, kg = (c&7)*4;
      float4 v = *(const float4*)&Af[(size_t)(bm+row)*K + k0+kg];
      unsigned hp0 = cvt_pk_bf16(v.x, v.y), hp1 = cvt_pk_bf16(v.z, v.w);
      unsigned lp0 = cvt_pk_bf16(v.x-lo16f(hp0), v.y-hi16f(hp0));
      unsigned lp1 = cvt_pk_bf16(v.z-lo16f(hp1), v.w-hi16f(hp1));
      int off = row*PK+kg;
      uintx2 th = {hp0, hp1}, tl = {lp0, lp1};
      *(uintx2*)&As[0][off] = th;
      *(uintx2*)&As[1][off] = tl;
    }
    #pragma unroll
    for (int c0=0;c0<BN*4;c0+=256){
      int c = c0 + tid;
      int row = c>>2, kg = (c&3)*8;
      *(short8*)&Bs[0][row*PK+kg] = *(const short8*)&BhT[(size_t)row*K + k0+kg];
      *(short8*)&Bs[1][row*PK+kg] = *(const short8*)&BlT[(size_t)row*K + k0+kg];
    }
    __syncthreads();
    short8 a_h[2], a_l[2], b_h[TN], b_l[TN];
    #pragma unroll
    for (int i=0;i<2;i++){
      int r = wm*32 + i*16 + n16;
      a_h[i] = *(const short8*)&As[0][r*PK + q*8];
      a_l[i] = *(const short8*)&As[1][r*PK + q*8];
    }
    #pragma unroll
    for (int j=0;j<TN;j++){
      int r = wn*(BN/2) + j*16 + n16;
      b_h[j] = *(const short8*)&Bs[0][r*PK + q*8];
      b_l[j] = *(const short8*)&Bs[1][r*PK + q*8];
    }
    #pragma unroll
    for (int i=0;i<2;i++){
      #pragma unroll
      for (int j=0;j<TN;j++){
        acc[i][j] = __builtin_amdgcn_mfma_f32_16x16x32_bf16(a_h[i], b_h[j], acc[i][j], 0,0,0);
        acc[i][j] = __builtin_amdgcn_mfma_f32_16x16x32_bf16(a_l[i], b_h[j], acc[i][j], 0,0,0);
        acc[i][j] = __builtin_amdgcn_mfma_f32_16x16x32_bf16(a_h[i], b_l[j], acc[i][j], 0,0,0);
      }
    }
    __syncthreads();
  }
  #pragma unroll
  for (int i=0;i<2;i++){
    #pragma unroll
    for (int j=0;j<TN;j++){
      #pragma unroll
      for (int r=0;r<4;r++){
        int row = bm + wm*32 + i*16 + q*4 + r;
        int col = wn*(BN/2) + j*16 + n16;
        float v = acc[i][j][r];
        v = (bx==2) ? sigmoidf_(v) : softplusf_(v);
        C[(size_t)row*N+col] = v;
      }
    }
  }
}

// ---------------- one-shot weight transpose+split (10 segments) ------------
__global__ __launch_bounds__(256) void splitT_all(
    const float* __restrict__ Wk,  const float* __restrict__ Wv,
    const float* __restrict__ We1, const float* __restrict__ Wd1,
    const float* __restrict__ Wa1, const float* __restrict__ Wg,
    const float* __restrict__ We2, const float* __restrict__ Wd2,
    const float* __restrict__ Wa2, const float* __restrict__ Wo,
    unsigned short* __restrict__ usb)
{
  size_t idx = (size_t)blockIdx.x*256 + threadIdx.x;
#define SEG(SRC, DH, DL, K_, N_) \
  { size_t sz = (size_t)(K_)*(N_); \
    if (idx < sz){ \
      int nn = (int)(idx/(K_)); int k = (int)(idx - (size_t)nn*(K_)); \
      float v = (SRC)[(size_t)k*(N_) + nn]; \
      unsigned short hh = bf16rn(v); \
      (DH)[idx] = hh; (DL)[idx] = bf16rn(v - bf16tof(hh)); \
      return; } \
    idx -= sz; }
  SEG(Wk,  usb+U_WKVTH,                    usb+U_WKVTL,                    Dq, Hq)
  SEG(Wv,  usb+U_WKVTH+(size_t)Hq*Dq,      usb+U_WKVTL+(size_t)Hq*Dq,      Dq, Hq)
  SEG(We1, usb+U_WEDATH,                   usb+U_WEDATL,                   Dq, Rq)
  SEG(Wd1, usb+U_WEDATH+(size_t)Rq*Dq,     usb+U_WEDATL+(size_t)Rq*Dq,     Dq, Rq)
  SEG(Wa1, usb+U_WEDATH+(size_t)2*Rq*Dq,   usb+U_WEDATL+(size_t)2*Rq*Dq,   Dq, Rq)
  SEG(Wg,  usb+U_WGTH,                     usb+U_WGTL,                     Dq, Dq)
  SEG(We2, usb+U_WE2TH,                    usb+U_WE2TL,                    Rq, Hq)
  SEG(Wd2, usb+U_WD2TH,                    usb+U_WD2TL,                    Rq, Hq)
  SEG(Wa2, usb+U_WA2TH,                    usb+U_WA2TL,                    Rq, Hq)
  SEG(Wo,  usb+U_WOTH,                     usb+U_WOTL,                     Hq, Dq)
#undef SEG
}

// row-major f32 [M][K] -> bf16 hi/lo planes (no transpose). 1 float4/thread.
__global__ __launch_bounds__(256) void splitX(const float* __restrict__ A,
    unsigned short* __restrict__ h, unsigned short* __restrict__ l)
{
  size_t idx = ((size_t)blockIdx.x*256 + threadIdx.x)*4;
  float4 v = *(const float4*)&A[idx];
  unsigned hp0 = cvt_pk_bf16(v.x, v.y), hp1 = cvt_pk_bf16(v.z, v.w);
  unsigned lp0 = cvt_pk_bf16(v.x-lo16f(hp0), v.y-hi16f(hp0));
  unsigned lp1 = cvt_pk_bf16(v.z-lo16f(hp1), v.w-hi16f(hp1));
  uintx2 th = {hp0, hp1}, tl = {lp0, lp1};
  *(uintx2*)&h[idx] = th;
  *(uintx2*)&l[idx] = tl;
}

// conv+LN for k: emits pre-split bf16 hi/lo planes (same split of the same
// f32 value -> GEMM1 inputs bit-identical to the old in-kernel split). v: f32.
__global__ __launch_bounds__(128) void conv_ln_kernel(
  const float* __restrict__ k_raw, const float* __restrict__ v_raw,
  const float* __restrict__ conv_w, const float* __restrict__ conv_b,
  const float* __restrict__ kn_g, const float* __restrict__ kn_b,
  unsigned short* __restrict__ khi, unsigned short* __restrict__ klo,
  float* __restrict__ v_out)
{
  int s = blockIdx.x, b = blockIdx.y, which = blockIdx.z;
  int h = threadIdx.x;
  const float* src = (which==0) ? k_raw : v_raw;
  float acc = conv_b[h];
  #pragma unroll
  for (int j=0;j<4;j++){
    int ss = s-3+j;
    if (ss>=0) acc += conv_w[h*4+j]*src[((size_t)b*Sq+ss)*Hq + h];
  }
  if (which==0){
    __shared__ float red[4];
    float sv = acc, s2 = acc*acc;
    #pragma unroll
    for (int off=32; off>0; off>>=1){
      sv += __shfl_down(sv, off, 64);
      s2 += __shfl_down(s2, off, 64);
    }
    if ((h&63)==0){ red[(h>>6)*2]=sv; red[(h>>6)*2+1]=s2; }
    __syncthreads();
    float mean = (red[0]+red[2])*(1.f/128.f);
    float var  = (red[1]+red[3])*(1.f/128.f) - mean*mean;
    float y = (acc-mean)*rsqrtf(var+1e-5f)*kn_g[h]+kn_b[h];
    unsigned short hh = bf16rn(y);
    size_t idx = ((size_t)b*Sq+s)*Hq + h;
    khi[idx] = hh;
    klo[idx] = bf16rn(y - bf16tof(hh));
  } else {
    v_out[((size_t)b*Sq+s)*Hq + h] = acc;
  }
}

// ---- LDS overlay offsets (bytes) for the fused kernel's scan branch ----
#define OFF_KCH   0            // 64*128*2   = 16384
#define OFF_KCL   16384        // 16384
#define OFF_ACTH  32768        // 64*256*2   = 32768
#define OFF_SAM   65536        // 1024
#define OFF_SUS   66560        // 512
#define OFF_PEN   67072        // 64*12*4 = 3072
#define OFF_DRED  70144        // 8*256*4 = 8192
#define OFF_SUU   78336        // 32
#define OFF_SAB   78368        // 512
#define OFF_SEB   78880        // 512
#define OFF_SABP  79392        // 8
#define OFF_SEBP  79400        // 8
#define LDS_TOTAL 79408

// Fused kernel: blocks 0..3 = sequential scan (1 per batch);
// blocks 4.. = Wg GEMM tiles, co-scheduled on idle CUs.
// Scan schedule (3 barriers/chunk; __syncthreads drains vmcnt -> all global
// loads are issued RIGHT AFTER a barrier so the next phase covers them):
//   B1 -> [vv/dd + ab/eb issue] -> W1+b1 upd(t-1) -> GEMM1(kc LDS) -> gelu
//   -> publish -> B2 -> [aw/ew] -> stage kc(t+1) async -> GEMM2
//   -> epilogue/pen -> B3 -> en/grad/us -> b2 -> butterfly d[m] -> W2 upd
__global__ __launch_bounds__(512, 2) void fused_scan_wg(
  const unsigned short* __restrict__ khi, const unsigned short* __restrict__ klo,
  const float* __restrict__ v_c,
  const float* __restrict__ eta, const float* __restrict__ delta,
  const float* __restrict__ alpha,
  const float* __restrict__ mW1, const float* __restrict__ mb1,
  const float* __restrict__ mW2, const float* __restrict__ mb2,
  float* __restrict__ combined,
  const float* __restrict__ x,
  const unsigned short* __restrict__ WgTh, const unsigned short* __restrict__ WgTl,
  float* __restrict__ glog)
{
  __shared__ __align__(16) char smem[LDS_TOTAL];
  const int blk = blockIdx.x;
  const int tid = threadIdx.x;
  const int wv = tid >> 6;
  const int lane = tid & 63;
  const int n = lane & 15;
  const int q = lane >> 4;

  if (blk >= 4){
    // ================= Wg GEMM branch (512 thr, 128x128 tile) =================
    unsigned short* As_h = (unsigned short*)smem;          // 128*40
    unsigned short* As_l = As_h + 128*40;
    unsigned short* Bs_h = As_l + 128*40;
    unsigned short* Bs_l = Bs_h + 128*40;
    const int g = blk - 4;
    const int bm = (g>>3)*128, bn = (g&7)*128;
    const int wm = wv&3, wn = wv>>2;
    f32x4 acc[2][4];
    #pragma unroll
    for (int i=0;i<2;i++){
      #pragma unroll
      for (int j=0;j<4;j++){ f32x4 z={0.f,0.f,0.f,0.f}; acc[i][j]=z; }
    }
    for (int k0=0;k0<Dq;k0+=32){
      #pragma unroll
      for (int r=0;r<2;r++){
        int idx = tid + 512*r;
        int row = idx>>3, kg = (idx&7)*4;
        float4 v = *(const float4*)&x[(size_t)(bm+row)*Dq + k0+kg];
        unsigned hp0 = cvt_pk_bf16(v.x, v.y), hp1 = cvt_pk_bf16(v.z, v.w);
        unsigned lp0 = cvt_pk_bf16(v.x-lo16f(hp0), v.y-hi16f(hp0));
        unsigned lp1 = cvt_pk_bf16(v.z-lo16f(hp1), v.w-hi16f(hp1));
        int off = row*40+kg;
        uintx2 th = {hp0, hp1}, tl = {lp0, lp1};
        *(uintx2*)&As_h[off] = th;
        *(uintx2*)&As_l[off] = tl;
      }
      {
        int row = tid>>2, kg = (tid&3)*8;
        *(short8*)&Bs_h[row*40+kg] = *(const short8*)&WgTh[(size_t)(bn+row)*Dq + k0+kg];
        *(short8*)&Bs_l[row*40+kg] = *(const short8*)&WgTl[(size_t)(bn+row)*Dq + k0+kg];
      }
      __syncthreads();
      short8 a_h[2], a_l[2], b_h[4], b_l[4];
      #pragma unroll
      for (int i=0;i<2;i++){
        int r = wm*32 + i*16 + n;
        a_h[i] = *(const short8*)&As_h[r*40 + q*8];
        a_l[i] = *(const short8*)&As_l[r*40 + q*8];
      }
      #pragma unroll
      for (int j=0;j<4;j++){
        int r = wn*64 + j*16 + n;
        b_h[j] = *(const short8*)&Bs_h[r*40 + q*8];
        b_l[j] = *(const short8*)&Bs_l[r*40 + q*8];
      }
      #pragma unroll
      for (int i=0;i<2;i++){
        #pragma unroll
        for (int j=0;j<4;j++){
          acc[i][j] = __builtin_amdgcn_mfma_f32_16x16x32_bf16(a_h[i], b_h[j], acc[i][j], 0,0,0);
          acc[i][j] = __builtin_amdgcn_mfma_f32_16x16x32_bf16(a_l[i], b_h[j], acc[i][j], 0,0,0);
          acc[i][j] = __builtin_amdgcn_mfma_f32_16x16x32_bf16(a_h[i], b_l[j], acc[i][j], 0,0,0);
        }
      }
      __syncthreads();
    }
    #pragma unroll
    for (int i=0;i<2;i++){
      #pragma unroll
      for (int j=0;j<4;j++){
        #pragma unroll
        for (int r=0;r<4;r++){
          int row = bm + wm*32 + i*16 + q*4 + r;
          int col = bn + wn*64 + j*16 + n;
          glog[(size_t)row*Dq+col] = acc[i][j][r];
        }
      }
    }
    return;
  }

  // ================= scan branch =================
  unsigned short* kc_hi  = (unsigned short*)(smem + OFF_KCH);
  unsigned short* kc_lo  = (unsigned short*)(smem + OFF_KCL);
  unsigned short* act_hi = (unsigned short*)(smem + OFF_ACTH);
  float* Sam = (float*)(smem + OFF_SAM);
  float* Sus = (float*)(smem + OFF_SUS);
  float* pen = (float*)(smem + OFF_PEN);   // [c][12] (8 wave partials)
  float* Dred= (float*)(smem + OFF_DRED);  // [wv][256] per-wave d = us.W2old partials
  float* Suu = (float*)(smem + OFF_SUU);   // [8]  per-wave us.us partials
  float* Sab = (float*)(smem + OFF_SAB);
  float* Seb = (float*)(smem + OFF_SEB);
  float* Sabp = (float*)(smem + OFF_SABP);
  float* Sebp = (float*)(smem + OFF_SEBP);

  const int b = blk;
  const int h = wv*16 + n;          // W2 row ownership (A-frag of swapped GEMM2)
  float w1m[2][4][8];   // W1[m=(2wv+tt)*16+n][h=ks*32+q*8+j]
  float w2m[8][8];      // W2[h=wv*16+n][m=ks2*32+q*8+j]
  float b1reg[2];       // b1[m=(2wv+tt)*16+n]
  float b2n[4];         // b2[h2=wv*16+q*4+r]  (swapped-GEMM2 output rows)
  #pragma unroll
  for (int tt=0;tt<2;tt++){
    int m = (2*wv+tt)*16 + n;
    #pragma unroll
    for (int ks=0;ks<4;ks++){
      const float* p = mW1 + (size_t)m*Hq + ks*32 + q*8;
      #pragma unroll
      for (int j=0;j<8;j++) w1m[tt][ks][j] = p[j];
    }
    b1reg[tt] = mb1[m];
  }
  {
    #pragma unroll
    for (int ks2=0;ks2<8;ks2++){
      const float* p = mW2 + (size_t)h*Mq + ks2*32 + q*8;
      #pragma unroll
      for (int j=0;j<8;j++) w2m[ks2][j] = p[j];
    }
    #pragma unroll
    for (int r=0;r<4;r++) b2n[r] = mb2[wv*16 + q*4 + r];
  }
  // cross-chunk carried scalars (chunk t-1 values, consumed at t's top)
  float aw = 0.f, ew = 0.f;
  float am_own[2] = {0.f, 0.f};

  const unsigned short* khb = khi + (size_t)b*Sq*Hq;
  const unsigned short* klb = klo + (size_t)b*Sq*Hq;

  // ---- async kc staging setup: pre-swizzled per-lane global offsets so the
  // linear global_load_lds write (base + lane*16) produces the swizzled LDS
  // image LDS[c*128 + pg*8 + e] = k[c][((pg^(c&15))<<3)+e].
  const int c0s = (wv*2+0)*4 + (lane>>4);
  const int c1s = (wv*2+1)*4 + (lane>>4);
  const int soff0 = c0s*Hq + ((((lane&15)^(c0s&15)))<<3);
  const int soff1 = c1s*Hq + ((((lane&15)^(c1s&15)))<<3);
  char* d_kh0 = smem + OFF_KCH + (wv*2+0)*1024;
  char* d_kh1 = smem + OFF_KCH + (wv*2+1)*1024;
  char* d_kl0 = smem + OFF_KCL + (wv*2+0)*1024;
  char* d_kl1 = smem + OFF_KCL + (wv*2+1)*1024;
  // prologue: stage chunk 0 (drains at B1 of t=0 via __syncthreads vmcnt(0))
  g2lds16(khb + soff0, d_kh0);
  g2lds16(khb + soff1, d_kh1);
  g2lds16(klb + soff0, d_kl0);
  g2lds16(klb + soff1, d_kl1);

  for (int t=0; t<NCHUNK; ++t){
    const size_t base = ((size_t)b*Sq + (size_t)t*Cq)*Hq;
    __syncthreads();   // B1: kc(t) staged; orders prev-chunk Sus/Dred/Suu

    // ---- issue this chunk's global loads NOW (drain at B2 under GEMM1) ----
    f32x4 vvv[4], ddd[4];
    #pragma unroll
    for (int ct=0;ct<4;ct++){
      size_t off = base + (size_t)(ct*16+n)*Hq + wv*16 + q*4;
      vvv[ct] = *(const f32x4*)&v_c[off];
      ddd[ct] = *(const f32x4*)&delta[off];
    }
    float ab_=0.f, eb_=0.f;
    if (tid < 128){
      ab_ = alpha[base + 63*Hq + tid];
      eb_ = eta[base + 63*Hq + tid];
    }

    // ---- W1 + b1 update from chunk t-1 (reads Sus/Dred/Suu) ----
    if (t > 0){
      float4 s0[4], s1[4];
      #pragma unroll
      for (int ks=0;ks<4;ks++){
        s0[ks] = *(const float4*)&Sus[ks*32 + q*8];
        s1[ks] = *(const float4*)&Sus[ks*32 + q*8 + 4];
      }
      float4 u0 = *(const float4*)&Suu[0];
      float4 u1 = *(const float4*)&Suu[4];
      float uu = u0.x+u0.y+u0.z+u0.w+u1.x+u1.y+u1.z+u1.w;
      #pragma unroll
      for (int tt=0;tt<2;tt++){
        int m = (2*wv+tt)*16 + n;
        float amm = am_own[tt];
        float eam = ew*amm;
        #pragma unroll
        for (int ks=0;ks<4;ks++){
          #pragma unroll
          for (int j=0;j<4;j++){
            w1m[tt][ks][j]   = aw*w1m[tt][ks][j]   - eam*s0[ks][j];
            w1m[tt][ks][j+4] = aw*w1m[tt][ks][j+4] - eam*s1[ks][j];
          }
        }
        float dsum = 0.f;
        #pragma unroll
        for (int w8=0;w8<8;w8++) dsum += Dred[w8*256 + m];
        // b1u = us.nW2[:,m] = aw*dsum - ew*uu*am[m]
        b1reg[tt] = aw*b1reg[tt] - ew*(aw*dsum - ew*uu*amm);
      }
    }

    // ---- GEMM1: inter = kc @ W1^T (kc hi/lo from LDS, W1 hi/lo: 3-MFMA) ----
    f32x4 acc1[2][4];
    #pragma unroll
    for (int tt=0;tt<2;tt++){
      #pragma unroll
      for (int ct=0;ct<4;ct++){ f32x4 z={0.f,0.f,0.f,0.f}; acc1[tt][ct]=z; }
    }
    __builtin_amdgcn_s_setprio(1);
    #pragma unroll
    for (int ks=0;ks<4;ks++){
      pk8 BH[2], BL[2];
      #pragma unroll
      for (int tt=0;tt<2;tt++){
        #pragma unroll
        for (int jp=0;jp<4;jp++){
          float a0 = w1m[tt][ks][2*jp], a1 = w1m[tt][ks][2*jp+1];
          unsigned hp = cvt_pk_bf16(a0, a1);
          BH[tt].u[jp] = hp;
          BL[tt].u[jp] = cvt_pk_bf16(a0 - lo16f(hp), a1 - hi16f(hp));
        }
      }
      #pragma unroll
      for (int ct=0;ct<4;ct++){
        int c = ct*16 + n;
        int off = c*Hq + ((((ks*4+q)^n))<<3);
        short8 ah = *(const short8*)&kc_hi[off];
        short8 al = *(const short8*)&kc_lo[off];
        #pragma unroll
        for (int tt=0;tt<2;tt++){
          acc1[tt][ct] = __builtin_amdgcn_mfma_f32_16x16x32_bf16(ah, BH[tt].s, acc1[tt][ct], 0,0,0);
          acc1[tt][ct] = __builtin_amdgcn_mfma_f32_16x16x32_bf16(al, BH[tt].s, acc1[tt][ct], 0,0,0);
          acc1[tt][ct] = __builtin_amdgcn_mfma_f32_16x16x32_bf16(ah, BL[tt].s, acc1[tt][ct], 0,0,0);
        }
      }
    }
    __builtin_amdgcn_s_setprio(0);
    // gelu -> act_hi + am
    #pragma unroll
    for (int tt=0;tt<2;tt++){
      int m = (2*wv+tt)*16 + n;
      float b1v = b1reg[tt];
      float amsum = 0.f;
      #pragma unroll
      for (int ct=0;ct<4;ct++){
        #pragma unroll
        for (int r=0;r<4;r++){
          float g = gelu_fast(acc1[tt][ct][r] + b1v);
          amsum += g;
          int c = ct*16 + q*4 + r;
          int pg = (m>>3) ^ (c & 15);
          act_hi[c*Mq + (pg<<3) + (m&7)] = bf16rn(g);
        }
      }
      amsum += __shfl_xor(amsum, 16, 64);
      amsum += __shfl_xor(amsum, 32, 64);
      am_own[tt] = amsum*(1.f/64.f);
      if (q==0) Sam[m] = am_own[tt];
    }
    // publish alpha/eta
    if (tid < 128){ Sab[tid] = ab_; Seb[tid] = eb_; }
    if (wv < 2){
      float a2 = ab_, e2 = eb_;
      #pragma unroll
      for (int mk=1;mk<64;mk<<=1){ a2 += __shfl_xor(a2,mk,64); e2 += __shfl_xor(e2,mk,64); }
      if (lane==0){ Sabp[wv] = a2; Sebp[wv] = e2; }
    }
    __syncthreads();   // B2: act/Sam/Sab/Sabp ready; all GEMM1 kc reads done

    // ---- aw/ew for this chunk (Sabp published pre-B2; read early to hide
    //      the LDS latency ahead of the post-B3 dependency chain) ----
    aw = (Sabp[0]+Sabp[1])*(1.f/128.f);
    ew = (Sebp[0]+Sebp[1])*(1.f/128.f);

    // ---- stage kc(t+1) into LDS (async; drains at B3 under GEMM2 cover) ----
    {
      const size_t nb = (size_t)((t+1<NCHUNK)?(t+1):t)*Cq*Hq;
      g2lds16(khb + nb + soff0, d_kh0);
      g2lds16(khb + nb + soff1, d_kh1);
      g2lds16(klb + nb + soff0, d_kl0);
      g2lds16(klb + nb + soff1, d_kl1);
    }

    // ---- GEMM2 (operand-swapped): out^T = W2 @ act^T -> out[h2][c] ----
    f32x4 acc2[4];
    #pragma unroll
    for (int ct=0;ct<4;ct++){ f32x4 z={0.f,0.f,0.f,0.f}; acc2[ct]=z; }
    __builtin_amdgcn_s_setprio(1);
    #pragma unroll
    for (int ks2=0;ks2<8;ks2++){
      pk8 BH, BL;
      #pragma unroll
      for (int jp=0;jp<4;jp++){
        float a0 = w2m[ks2][2*jp], a1 = w2m[ks2][2*jp+1];
        unsigned hp = cvt_pk_bf16(a0, a1);
        BH.u[jp] = hp;
        BL.u[jp] = cvt_pk_bf16(a0 - lo16f(hp), a1 - hi16f(hp));
      }
      #pragma unroll
      for (int ct=0;ct<4;ct++){
        int c = ct*16 + n;
        int off = c*Mq + ((((ks2*4+q)^n))<<3);
        short8 ah = *(const short8*)&act_hi[off];
        acc2[ct] = __builtin_amdgcn_mfma_f32_16x16x32_bf16(BH.s, ah, acc2[ct], 0,0,0);
        acc2[ct] = __builtin_amdgcn_mfma_f32_16x16x32_bf16(BL.s, ah, acc2[ct], 0,0,0);
      }
    }
    __builtin_amdgcn_s_setprio(0);

    // ---- epilogue: float4 out store, err, pen partials (2 shfl) ----
    float err[4][4];
    {
      float* cb = combined + base;
      #pragma unroll
      for (int ct=0;ct<4;ct++){
        int c = ct*16 + n;
        f32x4 ov;
        #pragma unroll
        for (int r=0;r<4;r++){
          float o = acc2[ct][r] + b2n[r];
          ov[r] = o;
          err[ct][r] = o - vvv[ct][r];
        }
        *(f32x4*)&cb[(size_t)c*Hq + wv*16 + q*4] = ov;
      }
      #pragma unroll
      for (int ct=0;ct<4;ct++){
        float s = err[ct][0]*err[ct][0] + err[ct][1]*err[ct][1]
                + err[ct][2]*err[ct][2] + err[ct][3]*err[ct][3];
        s += __shfl_xor(s, 16, 64);
        s += __shfl_xor(s, 32, 64);
        if (q==0) pen[(ct*16+n)*12 + wv] = s;
      }
    }
    __syncthreads();   // B3: pen ready; kc(t+1) staging drained (vmcnt(0))

    // ---- en (direct pen reads) -> grad -> us (n-butterfly) ----
    float en_c[4];
    #pragma unroll
    for (int ct=0;ct<4;ct++){
      int c = ct*16 + n;
      float4 e0 = *(const float4*)&pen[c*12];
      float4 e1 = *(const float4*)&pen[c*12+4];
      en_c[ct] = sqrtf(e0.x+e0.y+e0.z+e0.w+e1.x+e1.y+e1.z+e1.w);
    }
    float us_r[4];
    #pragma unroll
    for (int r=0;r<4;r++){
      float s = 0.f;
      #pragma unroll
      for (int ct=0;ct<4;ct++){
        float e = err[ct][r];
        float dvv = ddd[ct][r];
        float en = en_c[ct];
        float g = (en > dvv) ? dvv*e*__builtin_amdgcn_rcpf(en+1e-9f) : e;
        s += g;
      }
      s += __shfl_xor(s,1,64); s += __shfl_xor(s,2,64);
      s += __shfl_xor(s,4,64); s += __shfl_xor(s,8,64);
      us_r[r] = s*(1.f/64.f);     // us[h2 = wv*16+q*4+r], replicated over n
    }
    if (n==0){
      #pragma unroll
      for (int r=0;r<4;r++) Sus[wv*16 + q*4 + r] = us_r[r];
    }
    // uu partial over this wave's 16 h (sum over r in-thread, then over q)
    {
      float uun = us_r[0]*us_r[0] + us_r[1]*us_r[1]
                + us_r[2]*us_r[2] + us_r[3]*us_r[3];
      uun += __shfl_xor(uun, 16, 64);
      uun += __shfl_xor(uun, 32, 64);
      if (lane==0) Suu[wv] = uun;
    }
    // ---- b2 update (in-register, float4 Sab/Seb reads) ----
    {
      f32x4 sab = *(const f32x4*)&Sab[wv*16 + q*4];
      f32x4 seb = *(const f32x4*)&Seb[wv*16 + q*4];
      #pragma unroll
      for (int r=0;r<4;r++) b2n[r] = sab[r]*b2n[r] - seb[r]*us_r[r];
    }
    // ---- ush at W2-ownership lane (h = wv*16+n) via shfl pulls ----
    float ush;
    {
      int src = (n>>2)<<4;     // any lane in q-group n>>2 (us_r replicated over n)
      float p0 = __shfl(us_r[0], src, 64);
      float p1 = __shfl(us_r[1], src, 64);
      float p2 = __shfl(us_r[2], src, 64);
      float p3 = __shfl(us_r[3], src, 64);
      int rr = n&3;
      ush = (rr==0) ? p0 : (rr==1) ? p1 : (rr==2) ? p2 : p3;
    }

    // ---- d[m] = us . W2_old[:,m]: reduce-scatter butterfly over n ----
    {
      const bool bb0 = (n&1);
      float p1[8][4];
      #pragma unroll
      for (int k2=0;k2<8;k2++){
        #pragma unroll
        for (int l=0;l<4;l++){
          float mine = ush * (bb0 ? w2m[k2][l+4] : w2m[k2][l]);
          float oth  = ush * (bb0 ? w2m[k2][l]   : w2m[k2][l+4]);
          p1[k2][l] = mine + __shfl_xor(oth, 1, 64);
        }
      }
      const bool bb1 = (n>>1)&1;
      float p2[4][4];
      #pragma unroll
      for (int k2=0;k2<4;k2++){
        #pragma unroll
        for (int l=0;l<4;l++){
          float mine = bb1 ? p1[2*k2+1][l] : p1[2*k2][l];
          float oth  = bb1 ? p1[2*k2][l]   : p1[2*k2+1][l];
          p2[k2][l] = mine + __shfl_xor(oth, 2, 64);
        }
      }
      const bool bb2 = (n>>2)&1;
      float p3[2][4];
      #pragma unroll
      for (int k2=0;k2<2;k2++){
        #pragma unroll
        for (int l=0;l<4;l++){
          float mine = bb2 ? p2[2*k2+1][l] : p2[2*k2][l];
          float oth  = bb2 ? p2[2*k2][l]   : p2[2*k2+1][l];
          p3[k2][l] = mine + __shfl_xor(oth, 4, 64);
        }
      }
      const bool bb3 = (n>>3)&1;
      float4 p4;
      {
        float m0 = bb3 ? p3[1][0] : p3[0][0];
        float o0 = bb3 ? p3[0][0] : p3[1][0];
        p4.x = m0 + __shfl_xor(o0, 8, 64);
        float m1 = bb3 ? p3[1][1] : p3[0][1];
        float o1 = bb3 ? p3[0][1] : p3[1][1];
        p4.y = m1 + __shfl_xor(o1, 8, 64);
        float m2 = bb3 ? p3[1][2] : p3[0][2];
        float o2 = bb3 ? p3[0][2] : p3[1][2];
        p4.z = m2 + __shfl_xor(o2, 8, 64);
        float m3 = bb3 ? p3[1][3] : p3[0][3];
        float o3 = bb3 ? p3[0][3] : p3[1][3];
        p4.w = m3 + __shfl_xor(o3, 8, 64);
      }
      // lane owns 4 consecutive m: (n>>1)*32 + q*8 + (n&1)*4 + [0..3]
      int base_m = (n>>1)*32 + q*8 + (n&1)*4;
      *(float4*)&Dred[wv*256 + base_m] = p4;
    }

    // ---- W2 update (uses ush at h=wv*16+n, Sam reads; consumed by
    //      GEMM2(t+1) which is past B2(t+1) -> no extra barrier) ----
    {
      float eus = ew*ush;
      #pragma unroll
      for (int ks2=0;ks2<8;ks2++){
        float4 a0 = *(const float4*)&Sam[ks2*32 + q*8];
        float4 a1 = *(const float4*)&Sam[ks2*32 + q*8 + 4];
        #pragma unroll
        for (int j=0;j<4;j++){
          w2m[ks2][j]   = aw*w2m[ks2][j]   - eus*a0[j];
          w2m[ks2][j+4] = aw*w2m[ks2][j+4] - eus*a1[j];
        }
      }
    }
    // W1 + b1 update deferred to top of chunk t+1 (after B1).
  }
}

extern "C" void kernel_launch(void* const* d_in, const int* in_sizes, int n_in,
                              void* d_out, int out_size, void* d_ws, size_t ws_size,
                              hipStream_t stream)
{
  const float* x    = (const float*)d_in[0];
  // d_in[1]=Wq, d_in[14],[15]=qn_g/qn_b: dead (q path unused by output).
  const float* Wk   = (const float*)d_in[2];
  const float* Wv   = (const float*)d_in[3];
  const float* Wo   = (const float*)d_in[4];
  const float* Wg   = (const float*)d_in[5];
  const float* We1  = (const float*)d_in[6];
  const float* We2  = (const float*)d_in[7];
  const float* Wd1  = (const float*)d_in[8];
  const float* Wd2  = (const float*)d_in[9];
  const float* Wa1  = (const float*)d_in[10];
  const float* Wa2  = (const float*)d_in[11];
  const float* conv_w = (const float*)d_in[12];
  const float* conv_b = (const float*)d_in[13];
  const float* kn_g = (const float*)d_in[16];
  const float* kn_b = (const float*)d_in[17];
  const float* mW1  = (const float*)d_in[18];
  const float* mb1  = (const float*)d_in[19];
  const float* mW2  = (const float*)d_in[20];
  const float* mb2  = (const float*)d_in[21];
  float* out = (float*)d_out;

  float* ws = (float*)d_ws;
  size_t o = 0;
  float* k_raw = ws + o; o += (size_t)BSq*Hq;
  float* v_raw = ws + o; o += (size_t)BSq*Hq;
  float* te    = ws + o; o += (size_t)BSq*Rq;
  float* td    = ws + o; o += (size_t)BSq*Rq;
  float* ta    = ws + o; o += (size_t)BSq*Rq;
  float* glog  = ws + o; o += (size_t)BSq*Dq;
  float* etab  = ws + o; o += (size_t)BSq*Hq;
  float* deltab= ws + o; o += (size_t)BSq*Hq;
  float* alphab= ws + o; o += (size_t)BSq*Hq;
  float* kslot = ws + o; o += (size_t)BSq*Hq;   // khi/klo bf16 planes (8MB slot)
  float* v_c   = ws + o; o += (size_t)BSq*Hq;
  float* comb  = ws + o; o += (size_t)BSq*Hq;
  unsigned short* usb = (unsigned short*)(ws + o);

  unsigned short* khi = (unsigned short*)kslot;
  unsigned short* klo = khi + (size_t)BSq*Hq;

  // xh/xl (bf16 planes of x, 32MB each) overlay glog (64MB): dead once the
  // projections complete; glog written later by the fused kernel.
  unsigned short* xh = (unsigned short*)glog;
  unsigned short* xl = xh + (size_t)BSq*Dq;

  // one-shot weight transpose+split (all 10 weights, 1 launch)
  {
    size_t total = 2*(size_t)Hq*Dq + 3*(size_t)Rq*Dq + (size_t)Dq*Dq
                 + 3*(size_t)Hq*Rq + (size_t)Dq*Hq;
    splitT_all<<<(unsigned)(total/256), 256, 0, stream>>>(
        Wk, Wv, We1, Wd1, Wa1, Wg, We2, Wd2, Wa2, Wo, usb);
  }
  splitX<<<(size_t)BSq*Dq/4/256, 256, 0, stream>>>(x, xh, xl);

  dim3 blk(256);
  // merged x-projections (BM=64 tiles -> 512/768 blocks, 2-3 blocks/CU):
  gemm_bb<128><<<dim3(2, BSq/64), blk, 0, stream>>>(xh, xl, usb+U_WKVTH, usb+U_WKVTL, k_raw, v_raw, nullptr, Dq);
  gemm_bb<64> <<<dim3(3, BSq/64), blk, 0, stream>>>(xh, xl, usb+U_WEDATH, usb+U_WEDATL, te, td, ta, Dq);
  // merged second-stage R=64 GEMMs (eta/delta/alpha), BM=64 -> 768 blocks
  gemm_eda2<<<dim3(3, BSq/64), blk, 0, stream>>>(te, td, ta, usb, etab, deltab, alphab);
  conv_ln_kernel<<<dim3(Sq, Bq, 2), dim3(128), 0, stream>>>(
      k_raw, v_raw, conv_w, conv_b, kn_g, kn_b, khi, klo, v_c);
  // fused: scan (blocks 0..3) + Wg GEMM (blocks 4..1027) co-scheduled
  fused_scan_wg<<<dim3(4 + (BSq/128)*(Dq/128)), dim3(512), 0, stream>>>(
      khi, klo, v_c, etab, deltab, alphab, mW1, mb1, mW2, mb2, comb,
      x, usb+U_WGTH, usb+U_WGTL, glog);
  gemm_bf3<128,3><<<dim3(Dq/128, BSq/128), blk, 0, stream>>>(comb, usb+U_WOTH, usb+U_WOTL, out, glog, Dq, Hq);
}

// Round 9
// 1202.818 us; speedup vs baseline: 1.6705x; 1.0106x over previous
//
#include <hip/hip_runtime.h>
#include <math.h>

#define Bq 4
#define Sq 4096
#define Dq 1024
#define Hq 128
#define Mq 256
#define Rq 64
#define Cq 64
#define NCHUNK 64
#define BSq (Bq*Sq)

typedef __attribute__((ext_vector_type(8))) short short8;
typedef __attribute__((ext_vector_type(4))) float f32x4;
typedef __attribute__((ext_vector_type(2))) unsigned int uintx2;

// ---- packed-weight arena layout (elements of unsigned short) ----
#define U_WKVTH  ((size_t)0)
#define U_WKVTL  (U_WKVTH + (size_t)2*Hq*Dq)
#define U_WEDATH (U_WKVTL + (size_t)2*Hq*Dq)
#define U_WEDATL (U_WEDATH + (size_t)3*Rq*Dq)
#define U_WGTH   (U_WEDATL + (size_t)3*Rq*Dq)
#define U_WGTL   (U_WGTH + (size_t)Dq*Dq)
#define U_WE2TH  (U_WGTL + (size_t)Dq*Dq)
#define U_WE2TL  (U_WE2TH + (size_t)Hq*Rq)
#define U_WD2TH  (U_WE2TL + (size_t)Hq*Rq)
#define U_WD2TL  (U_WD2TH + (size_t)Hq*Rq)
#define U_WA2TH  (U_WD2TL + (size_t)Hq*Rq)
#define U_WA2TL  (U_WA2TH + (size_t)Hq*Rq)
#define U_WOTH   (U_WA2TL + (size_t)Hq*Rq)
#define U_WOTL   (U_WOTH + (size_t)Dq*Hq)
#define U_END    (U_WOTL + (size_t)Dq*Hq)

__device__ __forceinline__ float softplusf_(float x){
  return fmaxf(x,0.f) + log1pf(expf(-fabsf(x)));
}
__device__ __forceinline__ float sigmoidf_(float x){
  return 1.f/(1.f+__expf(-x));
}
__device__ __forceinline__ unsigned short bf16rn(float x){
  unsigned u = __float_as_uint(x);
  u += 0x7fffu + ((u>>16)&1u);
  return (unsigned short)(u>>16);
}
__device__ __forceinline__ float bf16tof(unsigned short s){
  return __uint_as_float(((unsigned)s)<<16);
}
// packed 2xf32 -> 2xbf16 in one instruction (RNE, matches bf16rn).
__device__ __forceinline__ unsigned cvt_pk_bf16(float a, float b){
  unsigned r;
  asm("v_cvt_pk_bf16_f32 %0, %1, %2" : "=v"(r) : "v"(a), "v"(b));
  return r;
}
__device__ __forceinline__ float lo16f(unsigned p){ return __uint_as_float(p<<16); }
__device__ __forceinline__ float hi16f(unsigned p){ return __uint_as_float(p & 0xffff0000u); }
union pk8 { unsigned u[4]; short8 s; };

// async global->LDS 16B copy: per-lane global src, wave-uniform LDS base
// (HW adds lane*16 to the LDS dest). C-style addrspace casts (CK pattern).
__device__ __forceinline__ void g2lds16(const unsigned short* g, void* lds){
  __builtin_amdgcn_global_load_lds(
      (const __attribute__((address_space(1))) unsigned int*)(const void*)g,
      (__attribute__((address_space(3))) unsigned int*)lds,
      16, 0, 0);
}

// branchless erf-gelu (A&S 7.1.26, |err|<=1.5e-7)
__device__ __forceinline__ float gelu_fast(float x){
  float z  = x*0.70710678118f;
  float az = fabsf(z);
  float t  = __builtin_amdgcn_rcpf(fmaf(0.3275911f, az, 1.f));
  float p  = fmaf(t, 1.061405429f, -1.453152027f);
  p = fmaf(t, p, 1.421413741f);
  p = fmaf(t, p, -0.284496736f);
  p = fmaf(t, p, 0.254829592f);
  p = p*t;
  float e  = __expf(-az*az);
  float er = copysignf(1.f - p*e, z);
  return 0.5f*x*(1.f + er);
}

// ---------------- bf16x3 MFMA GEMM, f32 A (cvt_pk staging) ----------------
template<int BN, int ACT>
__global__ __launch_bounds__(256) void gemm_bf3(
    const float* __restrict__ Af,
    const unsigned short* __restrict__ BhT, const unsigned short* __restrict__ BlT,
    float* __restrict__ C, const float* __restrict__ gate, int N, int K)
{
  constexpr int BM = 128;
  constexpr int PK = 40;
  constexpr int TN = BN/32;
  __shared__ __align__(16) unsigned short As[2][BM*PK];
  __shared__ __align__(16) unsigned short Bs[2][BN*PK];
  const int tid = threadIdx.x;
  const int bm = blockIdx.y*BM, bn = blockIdx.x*BN;
  const int wv = tid>>6, lane = tid&63;
  const int n16 = lane&15, q = lane>>4;
  const int wm = wv>>1, wn = wv&1;

  f32x4 acc[4][TN];
  #pragma unroll
  for (int i=0;i<4;i++){
    #pragma unroll
    for (int j=0;j<TN;j++){ f32x4 z={0.f,0.f,0.f,0.f}; acc[i][j]=z; }
  }
  for (int k0=0;k0<K;k0+=32){
    #pragma unroll
    for (int c0=0;c0<BM*8;c0+=256){
      int c = c0 + tid;
      int row = c>>3, kg = (c&7)*4;
      float4 v = *(const float4*)&Af[(size_t)(bm+row)*K + k0+kg];
      unsigned hp0 = cvt_pk_bf16(v.x, v.y), hp1 = cvt_pk_bf16(v.z, v.w);
      unsigned lp0 = cvt_pk_bf16(v.x-lo16f(hp0), v.y-hi16f(hp0));
      unsigned lp1 = cvt_pk_bf16(v.z-lo16f(hp1), v.w-hi16f(hp1));
      int off = row*PK+kg;
      uintx2 th = {hp0, hp1}, tl = {lp0, lp1};
      *(uintx2*)&As[0][off] = th;
      *(uintx2*)&As[1][off] = tl;
    }
    #pragma unroll
    for (int c0=0;c0<BN*4;c0+=256){
      int c = c0 + tid;
      int row = c>>2, kg = (c&3)*8;
      *(short8*)&Bs[0][row*PK+kg] = *(const short8*)&BhT[(size_t)(bn+row)*K + k0+kg];
      *(short8*)&Bs[1][row*PK+kg] = *(const short8*)&BlT[(size_t)(bn+row)*K + k0+kg];
    }
    __syncthreads();
    short8 a_h[4], a_l[4], b_h[TN], b_l[TN];
    #pragma unroll
    for (int i=0;i<4;i++){
      int r = wm*64 + i*16 + n16;
      a_h[i] = *(const short8*)&As[0][r*PK + q*8];
      a_l[i] = *(const short8*)&As[1][r*PK + q*8];
    }
    #pragma unroll
    for (int j=0;j<TN;j++){
      int r = wn*(BN/2) + j*16 + n16;
      b_h[j] = *(const short8*)&Bs[0][r*PK + q*8];
      b_l[j] = *(const short8*)&Bs[1][r*PK + q*8];
    }
    #pragma unroll
    for (int i=0;i<4;i++){
      #pragma unroll
      for (int j=0;j<TN;j++){
        acc[i][j] = __builtin_amdgcn_mfma_f32_16x16x32_bf16(a_h[i], b_h[j], acc[i][j], 0,0,0);
        acc[i][j] = __builtin_amdgcn_mfma_f32_16x16x32_bf16(a_l[i], b_h[j], acc[i][j], 0,0,0);
        acc[i][j] = __builtin_amdgcn_mfma_f32_16x16x32_bf16(a_h[i], b_l[j], acc[i][j], 0,0,0);
      }
    }
    __syncthreads();
  }
  #pragma unroll
  for (int i=0;i<4;i++){
    #pragma unroll
    for (int j=0;j<TN;j++){
      #pragma unroll
      for (int r=0;r<4;r++){
        int row = bm + wm*64 + i*16 + q*4 + r;
        int col = bn + wn*(BN/2) + j*16 + n16;
        float v = acc[i][j][r];
        if (ACT==1) v = softplusf_(v);
        else if (ACT==2) v = sigmoidf_(v);
        else if (ACT==3) v *= sigmoidf_(gate[(size_t)row*N+col]);
        C[(size_t)row*N+col] = v;
      }
    }
  }
}

// ---------------- merged x-projection GEMM: f32 A direct (no splitX) ------
// BM=64 (r7 occupancy win), packed-B rows select output via blockIdx.x.
__global__ __launch_bounds__(256) void gemm_kv(
    const float* __restrict__ x,
    const unsigned short* __restrict__ BhT, const unsigned short* __restrict__ BlT,
    float* __restrict__ C0, float* __restrict__ C1)
{
  constexpr int BM = 64, PK = 40, BN = 128, TN = 4, K = Dq;
  __shared__ __align__(16) unsigned short As[2][BM*PK];
  __shared__ __align__(16) unsigned short Bs[2][BN*PK];
  const int tid = threadIdx.x;
  const int bx = blockIdx.x;
  const int bm = blockIdx.y*BM;
  const int bnB = bx*BN;
  float* __restrict__ C = (bx==0) ? C0 : C1;
  const int wv = tid>>6, lane = tid&63;
  const int n16 = lane&15, q = lane>>4;
  const int wm = wv>>1, wn = wv&1;

  f32x4 acc[2][TN];
  #pragma unroll
  for (int i=0;i<2;i++){
    #pragma unroll
    for (int j=0;j<TN;j++){ f32x4 z={0.f,0.f,0.f,0.f}; acc[i][j]=z; }
  }
  for (int k0=0;k0<K;k0+=32){
    #pragma unroll
    for (int c0=0;c0<BM*8;c0+=256){
      int c = c0 + tid;
      int row = c>>3, kg = (c&7)*4;
      float4 v = *(const float4*)&x[(size_t)(bm+row)*K + k0+kg];
      unsigned hp0 = cvt_pk_bf16(v.x, v.y), hp1 = cvt_pk_bf16(v.z, v.w);
      unsigned lp0 = cvt_pk_bf16(v.x-lo16f(hp0), v.y-hi16f(hp0));
      unsigned lp1 = cvt_pk_bf16(v.z-lo16f(hp1), v.w-hi16f(hp1));
      int off = row*PK+kg;
      uintx2 th = {hp0, hp1}, tl = {lp0, lp1};
      *(uintx2*)&As[0][off] = th;
      *(uintx2*)&As[1][off] = tl;
    }
    #pragma unroll
    for (int c0=0;c0<BN*4;c0+=256){
      int c = c0 + tid;
      int row = c>>2, kg = (c&3)*8;
      *(short8*)&Bs[0][row*PK+kg] = *(const short8*)&BhT[(size_t)(bnB+row)*K + k0+kg];
      *(short8*)&Bs[1][row*PK+kg] = *(const short8*)&BlT[(size_t)(bnB+row)*K + k0+kg];
    }
    __syncthreads();
    short8 a_h[2], a_l[2], b_h[TN], b_l[TN];
    #pragma unroll
    for (int i=0;i<2;i++){
      int r = wm*32 + i*16 + n16;
      a_h[i] = *(const short8*)&As[0][r*PK + q*8];
      a_l[i] = *(const short8*)&As[1][r*PK + q*8];
    }
    #pragma unroll
    for (int j=0;j<TN;j++){
      int r = wn*(BN/2) + j*16 + n16;
      b_h[j] = *(const short8*)&Bs[0][r*PK + q*8];
      b_l[j] = *(const short8*)&Bs[1][r*PK + q*8];
    }
    #pragma unroll
    for (int i=0;i<2;i++){
      #pragma unroll
      for (int j=0;j<TN;j++){
        acc[i][j] = __builtin_amdgcn_mfma_f32_16x16x32_bf16(a_h[i], b_h[j], acc[i][j], 0,0,0);
        acc[i][j] = __builtin_amdgcn_mfma_f32_16x16x32_bf16(a_l[i], b_h[j], acc[i][j], 0,0,0);
        acc[i][j] = __builtin_amdgcn_mfma_f32_16x16x32_bf16(a_h[i], b_l[j], acc[i][j], 0,0,0);
      }
    }
    __syncthreads();
  }
  #pragma unroll
  for (int i=0;i<2;i++){
    #pragma unroll
    for (int j=0;j<TN;j++){
      #pragma unroll
      for (int r=0;r<4;r++){
        int row = bm + wm*32 + i*16 + q*4 + r;
        int col = wn*(BN/2) + j*16 + n16;
        C[(size_t)row*BN+col] = acc[i][j][r];
      }
    }
  }
}

// ---------------- merged eta/delta/alpha first-stage GEMM (f32 A) ---------
__global__ __launch_bounds__(256) void gemm_eda1(
    const float* __restrict__ x,
    const unsigned short* __restrict__ BhT, const unsigned short* __restrict__ BlT,
    float* __restrict__ C0, float* __restrict__ C1, float* __restrict__ C2)
{
  constexpr int BM = 64, PK = 40, BN = 64, TN = 2, K = Dq;
  __shared__ __align__(16) unsigned short As[2][BM*PK];
  __shared__ __align__(16) unsigned short Bs[2][BN*PK];
  const int tid = threadIdx.x;
  const int bx = blockIdx.x;
  const int bm = blockIdx.y*BM;
  const int bnB = bx*BN;
  float* __restrict__ C = (bx==0) ? C0 : ((bx==1) ? C1 : C2);
  const int wv = tid>>6, lane = tid&63;
  const int n16 = lane&15, q = lane>>4;
  const int wm = wv>>1, wn = wv&1;

  f32x4 acc[2][TN];
  #pragma unroll
  for (int i=0;i<2;i++){
    #pragma unroll
    for (int j=0;j<TN;j++){ f32x4 z={0.f,0.f,0.f,0.f}; acc[i][j]=z; }
  }
  for (int k0=0;k0<K;k0+=32){
    #pragma unroll
    for (int c0=0;c0<BM*8;c0+=256){
      int c = c0 + tid;
      int row = c>>3, kg = (c&7)*4;
      float4 v = *(const float4*)&x[(size_t)(bm+row)*K + k0+kg];
      unsigned hp0 = cvt_pk_bf16(v.x, v.y), hp1 = cvt_pk_bf16(v.z, v.w);
      unsigned lp0 = cvt_pk_bf16(v.x-lo16f(hp0), v.y-hi16f(hp0));
      unsigned lp1 = cvt_pk_bf16(v.z-lo16f(hp1), v.w-hi16f(hp1));
      int off = row*PK+kg;
      uintx2 th = {hp0, hp1}, tl = {lp0, lp1};
      *(uintx2*)&As[0][off] = th;
      *(uintx2*)&As[1][off] = tl;
    }
    {
      int c = tid;
      int row = c>>2, kg = (c&3)*8;
      *(short8*)&Bs[0][row*PK+kg] = *(const short8*)&BhT[(size_t)(bnB+row)*K + k0+kg];
      *(short8*)&Bs[1][row*PK+kg] = *(const short8*)&BlT[(size_t)(bnB+row)*K + k0+kg];
    }
    __syncthreads();
    short8 a_h[2], a_l[2], b_h[TN], b_l[TN];
    #pragma unroll
    for (int i=0;i<2;i++){
      int r = wm*32 + i*16 + n16;
      a_h[i] = *(const short8*)&As[0][r*PK + q*8];
      a_l[i] = *(const short8*)&As[1][r*PK + q*8];
    }
    #pragma unroll
    for (int j=0;j<TN;j++){
      int r = wn*(BN/2) + j*16 + n16;
      b_h[j] = *(const short8*)&Bs[0][r*PK + q*8];
      b_l[j] = *(const short8*)&Bs[1][r*PK + q*8];
    }
    #pragma unroll
    for (int i=0;i<2;i++){
      #pragma unroll
      for (int j=0;j<TN;j++){
        acc[i][j] = __builtin_amdgcn_mfma_f32_16x16x32_bf16(a_h[i], b_h[j], acc[i][j], 0,0,0);
        acc[i][j] = __builtin_amdgcn_mfma_f32_16x16x32_bf16(a_l[i], b_h[j], acc[i][j], 0,0,0);
        acc[i][j] = __builtin_amdgcn_mfma_f32_16x16x32_bf16(a_h[i], b_l[j], acc[i][j], 0,0,0);
      }
    }
    __syncthreads();
  }
  #pragma unroll
  for (int i=0;i<2;i++){
    #pragma unroll
    for (int j=0;j<TN;j++){
      #pragma unroll
      for (int r=0;r<4;r++){
        int row = bm + wm*32 + i*16 + q*4 + r;
        int col = wn*(BN/2) + j*16 + n16;
        C[(size_t)row*BN+col] = acc[i][j][r];
      }
    }
  }
}

// ---------------- merged second-stage R=64 GEMMs, BM=64 tiles -------------
__global__ __launch_bounds__(256) void gemm_eda2(
    const float* __restrict__ te, const float* __restrict__ td, const float* __restrict__ ta,
    const unsigned short* __restrict__ usb,
    float* __restrict__ etab, float* __restrict__ deltab, float* __restrict__ alphab)
{
  constexpr int BM = 64, PK = 40, BN = 128, TN = 4, K = Rq, N = Hq;
  __shared__ __align__(16) unsigned short As[2][BM*PK];
  __shared__ __align__(16) unsigned short Bs[2][BN*PK];
  const int tid = threadIdx.x;
  const int bx = blockIdx.x;
  const int bm = blockIdx.y*BM;
  const float* __restrict__ Af = (bx==0) ? te : (bx==1) ? td : ta;
  const unsigned short* __restrict__ BhT = usb + ((bx==0) ? U_WE2TH : (bx==1) ? U_WD2TH : U_WA2TH);
  const unsigned short* __restrict__ BlT = usb + ((bx==0) ? U_WE2TL : (bx==1) ? U_WD2TL : U_WA2TL);
  float* __restrict__ C = (bx==0) ? etab : (bx==1) ? deltab : alphab;
  const int wv = tid>>6, lane = tid&63;
  const int n16 = lane&15, q = lane>>4;
  const int wm = wv>>1, wn = wv&1;

  f32x4 acc[2][TN];
  #pragma unroll
  for (int i=0;i<2;i++){
    #pragma unroll
    for (int j=0;j<TN;j++){ f32x4 z={0.f,0.f,0.f,0.f}; acc[i][j]=z; }
  }
  for (int k0=0;k0<K;k0+=32){
    #pragma unroll
    for (int c0=0;c0<BM*8;c0+=256){
      int c = c0 + tid;
      int row = c>>3, kg = (c&7)*4;
      float4 v = *(const float4*)&Af[(size_t)(bm+row)*K + k0+kg];
      unsigned hp0 = cvt_pk_bf16(v.x, v.y), hp1 = cvt_pk_bf16(v.z, v.w);
      unsigned lp0 = cvt_pk_bf16(v.x-lo16f(hp0), v.y-hi16f(hp0));
      unsigned lp1 = cvt_pk_bf16(v.z-lo16f(hp1), v.w-hi16f(hp1));
      int off = row*PK+kg;
      uintx2 th = {hp0, hp1}, tl = {lp0, lp1};
      *(uintx2*)&As[0][off] = th;
      *(uintx2*)&As[1][off] = tl;
    }
    #pragma unroll
    for (int c0=0;c0<BN*4;c0+=256){
      int c = c0 + tid;
      int row = c>>2, kg = (c&3)*8;
      *(short8*)&Bs[0][row*PK+kg] = *(const short8*)&BhT[(size_t)row*K + k0+kg];
      *(short8*)&Bs[1][row*PK+kg] = *(const short8*)&BlT[(size_t)row*K + k0+kg];
    }
    __syncthreads();
    short8 a_h[2], a_l[2], b_h[TN], b_l[TN];
    #pragma unroll
    for (int i=0;i<2;i++){
      int r = wm*32 + i*16 + n16;
      a_h[i] = *(const short8*)&As[0][r*PK + q*8];
      a_l[i] = *(const short8*)&As[1][r*PK + q*8];
    }
    #pragma unroll
    for (int j=0;j<TN;j++){
      int r = wn*(BN/2) + j*16 + n16;
      b_h[j] = *(const short8*)&Bs[0][r*PK + q*8];
      b_l[j] = *(const short8*)&Bs[1][r*PK + q*8];
    }
    #pragma unroll
    for (int i=0;i<2;i++){
      #pragma unroll
      for (int j=0;j<TN;j++){
        acc[i][j] = __builtin_amdgcn_mfma_f32_16x16x32_bf16(a_h[i], b_h[j], acc[i][j], 0,0,0);
        acc[i][j] = __builtin_amdgcn_mfma_f32_16x16x32_bf16(a_l[i], b_h[j], acc[i][j], 0,0,0);
        acc[i][j] = __builtin_amdgcn_mfma_f32_16x16x32_bf16(a_h[i], b_l[j], acc[i][j], 0,0,0);
      }
    }
    __syncthreads();
  }
  #pragma unroll
  for (int i=0;i<2;i++){
    #pragma unroll
    for (int j=0;j<TN;j++){
      #pragma unroll
      for (int r=0;r<4;r++){
        int row = bm + wm*32 + i*16 + q*4 + r;
        int col = wn*(BN/2) + j*16 + n16;
        float v = acc[i][j][r];
        v = (bx==2) ? sigmoidf_(v) : softplusf_(v);
        C[(size_t)row*N+col] = v;
      }
    }
  }
}

// ---------------- one-shot weight transpose+split (10 segments) ------------
__global__ __launch_bounds__(256) void splitT_all(
    const float* __restrict__ Wk,  const float* __restrict__ Wv,
    const float* __restrict__ We1, const float* __restrict__ Wd1,
    const float* __restrict__ Wa1, const float* __restrict__ Wg,
    const float* __restrict__ We2, const float* __restrict__ Wd2,
    const float* __restrict__ Wa2, const float* __restrict__ Wo,
    unsigned short* __restrict__ usb)
{
  size_t idx = (size_t)blockIdx.x*256 + threadIdx.x;
#define SEG(SRC, DH, DL, K_, N_) \
  { size_t sz = (size_t)(K_)*(N_); \
    if (idx < sz){ \
      int nn = (int)(idx/(K_)); int k = (int)(idx - (size_t)nn*(K_)); \
      float v = (SRC)[(size_t)k*(N_) + nn]; \
      unsigned short hh = bf16rn(v); \
      (DH)[idx] = hh; (DL)[idx] = bf16rn(v - bf16tof(hh)); \
      return; } \
    idx -= sz; }
  SEG(Wk,  usb+U_WKVTH,                    usb+U_WKVTL,                    Dq, Hq)
  SEG(Wv,  usb+U_WKVTH+(size_t)Hq*Dq,      usb+U_WKVTL+(size_t)Hq*Dq,      Dq, Hq)
  SEG(We1, usb+U_WEDATH,                   usb+U_WEDATL,                   Dq, Rq)
  SEG(Wd1, usb+U_WEDATH+(size_t)Rq*Dq,     usb+U_WEDATL+(size_t)Rq*Dq,     Dq, Rq)
  SEG(Wa1, usb+U_WEDATH+(size_t)2*Rq*Dq,   usb+U_WEDATL+(size_t)2*Rq*Dq,   Dq, Rq)
  SEG(Wg,  usb+U_WGTH,                     usb+U_WGTL,                     Dq, Dq)
  SEG(We2, usb+U_WE2TH,                    usb+U_WE2TL,                    Rq, Hq)
  SEG(Wd2, usb+U_WD2TH,                    usb+U_WD2TL,                    Rq, Hq)
  SEG(Wa2, usb+U_WA2TH,                    usb+U_WA2TL,                    Rq, Hq)
  SEG(Wo,  usb+U_WOTH,                     usb+U_WOTL,                     Hq, Dq)
#undef SEG
}

// conv+LN for k: emits pre-split bf16 hi/lo planes (same split of the same
// f32 value -> GEMM1 inputs bit-identical to the old in-kernel split). v: f32.
__global__ __launch_bounds__(128) void conv_ln_kernel(
  const float* __restrict__ k_raw, const float* __restrict__ v_raw,
  const float* __restrict__ conv_w, const float* __restrict__ conv_b,
  const float* __restrict__ kn_g, const float* __restrict__ kn_b,
  unsigned short* __restrict__ khi, unsigned short* __restrict__ klo,
  float* __restrict__ v_out)
{
  int s = blockIdx.x, b = blockIdx.y, which = blockIdx.z;
  int h = threadIdx.x;
  const float* src = (which==0) ? k_raw : v_raw;
  float acc = conv_b[h];
  #pragma unroll
  for (int j=0;j<4;j++){
    int ss = s-3+j;
    if (ss>=0) acc += conv_w[h*4+j]*src[((size_t)b*Sq+ss)*Hq + h];
  }
  if (which==0){
    __shared__ float red[4];
    float sv = acc, s2 = acc*acc;
    #pragma unroll
    for (int off=32; off>0; off>>=1){
      sv += __shfl_down(sv, off, 64);
      s2 += __shfl_down(s2, off, 64);
    }
    if ((h&63)==0){ red[(h>>6)*2]=sv; red[(h>>6)*2+1]=s2; }
    __syncthreads();
    float mean = (red[0]+red[2])*(1.f/128.f);
    float var  = (red[1]+red[3])*(1.f/128.f) - mean*mean;
    float y = (acc-mean)*rsqrtf(var+1e-5f)*kn_g[h]+kn_b[h];
    unsigned short hh = bf16rn(y);
    size_t idx = ((size_t)b*Sq+s)*Hq + h;
    khi[idx] = hh;
    klo[idx] = bf16rn(y - bf16tof(hh));
  } else {
    v_out[((size_t)b*Sq+s)*Hq + h] = acc;
  }
}

// ---- LDS overlay offsets (bytes) for the fused kernel's scan branch ----
#define OFF_KCH   0            // 64*128*2   = 16384
#define OFF_KCL   16384        // 16384
#define OFF_ACTH  32768        // 64*256*2   = 32768
#define OFF_SAM   65536        // 1024
#define OFF_SUS   66560        // 512
#define OFF_PEN   67072        // 64*12*4 = 3072
#define OFF_DRED  70144        // 8*256*4 = 8192
#define OFF_SUU   78336        // 32
#define OFF_SAB   78368        // 512
#define OFF_SEB   78880        // 512
#define OFF_SABP  79392        // 8
#define OFF_SEBP  79400        // 8
#define LDS_TOTAL 79408

// Fused kernel: blocks 0..3 = sequential scan (1 per batch);
// blocks 4.. = Wg GEMM tiles, co-scheduled on idle CUs.
// Scan schedule (3 barriers/chunk; __syncthreads drains vmcnt -> all global
// loads are issued RIGHT AFTER a barrier so the next phase covers them):
//   B1 -> [vv/dd + ab/eb issue] -> W1+b1 upd(t-1) -> GEMM1(kc LDS) -> gelu
//   -> publish -> B2 -> [aw/ew] -> stage kc(t+1) async -> GEMM2
//   -> epilogue/pen -> B3 -> en/grad/us -> b2 -> butterfly d[m] -> W2 upd
__global__ __launch_bounds__(512, 2) void fused_scan_wg(
  const unsigned short* __restrict__ khi, const unsigned short* __restrict__ klo,
  const float* __restrict__ v_c,
  const float* __restrict__ eta, const float* __restrict__ delta,
  const float* __restrict__ alpha,
  const float* __restrict__ mW1, const float* __restrict__ mb1,
  const float* __restrict__ mW2, const float* __restrict__ mb2,
  float* __restrict__ combined,
  const float* __restrict__ x,
  const unsigned short* __restrict__ WgTh, const unsigned short* __restrict__ WgTl,
  float* __restrict__ glog)
{
  __shared__ __align__(16) char smem[LDS_TOTAL];
  const int blk = blockIdx.x;
  const int tid = threadIdx.x;
  const int wv = tid >> 6;
  const int lane = tid & 63;
  const int n = lane & 15;
  const int q = lane >> 4;

  if (blk >= 4){
    // ================= Wg GEMM branch (512 thr, 128x128 tile) =================
    unsigned short* As_h = (unsigned short*)smem;          // 128*40
    unsigned short* As_l = As_h + 128*40;
    unsigned short* Bs_h = As_l + 128*40;
    unsigned short* Bs_l = Bs_h + 128*40;
    const int g = blk - 4;
    const int bm = (g>>3)*128, bn = (g&7)*128;
    const int wm = wv&3, wn = wv>>2;
    f32x4 acc[2][4];
    #pragma unroll
    for (int i=0;i<2;i++){
      #pragma unroll
      for (int j=0;j<4;j++){ f32x4 z={0.f,0.f,0.f,0.f}; acc[i][j]=z; }
    }
    for (int k0=0;k0<Dq;k0+=32){
      #pragma unroll
      for (int r=0;r<2;r++){
        int idx = tid + 512*r;
        int row = idx>>3, kg = (idx&7)*4;
        float4 v = *(const float4*)&x[(size_t)(bm+row)*Dq + k0+kg];
        unsigned hp0 = cvt_pk_bf16(v.x, v.y), hp1 = cvt_pk_bf16(v.z, v.w);
        unsigned lp0 = cvt_pk_bf16(v.x-lo16f(hp0), v.y-hi16f(hp0));
        unsigned lp1 = cvt_pk_bf16(v.z-lo16f(hp1), v.w-hi16f(hp1));
        int off = row*40+kg;
        uintx2 th = {hp0, hp1}, tl = {lp0, lp1};
        *(uintx2*)&As_h[off] = th;
        *(uintx2*)&As_l[off] = tl;
      }
      {
        int row = tid>>2, kg = (tid&3)*8;
        *(short8*)&Bs_h[row*40+kg] = *(const short8*)&WgTh[(size_t)(bn+row)*Dq + k0+kg];
        *(short8*)&Bs_l[row*40+kg] = *(const short8*)&WgTl[(size_t)(bn+row)*Dq + k0+kg];
      }
      __syncthreads();
      short8 a_h[2], a_l[2], b_h[4], b_l[4];
      #pragma unroll
      for (int i=0;i<2;i++){
        int r = wm*32 + i*16 + n;
        a_h[i] = *(const short8*)&As_h[r*40 + q*8];
        a_l[i] = *(const short8*)&As_l[r*40 + q*8];
      }
      #pragma unroll
      for (int j=0;j<4;j++){
        int r = wn*64 + j*16 + n;
        b_h[j] = *(const short8*)&Bs_h[r*40 + q*8];
        b_l[j] = *(const short8*)&Bs_l[r*40 + q*8];
      }
      #pragma unroll
      for (int i=0;i<2;i++){
        #pragma unroll
        for (int j=0;j<4;j++){
          acc[i][j] = __builtin_amdgcn_mfma_f32_16x16x32_bf16(a_h[i], b_h[j], acc[i][j], 0,0,0);
          acc[i][j] = __builtin_amdgcn_mfma_f32_16x16x32_bf16(a_l[i], b_h[j], acc[i][j], 0,0,0);
          acc[i][j] = __builtin_amdgcn_mfma_f32_16x16x32_bf16(a_h[i], b_l[j], acc[i][j], 0,0,0);
        }
      }
      __syncthreads();
    }
    #pragma unroll
    for (int i=0;i<2;i++){
      #pragma unroll
      for (int j=0;j<4;j++){
        #pragma unroll
        for (int r=0;r<4;r++){
          int row = bm + wm*32 + i*16 + q*4 + r;
          int col = bn + wn*64 + j*16 + n;
          glog[(size_t)row*Dq+col] = acc[i][j][r];
        }
      }
    }
    return;
  }

  // ================= scan branch =================
  unsigned short* kc_hi  = (unsigned short*)(smem + OFF_KCH);
  unsigned short* kc_lo  = (unsigned short*)(smem + OFF_KCL);
  unsigned short* act_hi = (unsigned short*)(smem + OFF_ACTH);
  float* Sam = (float*)(smem + OFF_SAM);
  float* Sus = (float*)(smem + OFF_SUS);
  float* pen = (float*)(smem + OFF_PEN);   // [c][12] (8 wave partials)
  float* Dred= (float*)(smem + OFF_DRED);  // [wv][256] per-wave d = us.W2old partials
  float* Suu = (float*)(smem + OFF_SUU);   // [8]  per-wave us.us partials
  float* Sab = (float*)(smem + OFF_SAB);
  float* Seb = (float*)(smem + OFF_SEB);
  float* Sabp = (float*)(smem + OFF_SABP);
  float* Sebp = (float*)(smem + OFF_SEBP);

  const int b = blk;
  const int h = wv*16 + n;          // W2 row ownership (A-frag of swapped GEMM2)
  float w1m[2][4][8];   // W1[m=(2wv+tt)*16+n][h=ks*32+q*8+j]
  float w2m[8][8];      // W2[h=wv*16+n][m=ks2*32+q*8+j]
  float b1reg[2];       // b1[m=(2wv+tt)*16+n]
  float b2n[4];         // b2[h2=wv*16+q*4+r]  (swapped-GEMM2 output rows)
  #pragma unroll
  for (int tt=0;tt<2;tt++){
    int m = (2*wv+tt)*16 + n;
    #pragma unroll
    for (int ks=0;ks<4;ks++){
      const float* p = mW1 + (size_t)m*Hq + ks*32 + q*8;
      #pragma unroll
      for (int j=0;j<8;j++) w1m[tt][ks][j] = p[j];
    }
    b1reg[tt] = mb1[m];
  }
  {
    #pragma unroll
    for (int ks2=0;ks2<8;ks2++){
      const float* p = mW2 + (size_t)h*Mq + ks2*32 + q*8;
      #pragma unroll
      for (int j=0;j<8;j++) w2m[ks2][j] = p[j];
    }
    #pragma unroll
    for (int r=0;r<4;r++) b2n[r] = mb2[wv*16 + q*4 + r];
  }
  // cross-chunk carried scalars (chunk t-1 values, consumed at t's top)
  float aw = 0.f, ew = 0.f;
  float am_own[2] = {0.f, 0.f};

  const unsigned short* khb = khi + (size_t)b*Sq*Hq;
  const unsigned short* klb = klo + (size_t)b*Sq*Hq;

  // ---- async kc staging setup: pre-swizzled per-lane global offsets so the
  // linear global_load_lds write (base + lane*16) produces the swizzled LDS
  // image LDS[c*128 + pg*8 + e] = k[c][((pg^(c&15))<<3)+e].
  const int c0s = (wv*2+0)*4 + (lane>>4);
  const int c1s = (wv*2+1)*4 + (lane>>4);
  const int soff0 = c0s*Hq + ((((lane&15)^(c0s&15)))<<3);
  const int soff1 = c1s*Hq + ((((lane&15)^(c1s&15)))<<3);
  char* d_kh0 = smem + OFF_KCH + (wv*2+0)*1024;
  char* d_kh1 = smem + OFF_KCH + (wv*2+1)*1024;
  char* d_kl0 = smem + OFF_KCL + (wv*2+0)*1024;
  char* d_kl1 = smem + OFF_KCL + (wv*2+1)*1024;
  // prologue: stage chunk 0 (drains at B1 of t=0 via __syncthreads vmcnt(0))
  g2lds16(khb + soff0, d_kh0);
  g2lds16(khb + soff1, d_kh1);
  g2lds16(klb + soff0, d_kl0);
  g2lds16(klb + soff1, d_kl1);

  for (int t=0; t<NCHUNK; ++t){
    const size_t base = ((size_t)b*Sq + (size_t)t*Cq)*Hq;
    __syncthreads();   // B1: kc(t) staged; orders prev-chunk Sus/Dred/Suu

    // ---- issue this chunk's global loads NOW (drain at B2 under GEMM1) ----
    f32x4 vvv[4], ddd[4];
    #pragma unroll
    for (int ct=0;ct<4;ct++){
      size_t off = base + (size_t)(ct*16+n)*Hq + wv*16 + q*4;
      vvv[ct] = *(const f32x4*)&v_c[off];
      ddd[ct] = *(const f32x4*)&delta[off];
    }
    float ab_=0.f, eb_=0.f;
    if (tid < 128){
      ab_ = alpha[base + 63*Hq + tid];
      eb_ = eta[base + 63*Hq + tid];
    }

    // ---- W1 + b1 update from chunk t-1 (reads Sus/Dred/Suu) ----
    if (t > 0){
      float4 s0[4], s1[4];
      #pragma unroll
      for (int ks=0;ks<4;ks++){
        s0[ks] = *(const float4*)&Sus[ks*32 + q*8];
        s1[ks] = *(const float4*)&Sus[ks*32 + q*8 + 4];
      }
      float4 u0 = *(const float4*)&Suu[0];
      float4 u1 = *(const float4*)&Suu[4];
      float uu = u0.x+u0.y+u0.z+u0.w+u1.x+u1.y+u1.z+u1.w;
      #pragma unroll
      for (int tt=0;tt<2;tt++){
        int m = (2*wv+tt)*16 + n;
        float amm = am_own[tt];
        float eam = ew*amm;
        #pragma unroll
        for (int ks=0;ks<4;ks++){
          #pragma unroll
          for (int j=0;j<4;j++){
            w1m[tt][ks][j]   = aw*w1m[tt][ks][j]   - eam*s0[ks][j];
            w1m[tt][ks][j+4] = aw*w1m[tt][ks][j+4] - eam*s1[ks][j];
          }
        }
        float dsum = 0.f;
        #pragma unroll
        for (int w8=0;w8<8;w8++) dsum += Dred[w8*256 + m];
        // b1u = us.nW2[:,m] = aw*dsum - ew*uu*am[m]
        b1reg[tt] = aw*b1reg[tt] - ew*(aw*dsum - ew*uu*amm);
      }
    }

    // ---- GEMM1: inter = kc @ W1^T (kc hi/lo from LDS, W1 hi/lo: 3-MFMA) ----
    f32x4 acc1[2][4];
    #pragma unroll
    for (int tt=0;tt<2;tt++){
      #pragma unroll
      for (int ct=0;ct<4;ct++){ f32x4 z={0.f,0.f,0.f,0.f}; acc1[tt][ct]=z; }
    }
    __builtin_amdgcn_s_setprio(1);
    #pragma unroll
    for (int ks=0;ks<4;ks++){
      pk8 BH[2], BL[2];
      #pragma unroll
      for (int tt=0;tt<2;tt++){
        #pragma unroll
        for (int jp=0;jp<4;jp++){
          float a0 = w1m[tt][ks][2*jp], a1 = w1m[tt][ks][2*jp+1];
          unsigned hp = cvt_pk_bf16(a0, a1);
          BH[tt].u[jp] = hp;
          BL[tt].u[jp] = cvt_pk_bf16(a0 - lo16f(hp), a1 - hi16f(hp));
        }
      }
      #pragma unroll
      for (int ct=0;ct<4;ct++){
        int c = ct*16 + n;
        int off = c*Hq + ((((ks*4+q)^n))<<3);
        short8 ah = *(const short8*)&kc_hi[off];
        short8 al = *(const short8*)&kc_lo[off];
        #pragma unroll
        for (int tt=0;tt<2;tt++){
          acc1[tt][ct] = __builtin_amdgcn_mfma_f32_16x16x32_bf16(ah, BH[tt].s, acc1[tt][ct], 0,0,0);
          acc1[tt][ct] = __builtin_amdgcn_mfma_f32_16x16x32_bf16(al, BH[tt].s, acc1[tt][ct], 0,0,0);
          acc1[tt][ct] = __builtin_amdgcn_mfma_f32_16x16x32_bf16(ah, BL[tt].s, acc1[tt][ct], 0,0,0);
        }
      }
    }
    __builtin_amdgcn_s_setprio(0);
    // gelu -> act_hi + am
    #pragma unroll
    for (int tt=0;tt<2;tt++){
      int m = (2*wv+tt)*16 + n;
      float b1v = b1reg[tt];
      float amsum = 0.f;
      #pragma unroll
      for (int ct=0;ct<4;ct++){
        #pragma unroll
        for (int r=0;r<4;r++){
          float g = gelu_fast(acc1[tt][ct][r] + b1v);
          amsum += g;
          int c = ct*16 + q*4 + r;
          int pg = (m>>3) ^ (c & 15);
          act_hi[c*Mq + (pg<<3) + (m&7)] = bf16rn(g);
        }
      }
      amsum += __shfl_xor(amsum, 16, 64);
      amsum += __shfl_xor(amsum, 32, 64);
      am_own[tt] = amsum*(1.f/64.f);
      if (q==0) Sam[m] = am_own[tt];
    }
    // publish alpha/eta
    if (tid < 128){ Sab[tid] = ab_; Seb[tid] = eb_; }
    if (wv < 2){
      float a2 = ab_, e2 = eb_;
      #pragma unroll
      for (int mk=1;mk<64;mk<<=1){ a2 += __shfl_xor(a2,mk,64); e2 += __shfl_xor(e2,mk,64); }
      if (lane==0){ Sabp[wv] = a2; Sebp[wv] = e2; }
    }
    __syncthreads();   // B2: act/Sam/Sab/Sabp ready; all GEMM1 kc reads done

    // ---- aw/ew for this chunk (Sabp published pre-B2; read early to hide
    //      the LDS latency ahead of the post-B3 dependency chain) ----
    aw = (Sabp[0]+Sabp[1])*(1.f/128.f);
    ew = (Sebp[0]+Sebp[1])*(1.f/128.f);

    // ---- stage kc(t+1) into LDS (async; drains at B3 under GEMM2 cover) ----
    {
      const size_t nb = (size_t)((t+1<NCHUNK)?(t+1):t)*Cq*Hq;
      g2lds16(khb + nb + soff0, d_kh0);
      g2lds16(khb + nb + soff1, d_kh1);
      g2lds16(klb + nb + soff0, d_kl0);
      g2lds16(klb + nb + soff1, d_kl1);
    }

    // ---- GEMM2 (operand-swapped): out^T = W2 @ act^T -> out[h2][c] ----
    f32x4 acc2[4];
    #pragma unroll
    for (int ct=0;ct<4;ct++){ f32x4 z={0.f,0.f,0.f,0.f}; acc2[ct]=z; }
    __builtin_amdgcn_s_setprio(1);
    #pragma unroll
    for (int ks2=0;ks2<8;ks2++){
      pk8 BH, BL;
      #pragma unroll
      for (int jp=0;jp<4;jp++){
        float a0 = w2m[ks2][2*jp], a1 = w2m[ks2][2*jp+1];
        unsigned hp = cvt_pk_bf16(a0, a1);
        BH.u[jp] = hp;
        BL.u[jp] = cvt_pk_bf16(a0 - lo16f(hp), a1 - hi16f(hp));
      }
      #pragma unroll
      for (int ct=0;ct<4;ct++){
        int c = ct*16 + n;
        int off = c*Mq + ((((ks2*4+q)^n))<<3);
        short8 ah = *(const short8*)&act_hi[off];
        acc2[ct] = __builtin_amdgcn_mfma_f32_16x16x32_bf16(BH.s, ah, acc2[ct], 0,0,0);
        acc2[ct] = __builtin_amdgcn_mfma_f32_16x16x32_bf16(BL.s, ah, acc2[ct], 0,0,0);
      }
    }
    __builtin_amdgcn_s_setprio(0);

    // ---- epilogue: float4 out store, err, pen partials (2 shfl) ----
    float err[4][4];
    {
      float* cb = combined + base;
      #pragma unroll
      for (int ct=0;ct<4;ct++){
        int c = ct*16 + n;
        f32x4 ov;
        #pragma unroll
        for (int r=0;r<4;r++){
          float o = acc2[ct][r] + b2n[r];
          ov[r] = o;
          err[ct][r] = o - vvv[ct][r];
        }
        *(f32x4*)&cb[(size_t)c*Hq + wv*16 + q*4] = ov;
      }
      #pragma unroll
      for (int ct=0;ct<4;ct++){
        float s = err[ct][0]*err[ct][0] + err[ct][1]*err[ct][1]
                + err[ct][2]*err[ct][2] + err[ct][3]*err[ct][3];
        s += __shfl_xor(s, 16, 64);
        s += __shfl_xor(s, 32, 64);
        if (q==0) pen[(ct*16+n)*12 + wv] = s;
      }
    }
    __syncthreads();   // B3: pen ready; kc(t+1) staging drained (vmcnt(0))

    // ---- en (direct pen reads) -> grad -> us (n-butterfly) ----
    float en_c[4];
    #pragma unroll
    for (int ct=0;ct<4;ct++){
      int c = ct*16 + n;
      float4 e0 = *(const float4*)&pen[c*12];
      float4 e1 = *(const float4*)&pen[c*12+4];
      en_c[ct] = sqrtf(e0.x+e0.y+e0.z+e0.w+e1.x+e1.y+e1.z+e1.w);
    }
    float us_r[4];
    #pragma unroll
    for (int r=0;r<4;r++){
      float s = 0.f;
      #pragma unroll
      for (int ct=0;ct<4;ct++){
        float e = err[ct][r];
        float dvv = ddd[ct][r];
        float en = en_c[ct];
        float g = (en > dvv) ? dvv*e*__builtin_amdgcn_rcpf(en+1e-9f) : e;
        s += g;
      }
      s += __shfl_xor(s,1,64); s += __shfl_xor(s,2,64);
      s += __shfl_xor(s,4,64); s += __shfl_xor(s,8,64);
      us_r[r] = s*(1.f/64.f);     // us[h2 = wv*16+q*4+r], replicated over n
    }
    if (n==0){
      #pragma unroll
      for (int r=0;r<4;r++) Sus[wv*16 + q*4 + r] = us_r[r];
    }
    // uu partial over this wave's 16 h (sum over r in-thread, then over q)
    {
      float uun = us_r[0]*us_r[0] + us_r[1]*us_r[1]
                + us_r[2]*us_r[2] + us_r[3]*us_r[3];
      uun += __shfl_xor(uun, 16, 64);
      uun += __shfl_xor(uun, 32, 64);
      if (lane==0) Suu[wv] = uun;
    }
    // ---- b2 update (in-register, float4 Sab/Seb reads) ----
    {
      f32x4 sab = *(const f32x4*)&Sab[wv*16 + q*4];
      f32x4 seb = *(const f32x4*)&Seb[wv*16 + q*4];
      #pragma unroll
      for (int r=0;r<4;r++) b2n[r] = sab[r]*b2n[r] - seb[r]*us_r[r];
    }
    // ---- ush at W2-ownership lane (h = wv*16+n) via shfl pulls ----
    float ush;
    {
      int src = (n>>2)<<4;     // any lane in q-group n>>2 (us_r replicated over n)
      float p0 = __shfl(us_r[0], src, 64);
      float p1 = __shfl(us_r[1], src, 64);
      float p2 = __shfl(us_r[2], src, 64);
      float p3 = __shfl(us_r[3], src, 64);
      int rr = n&3;
      ush = (rr==0) ? p0 : (rr==1) ? p1 : (rr==2) ? p2 : p3;
    }

    // ---- d[m] = us . W2_old[:,m]: reduce-scatter butterfly over n ----
    {
      const bool bb0 = (n&1);
      float p1[8][4];
      #pragma unroll
      for (int k2=0;k2<8;k2++){
        #pragma unroll
        for (int l=0;l<4;l++){
          float mine = ush * (bb0 ? w2m[k2][l+4] : w2m[k2][l]);
          float oth  = ush * (bb0 ? w2m[k2][l]   : w2m[k2][l+4]);
          p1[k2][l] = mine + __shfl_xor(oth, 1, 64);
        }
      }
      const bool bb1 = (n>>1)&1;
      float p2[4][4];
      #pragma unroll
      for (int k2=0;k2<4;k2++){
        #pragma unroll
        for (int l=0;l<4;l++){
          float mine = bb1 ? p1[2*k2+1][l] : p1[2*k2][l];
          float oth  = bb1 ? p1[2*k2][l]   : p1[2*k2+1][l];
          p2[k2][l] = mine + __shfl_xor(oth, 2, 64);
        }
      }
      const bool bb2 = (n>>2)&1;
      float p3[2][4];
      #pragma unroll
      for (int k2=0;k2<2;k2++){
        #pragma unroll
        for (int l=0;l<4;l++){
          float mine = bb2 ? p2[2*k2+1][l] : p2[2*k2][l];
          float oth  = bb2 ? p2[2*k2][l]   : p2[2*k2+1][l];
          p3[k2][l] = mine + __shfl_xor(oth, 4, 64);
        }
      }
      const bool bb3 = (n>>3)&1;
      float4 p4;
      {
        float m0 = bb3 ? p3[1][0] : p3[0][0];
        float o0 = bb3 ? p3[0][0] : p3[1][0];
        p4.x = m0 + __shfl_xor(o0, 8, 64);
        float m1 = bb3 ? p3[1][1] : p3[0][1];
        float o1 = bb3 ? p3[0][1] : p3[1][1];
        p4.y = m1 + __shfl_xor(o1, 8, 64);
        float m2 = bb3 ? p3[1][2] : p3[0][2];
        float o2 = bb3 ? p3[0][2] : p3[1][2];
        p4.z = m2 + __shfl_xor(o2, 8, 64);
        float m3 = bb3 ? p3[1][3] : p3[0][3];
        float o3 = bb3 ? p3[0][3] : p3[1][3];
        p4.w = m3 + __shfl_xor(o3, 8, 64);
      }
      // lane owns 4 consecutive m: (n>>1)*32 + q*8 + (n&1)*4 + [0..3]
      int base_m = (n>>1)*32 + q*8 + (n&1)*4;
      *(float4*)&Dred[wv*256 + base_m] = p4;
    }

    // ---- W2 update (uses ush at h=wv*16+n, Sam reads; consumed by
    //      GEMM2(t+1) which is past B2(t+1) -> no extra barrier) ----
    {
      float eus = ew*ush;
      #pragma unroll
      for (int ks2=0;ks2<8;ks2++){
        float4 a0 = *(const float4*)&Sam[ks2*32 + q*8];
        float4 a1 = *(const float4*)&Sam[ks2*32 + q*8 + 4];
        #pragma unroll
        for (int j=0;j<4;j++){
          w2m[ks2][j]   = aw*w2m[ks2][j]   - eus*a0[j];
          w2m[ks2][j+4] = aw*w2m[ks2][j+4] - eus*a1[j];
        }
      }
    }
    // W1 + b1 update deferred to top of chunk t+1 (after B1).
  }
}

extern "C" void kernel_launch(void* const* d_in, const int* in_sizes, int n_in,
                              void* d_out, int out_size, void* d_ws, size_t ws_size,
                              hipStream_t stream)
{
  const float* x    = (const float*)d_in[0];
  // d_in[1]=Wq, d_in[14],[15]=qn_g/qn_b: dead (q path unused by output).
  const float* Wk   = (const float*)d_in[2];
  const float* Wv   = (const float*)d_in[3];
  const float* Wo   = (const float*)d_in[4];
  const float* Wg   = (const float*)d_in[5];
  const float* We1  = (const float*)d_in[6];
  const float* We2  = (const float*)d_in[7];
  const float* Wd1  = (const float*)d_in[8];
  const float* Wd2  = (const float*)d_in[9];
  const float* Wa1  = (const float*)d_in[10];
  const float* Wa2  = (const float*)d_in[11];
  const float* conv_w = (const float*)d_in[12];
  const float* conv_b = (const float*)d_in[13];
  const float* kn_g = (const float*)d_in[16];
  const float* kn_b = (const float*)d_in[17];
  const float* mW1  = (const float*)d_in[18];
  const float* mb1  = (const float*)d_in[19];
  const float* mW2  = (const float*)d_in[20];
  const float* mb2  = (const float*)d_in[21];
  float* out = (float*)d_out;

  float* ws = (float*)d_ws;
  size_t o = 0;
  float* k_raw = ws + o; o += (size_t)BSq*Hq;
  float* v_raw = ws + o; o += (size_t)BSq*Hq;
  float* te    = ws + o; o += (size_t)BSq*Rq;
  float* td    = ws + o; o += (size_t)BSq*Rq;
  float* ta    = ws + o; o += (size_t)BSq*Rq;
  float* glog  = ws + o; o += (size_t)BSq*Dq;
  float* etab  = ws + o; o += (size_t)BSq*Hq;
  float* deltab= ws + o; o += (size_t)BSq*Hq;
  float* alphab= ws + o; o += (size_t)BSq*Hq;
  float* kslot = ws + o; o += (size_t)BSq*Hq;   // khi/klo bf16 planes (8MB slot)
  float* v_c   = ws + o; o += (size_t)BSq*Hq;
  float* comb  = ws + o; o += (size_t)BSq*Hq;
  unsigned short* usb = (unsigned short*)(ws + o);

  unsigned short* khi = (unsigned short*)kslot;
  unsigned short* klo = khi + (size_t)BSq*Hq;

  // one-shot weight transpose+split (all 10 weights, 1 launch)
  {
    size_t total = 2*(size_t)Hq*Dq + 3*(size_t)Rq*Dq + (size_t)Dq*Dq
                 + 3*(size_t)Hq*Rq + (size_t)Dq*Hq;
    splitT_all<<<(unsigned)(total/256), 256, 0, stream>>>(
        Wk, Wv, We1, Wd1, Wa1, Wg, We2, Wd2, Wa2, Wo, usb);
  }

  dim3 blk(256);
  // merged x-projections, f32-A direct (splitX removed):
  gemm_kv  <<<dim3(2, BSq/64), blk, 0, stream>>>(x, usb+U_WKVTH, usb+U_WKVTL, k_raw, v_raw);
  gemm_eda1<<<dim3(3, BSq/64), blk, 0, stream>>>(x, usb+U_WEDATH, usb+U_WEDATL, te, td, ta);
  // merged second-stage R=64 GEMMs (eta/delta/alpha)
  gemm_eda2<<<dim3(3, BSq/64), blk, 0, stream>>>(te, td, ta, usb, etab, deltab, alphab);
  conv_ln_kernel<<<dim3(Sq, Bq, 2), dim3(128), 0, stream>>>(
      k_raw, v_raw, conv_w, conv_b, kn_g, kn_b, khi, klo, v_c);
  // fused: scan (blocks 0..3) + Wg GEMM (blocks 4..1027) co-scheduled
  fused_scan_wg<<<dim3(4 + (BSq/128)*(Dq/128)), dim3(512), 0, stream>>>(
      khi, klo, v_c, etab, deltab, alphab, mW1, mb1, mW2, mb2, comb,
      x, usb+U_WGTH, usb+U_WGTL, glog);
  gemm_bf3<128,3><<<dim3(Dq/128, BSq/128), blk, 0, stream>>>(comb, usb+U_WOTH, usb+U_WOTL, out, glog, Dq, Hq);
}

// Round 10
// 1199.835 us; speedup vs baseline: 1.6747x; 1.0025x over previous
//
#include <hip/hip_runtime.h>
#include <math.h>

#define Bq 4
#define Sq 4096
#define Dq 1024
#define Hq 128
#define Mq 256
#define Rq 64
#define Cq 64
#define NCHUNK 64
#define BSq (Bq*Sq)

typedef __attribute__((ext_vector_type(8))) short short8;
typedef __attribute__((ext_vector_type(4))) float f32x4;
typedef __attribute__((ext_vector_type(2))) unsigned int uintx2;

// ---- packed-weight arena layout (elements of unsigned short) ----
// x-projection pack: rows [Wk(128); Wv(128); We1(64); Wd1(64); Wa1(64)] = 448
#define U_XPH   ((size_t)0)
#define U_XPL   (U_XPH + (size_t)448*Dq)
#define U_WGTH  (U_XPL + (size_t)448*Dq)
#define U_WGTL  (U_WGTH + (size_t)Dq*Dq)
#define U_WE2TH (U_WGTL + (size_t)Dq*Dq)
#define U_WE2TL (U_WE2TH + (size_t)Hq*Rq)
#define U_WD2TH (U_WE2TL + (size_t)Hq*Rq)
#define U_WD2TL (U_WD2TH + (size_t)Hq*Rq)
#define U_WA2TH (U_WD2TL + (size_t)Hq*Rq)
#define U_WA2TL (U_WA2TH + (size_t)Hq*Rq)
#define U_WOTH  (U_WA2TL + (size_t)Hq*Rq)
#define U_WOTL  (U_WOTH + (size_t)Dq*Hq)
#define U_END   (U_WOTL + (size_t)Dq*Hq)

__device__ __forceinline__ float softplusf_(float x){
  return fmaxf(x,0.f) + log1pf(expf(-fabsf(x)));
}
__device__ __forceinline__ float sigmoidf_(float x){
  return 1.f/(1.f+__expf(-x));
}
__device__ __forceinline__ unsigned short bf16rn(float x){
  unsigned u = __float_as_uint(x);
  u += 0x7fffu + ((u>>16)&1u);
  return (unsigned short)(u>>16);
}
__device__ __forceinline__ float bf16tof(unsigned short s){
  return __uint_as_float(((unsigned)s)<<16);
}
// packed 2xf32 -> 2xbf16 in one instruction (RNE, matches bf16rn).
__device__ __forceinline__ unsigned cvt_pk_bf16(float a, float b){
  unsigned r;
  asm("v_cvt_pk_bf16_f32 %0, %1, %2" : "=v"(r) : "v"(a), "v"(b));
  return r;
}
__device__ __forceinline__ float lo16f(unsigned p){ return __uint_as_float(p<<16); }
__device__ __forceinline__ float hi16f(unsigned p){ return __uint_as_float(p & 0xffff0000u); }
union pk8 { unsigned u[4]; short8 s; };

// async global->LDS 16B copy: per-lane global src, wave-uniform LDS base
// (HW adds lane*16 to the LDS dest). C-style addrspace casts (CK pattern).
__device__ __forceinline__ void g2lds16(const unsigned short* g, void* lds){
  __builtin_amdgcn_global_load_lds(
      (const __attribute__((address_space(1))) unsigned int*)(const void*)g,
      (__attribute__((address_space(3))) unsigned int*)lds,
      16, 0, 0);
}

// branchless erf-gelu (A&S 7.1.26, |err|<=1.5e-7)
__device__ __forceinline__ float gelu_fast(float x){
  float z  = x*0.70710678118f;
  float az = fabsf(z);
  float t  = __builtin_amdgcn_rcpf(fmaf(0.3275911f, az, 1.f));
  float p  = fmaf(t, 1.061405429f, -1.453152027f);
  p = fmaf(t, p, 1.421413741f);
  p = fmaf(t, p, -0.284496736f);
  p = fmaf(t, p, 0.254829592f);
  p = p*t;
  float e  = __expf(-az*az);
  float er = copysignf(1.f - p*e, z);
  return 0.5f*x*(1.f + er);
}

// ---------------- bf16x3 MFMA GEMM, f32 A (cvt_pk staging), BM=128 --------
template<int BN, int ACT>
__global__ __launch_bounds__(256) void gemm_bf3(
    const float* __restrict__ Af,
    const unsigned short* __restrict__ BhT, const unsigned short* __restrict__ BlT,
    float* __restrict__ C, const float* __restrict__ gate, int N, int K)
{
  constexpr int BM = 128;
  constexpr int PK = 40;
  constexpr int TN = BN/32;
  __shared__ __align__(16) unsigned short As[2][BM*PK];
  __shared__ __align__(16) unsigned short Bs[2][BN*PK];
  const int tid = threadIdx.x;
  const int bm = blockIdx.y*BM, bn = blockIdx.x*BN;
  const int wv = tid>>6, lane = tid&63;
  const int n16 = lane&15, q = lane>>4;
  const int wm = wv>>1, wn = wv&1;

  f32x4 acc[4][TN];
  #pragma unroll
  for (int i=0;i<4;i++){
    #pragma unroll
    for (int j=0;j<TN;j++){ f32x4 z={0.f,0.f,0.f,0.f}; acc[i][j]=z; }
  }
  for (int k0=0;k0<K;k0+=32){
    #pragma unroll
    for (int c0=0;c0<BM*8;c0+=256){
      int c = c0 + tid;
      int row = c>>3, kg = (c&7)*4;
      float4 v = *(const float4*)&Af[(size_t)(bm+row)*K + k0+kg];
      unsigned hp0 = cvt_pk_bf16(v.x, v.y), hp1 = cvt_pk_bf16(v.z, v.w);
      unsigned lp0 = cvt_pk_bf16(v.x-lo16f(hp0), v.y-hi16f(hp0));
      unsigned lp1 = cvt_pk_bf16(v.z-lo16f(hp1), v.w-hi16f(hp1));
      int off = row*PK+kg;
      uintx2 th = {hp0, hp1}, tl = {lp0, lp1};
      *(uintx2*)&As[0][off] = th;
      *(uintx2*)&As[1][off] = tl;
    }
    #pragma unroll
    for (int c0=0;c0<BN*4;c0+=256){
      int c = c0 + tid;
      int row = c>>2, kg = (c&3)*8;
      *(short8*)&Bs[0][row*PK+kg] = *(const short8*)&BhT[(size_t)(bn+row)*K + k0+kg];
      *(short8*)&Bs[1][row*PK+kg] = *(const short8*)&BlT[(size_t)(bn+row)*K + k0+kg];
    }
    __syncthreads();
    short8 a_h[4], a_l[4], b_h[TN], b_l[TN];
    #pragma unroll
    for (int i=0;i<4;i++){
      int r = wm*64 + i*16 + n16;
      a_h[i] = *(const short8*)&As[0][r*PK + q*8];
      a_l[i] = *(const short8*)&As[1][r*PK + q*8];
    }
    #pragma unroll
    for (int j=0;j<TN;j++){
      int r = wn*(BN/2) + j*16 + n16;
      b_h[j] = *(const short8*)&Bs[0][r*PK + q*8];
      b_l[j] = *(const short8*)&Bs[1][r*PK + q*8];
    }
    #pragma unroll
    for (int i=0;i<4;i++){
      #pragma unroll
      for (int j=0;j<TN;j++){
        acc[i][j] = __builtin_amdgcn_mfma_f32_16x16x32_bf16(a_h[i], b_h[j], acc[i][j], 0,0,0);
        acc[i][j] = __builtin_amdgcn_mfma_f32_16x16x32_bf16(a_l[i], b_h[j], acc[i][j], 0,0,0);
        acc[i][j] = __builtin_amdgcn_mfma_f32_16x16x32_bf16(a_h[i], b_l[j], acc[i][j], 0,0,0);
      }
    }
    __syncthreads();
  }
  #pragma unroll
  for (int i=0;i<4;i++){
    #pragma unroll
    for (int j=0;j<TN;j++){
      #pragma unroll
      for (int r=0;r<4;r++){
        int row = bm + wm*64 + i*16 + q*4 + r;
        int col = bn + wn*(BN/2) + j*16 + n16;
        float v = acc[i][j][r];
        if (ACT==1) v = softplusf_(v);
        else if (ACT==2) v = sigmoidf_(v);
        else if (ACT==3) v *= sigmoidf_(gate[(size_t)row*N+col]);
        C[(size_t)row*N+col] = v;
      }
    }
  }
}

// ---------------- merged x-projection GEMM (one dispatch, 4 tiles) --------
// f32 A direct (cvt_pk staging), BM=64, BN=128. Packed-B rows
// [Wk;Wv;We1;Wd1;Wa1]; bx row offsets {0,128,256,320}:
//   bx=0 -> k_raw[.][128]; bx=1 -> v_raw[.][128];
//   bx=2 -> cols [We1|Wd1] -> te|td; bx=3 -> cols [Wd1|Wa1] -> discard|ta.
__global__ __launch_bounds__(256) void gemm_xproj(
    const float* __restrict__ x,
    const unsigned short* __restrict__ BhT, const unsigned short* __restrict__ BlT,
    float* __restrict__ k_raw, float* __restrict__ v_raw,
    float* __restrict__ te, float* __restrict__ td, float* __restrict__ ta)
{
  constexpr int BM = 64, PK = 40, BN = 128, TN = 4, K = Dq;
  __shared__ __align__(16) unsigned short As[2][BM*PK];
  __shared__ __align__(16) unsigned short Bs[2][BN*PK];
  const int tid = threadIdx.x;
  const int bx = blockIdx.x;
  const int bm = blockIdx.y*BM;
  const int bnB = (bx<=2) ? bx*128 : 320;
  const int wv = tid>>6, lane = tid&63;
  const int n16 = lane&15, q = lane>>4;
  const int wm = wv>>1, wn = wv&1;

  f32x4 acc[2][TN];
  #pragma unroll
  for (int i=0;i<2;i++){
    #pragma unroll
    for (int j=0;j<TN;j++){ f32x4 z={0.f,0.f,0.f,0.f}; acc[i][j]=z; }
  }
  for (int k0=0;k0<K;k0+=32){
    #pragma unroll
    for (int c0=0;c0<BM*8;c0+=256){
      int c = c0 + tid;
      int row = c>>3, kg = (c&7)*4;
      float4 v = *(const float4*)&x[(size_t)(bm+row)*K + k0+kg];
      unsigned hp0 = cvt_pk_bf16(v.x, v.y), hp1 = cvt_pk_bf16(v.z, v.w);
      unsigned lp0 = cvt_pk_bf16(v.x-lo16f(hp0), v.y-hi16f(hp0));
      unsigned lp1 = cvt_pk_bf16(v.z-lo16f(hp1), v.w-hi16f(hp1));
      int off = row*PK+kg;
      uintx2 th = {hp0, hp1}, tl = {lp0, lp1};
      *(uintx2*)&As[0][off] = th;
      *(uintx2*)&As[1][off] = tl;
    }
    #pragma unroll
    for (int c0=0;c0<BN*4;c0+=256){
      int c = c0 + tid;
      int row = c>>2, kg = (c&3)*8;
      *(short8*)&Bs[0][row*PK+kg] = *(const short8*)&BhT[(size_t)(bnB+row)*K + k0+kg];
      *(short8*)&Bs[1][row*PK+kg] = *(const short8*)&BlT[(size_t)(bnB+row)*K + k0+kg];
    }
    __syncthreads();
    short8 a_h[2], a_l[2], b_h[TN], b_l[TN];
    #pragma unroll
    for (int i=0;i<2;i++){
      int r = wm*32 + i*16 + n16;
      a_h[i] = *(const short8*)&As[0][r*PK + q*8];
      a_l[i] = *(const short8*)&As[1][r*PK + q*8];
    }
    #pragma unroll
    for (int j=0;j<TN;j++){
      int r = wn*(BN/2) + j*16 + n16;
      b_h[j] = *(const short8*)&Bs[0][r*PK + q*8];
      b_l[j] = *(const short8*)&Bs[1][r*PK + q*8];
    }
    #pragma unroll
    for (int i=0;i<2;i++){
      #pragma unroll
      for (int j=0;j<TN;j++){
        acc[i][j] = __builtin_amdgcn_mfma_f32_16x16x32_bf16(a_h[i], b_h[j], acc[i][j], 0,0,0);
        acc[i][j] = __builtin_amdgcn_mfma_f32_16x16x32_bf16(a_l[i], b_h[j], acc[i][j], 0,0,0);
        acc[i][j] = __builtin_amdgcn_mfma_f32_16x16x32_bf16(a_h[i], b_l[j], acc[i][j], 0,0,0);
      }
    }
    __syncthreads();
  }
  #pragma unroll
  for (int i=0;i<2;i++){
    #pragma unroll
    for (int j=0;j<TN;j++){
      #pragma unroll
      for (int r=0;r<4;r++){
        int row = bm + wm*32 + i*16 + q*4 + r;
        int col = wn*64 + j*16 + n16;
        float v = acc[i][j][r];
        if (bx==0){
          k_raw[(size_t)row*Hq + col] = v;
        } else if (bx==1){
          v_raw[(size_t)row*Hq + col] = v;
        } else if (bx==2){
          if (col < 64) te[(size_t)row*Rq + col] = v;
          else          td[(size_t)row*Rq + col-64] = v;
        } else {
          if (col >= 64) ta[(size_t)row*Rq + col-64] = v;
        }
      }
    }
  }
}

// ---------------- merged second-stage R=64 GEMMs, BM=64 tiles -------------
__global__ __launch_bounds__(256) void gemm_eda2(
    const float* __restrict__ te, const float* __restrict__ td, const float* __restrict__ ta,
    const unsigned short* __restrict__ usb,
    float* __restrict__ etab, float* __restrict__ deltab, float* __restrict__ alphab)
{
  constexpr int BM = 64, PK = 40, BN = 128, TN = 4, K = Rq, N = Hq;
  __shared__ __align__(16) unsigned short As[2][BM*PK];
  __shared__ __align__(16) unsigned short Bs[2][BN*PK];
  const int tid = threadIdx.x;
  const int bx = blockIdx.x;
  const int bm = blockIdx.y*BM;
  const float* __restrict__ Af = (bx==0) ? te : (bx==1) ? td : ta;
  const unsigned short* __restrict__ BhT = usb + ((bx==0) ? U_WE2TH : (bx==1) ? U_WD2TH : U_WA2TH);
  const unsigned short* __restrict__ BlT = usb + ((bx==0) ? U_WE2TL : (bx==1) ? U_WD2TL : U_WA2TL);
  float* __restrict__ C = (bx==0) ? etab : (bx==1) ? deltab : alphab;
  const int wv = tid>>6, lane = tid&63;
  const int n16 = lane&15, q = lane>>4;
  const int wm = wv>>1, wn = wv&1;

  f32x4 acc[2][TN];
  #pragma unroll
  for (int i=0;i<2;i++){
    #pragma unroll
    for (int j=0;j<TN;j++){ f32x4 z={0.f,0.f,0.f,0.f}; acc[i][j]=z; }
  }
  for (int k0=0;k0<K;k0+=32){
    #pragma unroll
    for (int c0=0;c0<BM*8;c0+=256){
      int c = c0 + tid;
      int row = c>>3, kg = (c&7)*4;
      float4 v = *(const float4*)&Af[(size_t)(bm+row)*K + k0+kg];
      unsigned hp0 = cvt_pk_bf16(v.x, v.y), hp1 = cvt_pk_bf16(v.z, v.w);
      unsigned lp0 = cvt_pk_bf16(v.x-lo16f(hp0), v.y-hi16f(hp0));
      unsigned lp1 = cvt_pk_bf16(v.z-lo16f(hp1), v.w-hi16f(hp1));
      int off = row*PK+kg;
      uintx2 th = {hp0, hp1}, tl = {lp0, lp1};
      *(uintx2*)&As[0][off] = th;
      *(uintx2*)&As[1][off] = tl;
    }
    #pragma unroll
    for (int c0=0;c0<BN*4;c0+=256){
      int c = c0 + tid;
      int row = c>>2, kg = (c&3)*8;
      *(short8*)&Bs[0][row*PK+kg] = *(const short8*)&BhT[(size_t)row*K + k0+kg];
      *(short8*)&Bs[1][row*PK+kg] = *(const short8*)&BlT[(size_t)row*K + k0+kg];
    }
    __syncthreads();
    short8 a_h[2], a_l[2], b_h[TN], b_l[TN];
    #pragma unroll
    for (int i=0;i<2;i++){
      int r = wm*32 + i*16 + n16;
      a_h[i] = *(const short8*)&As[0][r*PK + q*8];
      a_l[i] = *(const short8*)&As[1][r*PK + q*8];
    }
    #pragma unroll
    for (int j=0;j<TN;j++){
      int r = wn*(BN/2) + j*16 + n16;
      b_h[j] = *(const short8*)&Bs[0][r*PK + q*8];
      b_l[j] = *(const short8*)&Bs[1][r*PK + q*8];
    }
    #pragma unroll
    for (int i=0;i<2;i++){
      #pragma unroll
      for (int j=0;j<TN;j++){
        acc[i][j] = __builtin_amdgcn_mfma_f32_16x16x32_bf16(a_h[i], b_h[j], acc[i][j], 0,0,0);
        acc[i][j] = __builtin_amdgcn_mfma_f32_16x16x32_bf16(a_l[i], b_h[j], acc[i][j], 0,0,0);
        acc[i][j] = __builtin_amdgcn_mfma_f32_16x16x32_bf16(a_h[i], b_l[j], acc[i][j], 0,0,0);
      }
    }
    __syncthreads();
  }
  #pragma unroll
  for (int i=0;i<2;i++){
    #pragma unroll
    for (int j=0;j<TN;j++){
      #pragma unroll
      for (int r=0;r<4;r++){
        int row = bm + wm*32 + i*16 + q*4 + r;
        int col = wn*(BN/2) + j*16 + n16;
        float v = acc[i][j][r];
        v = (bx==2) ? sigmoidf_(v) : softplusf_(v);
        C[(size_t)row*N+col] = v;
      }
    }
  }
}

// ---------------- one-shot weight transpose+split (10 segments) ------------
__global__ __launch_bounds__(256) void splitT_all(
    const float* __restrict__ Wk,  const float* __restrict__ Wv,
    const float* __restrict__ We1, const float* __restrict__ Wd1,
    const float* __restrict__ Wa1, const float* __restrict__ Wg,
    const float* __restrict__ We2, const float* __restrict__ Wd2,
    const float* __restrict__ Wa2, const float* __restrict__ Wo,
    unsigned short* __restrict__ usb)
{
  size_t idx = (size_t)blockIdx.x*256 + threadIdx.x;
#define SEG(SRC, DH, DL, K_, N_) \
  { size_t sz = (size_t)(K_)*(N_); \
    if (idx < sz){ \
      int nn = (int)(idx/(K_)); int k = (int)(idx - (size_t)nn*(K_)); \
      float v = (SRC)[(size_t)k*(N_) + nn]; \
      unsigned short hh = bf16rn(v); \
      (DH)[idx] = hh; (DL)[idx] = bf16rn(v - bf16tof(hh)); \
      return; } \
    idx -= sz; }
  SEG(Wk,  usb+U_XPH,                   usb+U_XPL,                   Dq, Hq)
  SEG(Wv,  usb+U_XPH+(size_t)128*Dq,    usb+U_XPL+(size_t)128*Dq,    Dq, Hq)
  SEG(We1, usb+U_XPH+(size_t)256*Dq,    usb+U_XPL+(size_t)256*Dq,    Dq, Rq)
  SEG(Wd1, usb+U_XPH+(size_t)320*Dq,    usb+U_XPL+(size_t)320*Dq,    Dq, Rq)
  SEG(Wa1, usb+U_XPH+(size_t)384*Dq,    usb+U_XPL+(size_t)384*Dq,    Dq, Rq)
  SEG(Wg,  usb+U_WGTH,                  usb+U_WGTL,                  Dq, Dq)
  SEG(We2, usb+U_WE2TH,                 usb+U_WE2TL,                 Rq, Hq)
  SEG(Wd2, usb+U_WD2TH,                 usb+U_WD2TL,                 Rq, Hq)
  SEG(Wa2, usb+U_WA2TH,                 usb+U_WA2TL,                 Rq, Hq)
  SEG(Wo,  usb+U_WOTH,                  usb+U_WOTL,                  Hq, Dq)
#undef SEG
}

// conv+LN, coarsened: one 256-thread block handles k-conv+LN AND v-conv for
// 2 s-positions (sp = tid>>7). 8192 blocks instead of 32768. k emits
// pre-split bf16 hi/lo planes (same split of the same f32 -> bit-identical).
__global__ __launch_bounds__(256) void conv_ln_kernel(
  const float* __restrict__ k_raw, const float* __restrict__ v_raw,
  const float* __restrict__ conv_w, const float* __restrict__ conv_b,
  const float* __restrict__ kn_g, const float* __restrict__ kn_b,
  unsigned short* __restrict__ khi, unsigned short* __restrict__ klo,
  float* __restrict__ v_out)
{
  const int b  = blockIdx.y;
  const int sp = threadIdx.x >> 7;       // 0/1: which s within the pair
  const int h  = threadIdx.x & 127;
  const int s  = blockIdx.x*2 + sp;
  const int w4 = threadIdx.x >> 6;       // wave 0..3 (waves {0,1}=sp0, {2,3}=sp1)
  const float cb = conv_b[h];
  float acck = cb, accv = cb;
  #pragma unroll
  for (int j=0;j<4;j++){
    int ss = s-3+j;
    if (ss>=0){
      float w = conv_w[h*4+j];
      size_t idx = ((size_t)b*Sq+ss)*Hq + h;
      acck += w*k_raw[idx];
      accv += w*v_raw[idx];
    }
  }
  // LN over the 128 threads sharing sp
  __shared__ float red[8];
  float sv = acck, s2 = acck*acck;
  #pragma unroll
  for (int off=32; off>0; off>>=1){
    sv += __shfl_down(sv, off, 64);
    s2 += __shfl_down(s2, off, 64);
  }
  if ((threadIdx.x&63)==0){ red[w4*2]=sv; red[w4*2+1]=s2; }
  __syncthreads();
  float mean = (red[sp*4+0]+red[sp*4+2])*(1.f/128.f);
  float var  = (red[sp*4+1]+red[sp*4+3])*(1.f/128.f) - mean*mean;
  float y = (acck-mean)*rsqrtf(var+1e-5f)*kn_g[h]+kn_b[h];
  unsigned short hh = bf16rn(y);
  size_t idx = ((size_t)b*Sq+s)*Hq + h;
  khi[idx] = hh;
  klo[idx] = bf16rn(y - bf16tof(hh));
  v_out[idx] = accv;
}

// ---- LDS overlay offsets (bytes) for the fused kernel's scan branch ----
#define OFF_KCH   0            // 64*128*2   = 16384
#define OFF_KCL   16384        // 16384
#define OFF_ACTH  32768        // 64*256*2   = 32768
#define OFF_SAM   65536        // 1024
#define OFF_SUS   66560        // 512
#define OFF_PEN   67072        // 64*12*4 = 3072
#define OFF_DRED  70144        // 8*256*4 = 8192
#define OFF_SUU   78336        // 32
#define OFF_SAB   78368        // 512
#define OFF_SEB   78880        // 512
#define OFF_SABP  79392        // 8
#define OFF_SEBP  79400        // 8
#define LDS_TOTAL 79408

// Fused kernel: blocks 0..3 = sequential scan (1 per batch);
// blocks 4.. = Wg GEMM tiles, co-scheduled on idle CUs.
// Scan schedule (3 barriers/chunk; __syncthreads drains vmcnt -> all global
// loads are issued RIGHT AFTER a barrier so the next phase covers them):
//   B1 -> [vv/dd + ab/eb issue] -> W1+b1 upd(t-1) -> GEMM1(kc LDS) -> gelu
//   -> publish -> B2 -> [aw/ew] -> stage kc(t+1) async -> GEMM2
//   -> epilogue/pen -> B3 -> en/grad/us -> b2 -> butterfly d[m] -> W2 upd
__global__ __launch_bounds__(512, 2) void fused_scan_wg(
  const unsigned short* __restrict__ khi, const unsigned short* __restrict__ klo,
  const float* __restrict__ v_c,
  const float* __restrict__ eta, const float* __restrict__ delta,
  const float* __restrict__ alpha,
  const float* __restrict__ mW1, const float* __restrict__ mb1,
  const float* __restrict__ mW2, const float* __restrict__ mb2,
  float* __restrict__ combined,
  const float* __restrict__ x,
  const unsigned short* __restrict__ WgTh, const unsigned short* __restrict__ WgTl,
  float* __restrict__ glog)
{
  __shared__ __align__(16) char smem[LDS_TOTAL];
  const int blk = blockIdx.x;
  const int tid = threadIdx.x;
  const int wv = tid >> 6;
  const int lane = tid & 63;
  const int n = lane & 15;
  const int q = lane >> 4;

  if (blk >= 4){
    // ================= Wg GEMM branch (512 thr, 128x128 tile) =================
    unsigned short* As_h = (unsigned short*)smem;          // 128*40
    unsigned short* As_l = As_h + 128*40;
    unsigned short* Bs_h = As_l + 128*40;
    unsigned short* Bs_l = Bs_h + 128*40;
    const int g = blk - 4;
    const int bm = (g>>3)*128, bn = (g&7)*128;
    const int wm = wv&3, wn = wv>>2;
    f32x4 acc[2][4];
    #pragma unroll
    for (int i=0;i<2;i++){
      #pragma unroll
      for (int j=0;j<4;j++){ f32x4 z={0.f,0.f,0.f,0.f}; acc[i][j]=z; }
    }
    for (int k0=0;k0<Dq;k0+=32){
      #pragma unroll
      for (int r=0;r<2;r++){
        int idx = tid + 512*r;
        int row = idx>>3, kg = (idx&7)*4;
        float4 v = *(const float4*)&x[(size_t)(bm+row)*Dq + k0+kg];
        unsigned hp0 = cvt_pk_bf16(v.x, v.y), hp1 = cvt_pk_bf16(v.z, v.w);
        unsigned lp0 = cvt_pk_bf16(v.x-lo16f(hp0), v.y-hi16f(hp0));
        unsigned lp1 = cvt_pk_bf16(v.z-lo16f(hp1), v.w-hi16f(hp1));
        int off = row*40+kg;
        uintx2 th = {hp0, hp1}, tl = {lp0, lp1};
        *(uintx2*)&As_h[off] = th;
        *(uintx2*)&As_l[off] = tl;
      }
      {
        int row = tid>>2, kg = (tid&3)*8;
        *(short8*)&Bs_h[row*40+kg] = *(const short8*)&WgTh[(size_t)(bn+row)*Dq + k0+kg];
        *(short8*)&Bs_l[row*40+kg] = *(const short8*)&WgTl[(size_t)(bn+row)*Dq + k0+kg];
      }
      __syncthreads();
      short8 a_h[2], a_l[2], b_h[4], b_l[4];
      #pragma unroll
      for (int i=0;i<2;i++){
        int r = wm*32 + i*16 + n;
        a_h[i] = *(const short8*)&As_h[r*40 + q*8];
        a_l[i] = *(const short8*)&As_l[r*40 + q*8];
      }
      #pragma unroll
      for (int j=0;j<4;j++){
        int r = wn*64 + j*16 + n;
        b_h[j] = *(const short8*)&Bs_h[r*40 + q*8];
        b_l[j] = *(const short8*)&Bs_l[r*40 + q*8];
      }
      #pragma unroll
      for (int i=0;i<2;i++){
        #pragma unroll
        for (int j=0;j<4;j++){
          acc[i][j] = __builtin_amdgcn_mfma_f32_16x16x32_bf16(a_h[i], b_h[j], acc[i][j], 0,0,0);
          acc[i][j] = __builtin_amdgcn_mfma_f32_16x16x32_bf16(a_l[i], b_h[j], acc[i][j], 0,0,0);
          acc[i][j] = __builtin_amdgcn_mfma_f32_16x16x32_bf16(a_h[i], b_l[j], acc[i][j], 0,0,0);
        }
      }
      __syncthreads();
    }
    #pragma unroll
    for (int i=0;i<2;i++){
      #pragma unroll
      for (int j=0;j<4;j++){
        #pragma unroll
        for (int r=0;r<4;r++){
          int row = bm + wm*32 + i*16 + q*4 + r;
          int col = bn + wn*64 + j*16 + n;
          glog[(size_t)row*Dq+col] = acc[i][j][r];
        }
      }
    }
    return;
  }

  // ================= scan branch =================
  unsigned short* kc_hi  = (unsigned short*)(smem + OFF_KCH);
  unsigned short* kc_lo  = (unsigned short*)(smem + OFF_KCL);
  unsigned short* act_hi = (unsigned short*)(smem + OFF_ACTH);
  float* Sam = (float*)(smem + OFF_SAM);
  float* Sus = (float*)(smem + OFF_SUS);
  float* pen = (float*)(smem + OFF_PEN);   // [c][12] (8 wave partials)
  float* Dred= (float*)(smem + OFF_DRED);  // [wv][256] per-wave d = us.W2old partials
  float* Suu = (float*)(smem + OFF_SUU);   // [8]  per-wave us.us partials
  float* Sab = (float*)(smem + OFF_SAB);
  float* Seb = (float*)(smem + OFF_SEB);
  float* Sabp = (float*)(smem + OFF_SABP);
  float* Sebp = (float*)(smem + OFF_SEBP);

  const int b = blk;
  const int h = wv*16 + n;          // W2 row ownership (A-frag of swapped GEMM2)
  float w1m[2][4][8];   // W1[m=(2wv+tt)*16+n][h=ks*32+q*8+j]
  float w2m[8][8];      // W2[h=wv*16+n][m=ks2*32+q*8+j]
  float b1reg[2];       // b1[m=(2wv+tt)*16+n]
  float b2n[4];         // b2[h2=wv*16+q*4+r]  (swapped-GEMM2 output rows)
  #pragma unroll
  for (int tt=0;tt<2;tt++){
    int m = (2*wv+tt)*16 + n;
    #pragma unroll
    for (int ks=0;ks<4;ks++){
      const float* p = mW1 + (size_t)m*Hq + ks*32 + q*8;
      #pragma unroll
      for (int j=0;j<8;j++) w1m[tt][ks][j] = p[j];
    }
    b1reg[tt] = mb1[m];
  }
  {
    #pragma unroll
    for (int ks2=0;ks2<8;ks2++){
      const float* p = mW2 + (size_t)h*Mq + ks2*32 + q*8;
      #pragma unroll
      for (int j=0;j<8;j++) w2m[ks2][j] = p[j];
    }
    #pragma unroll
    for (int r=0;r<4;r++) b2n[r] = mb2[wv*16 + q*4 + r];
  }
  // cross-chunk carried scalars (chunk t-1 values, consumed at t's top)
  float aw = 0.f, ew = 0.f;
  float am_own[2] = {0.f, 0.f};

  const unsigned short* khb = khi + (size_t)b*Sq*Hq;
  const unsigned short* klb = klo + (size_t)b*Sq*Hq;

  // ---- async kc staging setup: pre-swizzled per-lane global offsets so the
  // linear global_load_lds write (base + lane*16) produces the swizzled LDS
  // image LDS[c*128 + pg*8 + e] = k[c][((pg^(c&15))<<3)+e].
  const int c0s = (wv*2+0)*4 + (lane>>4);
  const int c1s = (wv*2+1)*4 + (lane>>4);
  const int soff0 = c0s*Hq + ((((lane&15)^(c0s&15)))<<3);
  const int soff1 = c1s*Hq + ((((lane&15)^(c1s&15)))<<3);
  char* d_kh0 = smem + OFF_KCH + (wv*2+0)*1024;
  char* d_kh1 = smem + OFF_KCH + (wv*2+1)*1024;
  char* d_kl0 = smem + OFF_KCL + (wv*2+0)*1024;
  char* d_kl1 = smem + OFF_KCL + (wv*2+1)*1024;
  // prologue: stage chunk 0 (drains at B1 of t=0 via __syncthreads vmcnt(0))
  g2lds16(khb + soff0, d_kh0);
  g2lds16(khb + soff1, d_kh1);
  g2lds16(klb + soff0, d_kl0);
  g2lds16(klb + soff1, d_kl1);

  for (int t=0; t<NCHUNK; ++t){
    const size_t base = ((size_t)b*Sq + (size_t)t*Cq)*Hq;
    __syncthreads();   // B1: kc(t) staged; orders prev-chunk Sus/Dred/Suu

    // ---- issue this chunk's global loads NOW (drain at B2 under GEMM1) ----
    f32x4 vvv[4], ddd[4];
    #pragma unroll
    for (int ct=0;ct<4;ct++){
      size_t off = base + (size_t)(ct*16+n)*Hq + wv*16 + q*4;
      vvv[ct] = *(const f32x4*)&v_c[off];
      ddd[ct] = *(const f32x4*)&delta[off];
    }
    float ab_=0.f, eb_=0.f;
    if (tid < 128){
      ab_ = alpha[base + 63*Hq + tid];
      eb_ = eta[base + 63*Hq + tid];
    }

    // ---- W1 + b1 update from chunk t-1 (reads Sus/Dred/Suu) ----
    if (t > 0){
      float4 s0[4], s1[4];
      #pragma unroll
      for (int ks=0;ks<4;ks++){
        s0[ks] = *(const float4*)&Sus[ks*32 + q*8];
        s1[ks] = *(const float4*)&Sus[ks*32 + q*8 + 4];
      }
      float4 u0 = *(const float4*)&Suu[0];
      float4 u1 = *(const float4*)&Suu[4];
      float uu = u0.x+u0.y+u0.z+u0.w+u1.x+u1.y+u1.z+u1.w;
      #pragma unroll
      for (int tt=0;tt<2;tt++){
        int m = (2*wv+tt)*16 + n;
        float amm = am_own[tt];
        float eam = ew*amm;
        #pragma unroll
        for (int ks=0;ks<4;ks++){
          #pragma unroll
          for (int j=0;j<4;j++){
            w1m[tt][ks][j]   = aw*w1m[tt][ks][j]   - eam*s0[ks][j];
            w1m[tt][ks][j+4] = aw*w1m[tt][ks][j+4] - eam*s1[ks][j];
          }
        }
        float dsum = 0.f;
        #pragma unroll
        for (int w8=0;w8<8;w8++) dsum += Dred[w8*256 + m];
        // b1u = us.nW2[:,m] = aw*dsum - ew*uu*am[m]
        b1reg[tt] = aw*b1reg[tt] - ew*(aw*dsum - ew*uu*amm);
      }
    }

    // ---- GEMM1: inter = kc @ W1^T (kc hi/lo from LDS, W1 hi/lo: 3-MFMA) ----
    f32x4 acc1[2][4];
    #pragma unroll
    for (int tt=0;tt<2;tt++){
      #pragma unroll
      for (int ct=0;ct<4;ct++){ f32x4 z={0.f,0.f,0.f,0.f}; acc1[tt][ct]=z; }
    }
    __builtin_amdgcn_s_setprio(1);
    #pragma unroll
    for (int ks=0;ks<4;ks++){
      pk8 BH[2], BL[2];
      #pragma unroll
      for (int tt=0;tt<2;tt++){
        #pragma unroll
        for (int jp=0;jp<4;jp++){
          float a0 = w1m[tt][ks][2*jp], a1 = w1m[tt][ks][2*jp+1];
          unsigned hp = cvt_pk_bf16(a0, a1);
          BH[tt].u[jp] = hp;
          BL[tt].u[jp] = cvt_pk_bf16(a0 - lo16f(hp), a1 - hi16f(hp));
        }
      }
      #pragma unroll
      for (int ct=0;ct<4;ct++){
        int c = ct*16 + n;
        int off = c*Hq + ((((ks*4+q)^n))<<3);
        short8 ah = *(const short8*)&kc_hi[off];
        short8 al = *(const short8*)&kc_lo[off];
        #pragma unroll
        for (int tt=0;tt<2;tt++){
          acc1[tt][ct] = __builtin_amdgcn_mfma_f32_16x16x32_bf16(ah, BH[tt].s, acc1[tt][ct], 0,0,0);
          acc1[tt][ct] = __builtin_amdgcn_mfma_f32_16x16x32_bf16(al, BH[tt].s, acc1[tt][ct], 0,0,0);
          acc1[tt][ct] = __builtin_amdgcn_mfma_f32_16x16x32_bf16(ah, BL[tt].s, acc1[tt][ct], 0,0,0);
        }
      }
    }
    __builtin_amdgcn_s_setprio(0);
    // gelu -> act_hi + am
    #pragma unroll
    for (int tt=0;tt<2;tt++){
      int m = (2*wv+tt)*16 + n;
      float b1v = b1reg[tt];
      float amsum = 0.f;
      #pragma unroll
      for (int ct=0;ct<4;ct++){
        #pragma unroll
        for (int r=0;r<4;r++){
          float g = gelu_fast(acc1[tt][ct][r] + b1v);
          amsum += g;
          int c = ct*16 + q*4 + r;
          int pg = (m>>3) ^ (c & 15);
          act_hi[c*Mq + (pg<<3) + (m&7)] = bf16rn(g);
        }
      }
      amsum += __shfl_xor(amsum, 16, 64);
      amsum += __shfl_xor(amsum, 32, 64);
      am_own[tt] = amsum*(1.f/64.f);
      if (q==0) Sam[m] = am_own[tt];
    }
    // publish alpha/eta
    if (tid < 128){ Sab[tid] = ab_; Seb[tid] = eb_; }
    if (wv < 2){
      float a2 = ab_, e2 = eb_;
      #pragma unroll
      for (int mk=1;mk<64;mk<<=1){ a2 += __shfl_xor(a2,mk,64); e2 += __shfl_xor(e2,mk,64); }
      if (lane==0){ Sabp[wv] = a2; Sebp[wv] = e2; }
    }
    __syncthreads();   // B2: act/Sam/Sab/Sabp ready; all GEMM1 kc reads done

    // ---- aw/ew for this chunk (Sabp published pre-B2; read early to hide
    //      the LDS latency ahead of the post-B3 dependency chain) ----
    aw = (Sabp[0]+Sabp[1])*(1.f/128.f);
    ew = (Sebp[0]+Sebp[1])*(1.f/128.f);

    // ---- stage kc(t+1) into LDS (async; drains at B3 under GEMM2 cover) ----
    {
      const size_t nb = (size_t)((t+1<NCHUNK)?(t+1):t)*Cq*Hq;
      g2lds16(khb + nb + soff0, d_kh0);
      g2lds16(khb + nb + soff1, d_kh1);
      g2lds16(klb + nb + soff0, d_kl0);
      g2lds16(klb + nb + soff1, d_kl1);
    }

    // ---- GEMM2 (operand-swapped): out^T = W2 @ act^T -> out[h2][c] ----
    f32x4 acc2[4];
    #pragma unroll
    for (int ct=0;ct<4;ct++){ f32x4 z={0.f,0.f,0.f,0.f}; acc2[ct]=z; }
    __builtin_amdgcn_s_setprio(1);
    #pragma unroll
    for (int ks2=0;ks2<8;ks2++){
      pk8 BH, BL;
      #pragma unroll
      for (int jp=0;jp<4;jp++){
        float a0 = w2m[ks2][2*jp], a1 = w2m[ks2][2*jp+1];
        unsigned hp = cvt_pk_bf16(a0, a1);
        BH.u[jp] = hp;
        BL.u[jp] = cvt_pk_bf16(a0 - lo16f(hp), a1 - hi16f(hp));
      }
      #pragma unroll
      for (int ct=0;ct<4;ct++){
        int c = ct*16 + n;
        int off = c*Mq + ((((ks2*4+q)^n))<<3);
        short8 ah = *(const short8*)&act_hi[off];
        acc2[ct] = __builtin_amdgcn_mfma_f32_16x16x32_bf16(BH.s, ah, acc2[ct], 0,0,0);
        acc2[ct] = __builtin_amdgcn_mfma_f32_16x16x32_bf16(BL.s, ah, acc2[ct], 0,0,0);
      }
    }
    __builtin_amdgcn_s_setprio(0);

    // ---- epilogue: float4 out store, err, pen partials (2 shfl) ----
    float err[4][4];
    {
      float* cb = combined + base;
      #pragma unroll
      for (int ct=0;ct<4;ct++){
        int c = ct*16 + n;
        f32x4 ov;
        #pragma unroll
        for (int r=0;r<4;r++){
          float o = acc2[ct][r] + b2n[r];
          ov[r] = o;
          err[ct][r] = o - vvv[ct][r];
        }
        *(f32x4*)&cb[(size_t)c*Hq + wv*16 + q*4] = ov;
      }
      #pragma unroll
      for (int ct=0;ct<4;ct++){
        float s = err[ct][0]*err[ct][0] + err[ct][1]*err[ct][1]
                + err[ct][2]*err[ct][2] + err[ct][3]*err[ct][3];
        s += __shfl_xor(s, 16, 64);
        s += __shfl_xor(s, 32, 64);
        if (q==0) pen[(ct*16+n)*12 + wv] = s;
      }
    }
    __syncthreads();   // B3: pen ready; kc(t+1) staging drained (vmcnt(0))

    // ---- en (direct pen reads) -> grad -> us (n-butterfly) ----
    float en_c[4];
    #pragma unroll
    for (int ct=0;ct<4;ct++){
      int c = ct*16 + n;
      float4 e0 = *(const float4*)&pen[c*12];
      float4 e1 = *(const float4*)&pen[c*12+4];
      en_c[ct] = sqrtf(e0.x+e0.y+e0.z+e0.w+e1.x+e1.y+e1.z+e1.w);
    }
    float us_r[4];
    #pragma unroll
    for (int r=0;r<4;r++){
      float s = 0.f;
      #pragma unroll
      for (int ct=0;ct<4;ct++){
        float e = err[ct][r];
        float dvv = ddd[ct][r];
        float en = en_c[ct];
        float g = (en > dvv) ? dvv*e*__builtin_amdgcn_rcpf(en+1e-9f) : e;
        s += g;
      }
      s += __shfl_xor(s,1,64); s += __shfl_xor(s,2,64);
      s += __shfl_xor(s,4,64); s += __shfl_xor(s,8,64);
      us_r[r] = s*(1.f/64.f);     // us[h2 = wv*16+q*4+r], replicated over n
    }
    if (n==0){
      #pragma unroll
      for (int r=0;r<4;r++) Sus[wv*16 + q*4 + r] = us_r[r];
    }
    // uu partial over this wave's 16 h (sum over r in-thread, then over q)
    {
      float uun = us_r[0]*us_r[0] + us_r[1]*us_r[1]
                + us_r[2]*us_r[2] + us_r[3]*us_r[3];
      uun += __shfl_xor(uun, 16, 64);
      uun += __shfl_xor(uun, 32, 64);
      if (lane==0) Suu[wv] = uun;
    }
    // ---- b2 update (in-register, float4 Sab/Seb reads) ----
    {
      f32x4 sab = *(const f32x4*)&Sab[wv*16 + q*4];
      f32x4 seb = *(const f32x4*)&Seb[wv*16 + q*4];
      #pragma unroll
      for (int r=0;r<4;r++) b2n[r] = sab[r]*b2n[r] - seb[r]*us_r[r];
    }
    // ---- ush at W2-ownership lane (h = wv*16+n) via shfl pulls ----
    float ush;
    {
      int src = (n>>2)<<4;     // any lane in q-group n>>2 (us_r replicated over n)
      float p0 = __shfl(us_r[0], src, 64);
      float p1 = __shfl(us_r[1], src, 64);
      float p2 = __shfl(us_r[2], src, 64);
      float p3 = __shfl(us_r[3], src, 64);
      int rr = n&3;
      ush = (rr==0) ? p0 : (rr==1) ? p1 : (rr==2) ? p2 : p3;
    }

    // ---- d[m] = us . W2_old[:,m]: reduce-scatter butterfly over n ----
    {
      const bool bb0 = (n&1);
      float p1[8][4];
      #pragma unroll
      for (int k2=0;k2<8;k2++){
        #pragma unroll
        for (int l=0;l<4;l++){
          float mine = ush * (bb0 ? w2m[k2][l+4] : w2m[k2][l]);
          float oth  = ush * (bb0 ? w2m[k2][l]   : w2m[k2][l+4]);
          p1[k2][l] = mine + __shfl_xor(oth, 1, 64);
        }
      }
      const bool bb1 = (n>>1)&1;
      float p2[4][4];
      #pragma unroll
      for (int k2=0;k2<4;k2++){
        #pragma unroll
        for (int l=0;l<4;l++){
          float mine = bb1 ? p1[2*k2+1][l] : p1[2*k2][l];
          float oth  = bb1 ? p1[2*k2][l]   : p1[2*k2+1][l];
          p2[k2][l] = mine + __shfl_xor(oth, 2, 64);
        }
      }
      const bool bb2 = (n>>2)&1;
      float p3[2][4];
      #pragma unroll
      for (int k2=0;k2<2;k2++){
        #pragma unroll
        for (int l=0;l<4;l++){
          float mine = bb2 ? p2[2*k2+1][l] : p2[2*k2][l];
          float oth  = bb2 ? p2[2*k2][l]   : p2[2*k2+1][l];
          p3[k2][l] = mine + __shfl_xor(oth, 4, 64);
        }
      }
      const bool bb3 = (n>>3)&1;
      float4 p4;
      {
        float m0 = bb3 ? p3[1][0] : p3[0][0];
        float o0 = bb3 ? p3[0][0] : p3[1][0];
        p4.x = m0 + __shfl_xor(o0, 8, 64);
        float m1 = bb3 ? p3[1][1] : p3[0][1];
        float o1 = bb3 ? p3[0][1] : p3[1][1];
        p4.y = m1 + __shfl_xor(o1, 8, 64);
        float m2 = bb3 ? p3[1][2] : p3[0][2];
        float o2 = bb3 ? p3[0][2] : p3[1][2];
        p4.z = m2 + __shfl_xor(o2, 8, 64);
        float m3 = bb3 ? p3[1][3] : p3[0][3];
        float o3 = bb3 ? p3[0][3] : p3[1][3];
        p4.w = m3 + __shfl_xor(o3, 8, 64);
      }
      // lane owns 4 consecutive m: (n>>1)*32 + q*8 + (n&1)*4 + [0..3]
      int base_m = (n>>1)*32 + q*8 + (n&1)*4;
      *(float4*)&Dred[wv*256 + base_m] = p4;
    }

    // ---- W2 update (uses ush at h=wv*16+n, Sam reads; consumed by
    //      GEMM2(t+1) which is past B2(t+1) -> no extra barrier) ----
    {
      float eus = ew*ush;
      #pragma unroll
      for (int ks2=0;ks2<8;ks2++){
        float4 a0 = *(const float4*)&Sam[ks2*32 + q*8];
        float4 a1 = *(const float4*)&Sam[ks2*32 + q*8 + 4];
        #pragma unroll
        for (int j=0;j<4;j++){
          w2m[ks2][j]   = aw*w2m[ks2][j]   - eus*a0[j];
          w2m[ks2][j+4] = aw*w2m[ks2][j+4] - eus*a1[j];
        }
      }
    }
    // W1 + b1 update deferred to top of chunk t+1 (after B1).
  }
}

extern "C" void kernel_launch(void* const* d_in, const int* in_sizes, int n_in,
                              void* d_out, int out_size, void* d_ws, size_t ws_size,
                              hipStream_t stream)
{
  const float* x    = (const float*)d_in[0];
  // d_in[1]=Wq, d_in[14],[15]=qn_g/qn_b: dead (q path unused by output).
  const float* Wk   = (const float*)d_in[2];
  const float* Wv   = (const float*)d_in[3];
  const float* Wo   = (const float*)d_in[4];
  const float* Wg   = (const float*)d_in[5];
  const float* We1  = (const float*)d_in[6];
  const float* We2  = (const float*)d_in[7];
  const float* Wd1  = (const float*)d_in[8];
  const float* Wd2  = (const float*)d_in[9];
  const float* Wa1  = (const float*)d_in[10];
  const float* Wa2  = (const float*)d_in[11];
  const float* conv_w = (const float*)d_in[12];
  const float* conv_b = (const float*)d_in[13];
  const float* kn_g = (const float*)d_in[16];
  const float* kn_b = (const float*)d_in[17];
  const float* mW1  = (const float*)d_in[18];
  const float* mb1  = (const float*)d_in[19];
  const float* mW2  = (const float*)d_in[20];
  const float* mb2  = (const float*)d_in[21];
  float* out = (float*)d_out;

  float* ws = (float*)d_ws;
  size_t o = 0;
  float* k_raw = ws + o; o += (size_t)BSq*Hq;
  float* v_raw = ws + o; o += (size_t)BSq*Hq;
  float* te    = ws + o; o += (size_t)BSq*Rq;
  float* td    = ws + o; o += (size_t)BSq*Rq;
  float* ta    = ws + o; o += (size_t)BSq*Rq;
  float* glog  = ws + o; o += (size_t)BSq*Dq;
  float* etab  = ws + o; o += (size_t)BSq*Hq;
  float* deltab= ws + o; o += (size_t)BSq*Hq;
  float* alphab= ws + o; o += (size_t)BSq*Hq;
  float* kslot = ws + o; o += (size_t)BSq*Hq;   // khi/klo bf16 planes (8MB slot)
  float* v_c   = ws + o; o += (size_t)BSq*Hq;
  float* comb  = ws + o; o += (size_t)BSq*Hq;
  unsigned short* usb = (unsigned short*)(ws + o);

  unsigned short* khi = (unsigned short*)kslot;
  unsigned short* klo = khi + (size_t)BSq*Hq;

  // one-shot weight transpose+split (all 10 weights, 1 launch)
  {
    size_t total = (size_t)448*Dq + (size_t)Dq*Dq + 3*(size_t)Hq*Rq + (size_t)Dq*Hq;
    splitT_all<<<(unsigned)(total/256), 256, 0, stream>>>(
        Wk, Wv, We1, Wd1, Wa1, Wg, We2, Wd2, Wa2, Wo, usb);
  }

  dim3 blk(256);
  // merged x-projections: ONE dispatch (Wk, Wv, We1|Wd1, Wd1|Wa1 tiles)
  gemm_xproj<<<dim3(4, BSq/64), blk, 0, stream>>>(
      x, usb+U_XPH, usb+U_XPL, k_raw, v_raw, te, td, ta);
  // merged second-stage R=64 GEMMs (eta/delta/alpha)
  gemm_eda2<<<dim3(3, BSq/64), blk, 0, stream>>>(te, td, ta, usb, etab, deltab, alphab);
  // coarsened conv+LN (k and v, 2 s-positions per block)
  conv_ln_kernel<<<dim3(Sq/2, Bq), dim3(256), 0, stream>>>(
      k_raw, v_raw, conv_w, conv_b, kn_g, kn_b, khi, klo, v_c);
  // fused: scan (blocks 0..3) + Wg GEMM (blocks 4..1027) co-scheduled
  fused_scan_wg<<<dim3(4 + (BSq/128)*(Dq/128)), dim3(512), 0, stream>>>(
      khi, klo, v_c, etab, deltab, alphab, mW1, mb1, mW2, mb2, comb,
      x, usb+U_WGTH, usb+U_WGTL, glog);
  gemm_bf3<128,3><<<dim3(Dq/128, BSq/128), blk, 0, stream>>>(comb, usb+U_WOTH, usb+U_WOTL, out, glog, Dq, Hq);
}